// Round 4
// baseline (485.969 us; speedup 1.0000x reference)
//
#include <hip/hip_runtime.h>
#include <hip/hip_bf16.h>
#include <math.h>

// Problem constants
#define BB 2
#define TT 1024
#define CC 1024
#define HH 16
#define DD 64
#define EE 16
#define II 256
#define NN (BB*TT)          // 2048 tokens
#define EPSLN 1e-5f
#define LDA 72              // bf16 LDS row stride: 144B rows, 16B-aligned

typedef __attribute__((ext_vector_type(8))) short short8;
typedef __attribute__((ext_vector_type(4))) short s16x4;
typedef __attribute__((ext_vector_type(4))) float f32x4;

__device__ inline void splitbf(float x, short& hi, short& lo) {
    __hip_bfloat16 h = __float2bfloat16(x);
    float hf = __bfloat162float(h);
    __hip_bfloat16 l = __float2bfloat16(x - hf);
    hi = *(short*)&h;
    lo = *(short*)&l;
}

// ---------------------------------------------------------------------------
// LayerNorm (LN1): one block per row. Emits pre-split bf16 hi/lo.
// ---------------------------------------------------------------------------
__global__ __launch_bounds__(256) void ln_kernel(const float* __restrict__ x,
                                                 const float* __restrict__ g,
                                                 const float* __restrict__ bta,
                                                 __hip_bfloat16* __restrict__ outh,
                                                 __hip_bfloat16* __restrict__ outl) {
    const int row = blockIdx.x, tid = threadIdx.x;
    __shared__ float r1[256], r2[256];
    const float* xr = x + (long)row * CC;
    float4 xv = ((const float4*)xr)[tid];
    float s  = xv.x + xv.y + xv.z + xv.w;
    float q2 = xv.x*xv.x + xv.y*xv.y + xv.z*xv.z + xv.w*xv.w;
    r1[tid] = s; r2[tid] = q2; __syncthreads();
    for (int st = 128; st > 0; st >>= 1) {
        if (tid < st) { r1[tid] += r1[tid+st]; r2[tid] += r2[tid+st]; }
        __syncthreads();
    }
    const float mu  = r1[0] * (1.f/CC);
    const float var = r2[0] * (1.f/CC) - mu*mu;
    const float rs  = rsqrtf(var + EPSLN);
    float4 gv = ((const float4*)g)[tid];
    float4 bv = ((const float4*)bta)[tid];
    float xs[4];
    xs[0] = (xv.x-mu)*rs*gv.x + bv.x;
    xs[1] = (xv.y-mu)*rs*gv.y + bv.y;
    xs[2] = (xv.z-mu)*rs*gv.z + bv.z;
    xs[3] = (xv.w-mu)*rs*gv.w + bv.w;
    s16x4 hv, lv;
    #pragma unroll
    for (int j = 0; j < 4; j++) { short h,l; splitbf(xs[j], h, l); hv[j]=h; lv[j]=l; }
    *(s16x4*)(outh + (long)row * CC + tid*4) = hv;
    *(s16x4*)(outl + (long)row * CC + tid*4) = lv;
}

// ---------------------------------------------------------------------------
// Fused LN2 + router: LN -> h2b bf16; scores/mask/k_per_token in one pass.
// ---------------------------------------------------------------------------
__global__ __launch_bounds__(256) void ln2_router(const float* __restrict__ xio,
                                                  const float* __restrict__ g,
                                                  const float* __restrict__ bta,
                                                  const float* __restrict__ sim,
                                                  const float* __restrict__ cn,
                                                  const float* __restrict__ thr,
                                                  __hip_bfloat16* __restrict__ h2b,
                                                  float* __restrict__ scores,
                                                  float* __restrict__ kpt,
                                                  float* __restrict__ maskb) {
    const int row = blockIdx.x, tid = threadIdx.x;
    __shared__ float r1[256], r2[256];
    __shared__ float red[256*17];
    float4 xv = ((const float4*)(xio + (long)row*CC))[tid];
    float s  = xv.x + xv.y + xv.z + xv.w;
    float q2 = xv.x*xv.x + xv.y*xv.y + xv.z*xv.z + xv.w*xv.w;
    r1[tid] = s; r2[tid] = q2; __syncthreads();
    for (int st = 128; st > 0; st >>= 1) {
        if (tid < st) { r1[tid] += r1[tid+st]; r2[tid] += r2[tid+st]; }
        __syncthreads();
    }
    const float mu  = r1[0] * (1.f/CC);
    const float var = r2[0] * (1.f/CC) - mu*mu;
    const float rs  = rsqrtf(var + EPSLN);
    float4 gv = ((const float4*)g)[tid];
    float4 bv = ((const float4*)bta)[tid];
    float ovs[4];
    ovs[0] = (xv.x-mu)*rs*gv.x + bv.x;
    ovs[1] = (xv.y-mu)*rs*gv.y + bv.y;
    ovs[2] = (xv.z-mu)*rs*gv.z + bv.z;
    ovs[3] = (xv.w-mu)*rs*gv.w + bv.w;
    {
        __hip_bfloat16* p = h2b + (long)row*CC + tid*4;
        p[0] = __float2bfloat16(ovs[0]); p[1] = __float2bfloat16(ovs[1]);
        p[2] = __float2bfloat16(ovs[2]); p[3] = __float2bfloat16(ovs[3]);
    }
    // router: this thread's 4 contiguous channels
    float acc[17] = {};
    #pragma unroll
    for (int j = 0; j < 4; j++) {
        const float v = ovs[j];
        acc[16] += v*v;
        const float* sr = sim + (long)(tid*4 + j)*EE;
        #pragma unroll
        for (int e2 = 0; e2 < EE; e2++) acc[e2] += v*sr[e2];
    }
    #pragma unroll
    for (int e2 = 0; e2 < 17; e2++) red[tid*17 + e2] = acc[e2];
    __syncthreads();
    for (int st = 128; st > 0; st >>= 1) {
        if (tid < st)
            for (int e2 = 0; e2 < 17; e2++) red[tid*17+e2] += red[(tid+st)*17+e2];
        __syncthreads();
    }
    if (tid < EE) {
        const float nrm = sqrtf(red[16]);
        const float sc  = red[tid] / (nrm * cn[tid]);
        scores[(long)row*EE + tid] = sc;
        const float mkv = sc > thr[0] ? 1.f : 0.f;
        maskb[(long)row*EE + tid] = mkv;
        red[tid] = mkv;
    }
    __syncthreads();
    if (tid == 0) {
        float c2 = 0.f;
        for (int e2 = 0; e2 < EE; e2++) c2 += red[e2];
        kpt[row] = c2;
    }
}

// ---------------------------------------------------------------------------
// One-shot QKVO weight prep (single launch, z selects weight):
// W[K][N] fp32 -> Wt[N][K] bf16 hi + lo (bf16x3 split).
// ---------------------------------------------------------------------------
__global__ __launch_bounds__(256) void transpose_split4(const float* __restrict__ W0,
                                                        const float* __restrict__ W1,
                                                        const float* __restrict__ W2,
                                                        const float* __restrict__ W3,
                                                        __hip_bfloat16* __restrict__ Wth_base,
                                                        __hip_bfloat16* __restrict__ Wtl_base) {
    const int z = blockIdx.z;
    const float* W = (z==0) ? W0 : (z==1) ? W1 : (z==2) ? W2 : W3;
    __hip_bfloat16* Wth = Wth_base + (long)z*CC*CC;
    __hip_bfloat16* Wtl = Wtl_base + (long)z*CC*CC;
    const int n0 = blockIdx.x * 32, k0 = blockIdx.y * 32;
    __shared__ float t[32][33];
    const int tx = threadIdx.x & 31, ty = threadIdx.x >> 5;
    #pragma unroll
    for (int i = 0; i < 4; i++)
        t[ty + i*8][tx] = W[(long)(k0 + ty + i*8)*CC + n0 + tx];
    __syncthreads();
    #pragma unroll
    for (int i = 0; i < 4; i++) {
        float v = t[tx][ty + i*8];
        short h, l; splitbf(v, h, l);
        *(short*)&Wth[(long)(n0 + ty + i*8)*CC + k0 + tx] = h;
        *(short*)&Wtl[(long)(n0 + ty + i*8)*CC + k0 + tx] = l;
    }
}

// ---------------------------------------------------------------------------
// Expert weight prep (single launch): z = half*16 + e. half0: w1 [C][I] ->
// w1t [I][C]; half1: w2 [I][C] -> w2t [C][I]. Flattened grid.x = 256 blocks/e.
// ---------------------------------------------------------------------------
__global__ __launch_bounds__(256) void transpose_f2b_both(const float* __restrict__ w1,
                                                          const float* __restrict__ w2,
                                                          __hip_bfloat16* __restrict__ w1t,
                                                          __hip_bfloat16* __restrict__ w2t) {
    const int zz = blockIdx.z;
    const int half = zz >> 4, e = zz & 15;
    const float* W; __hip_bfloat16* Wt; int K, N, nbx;
    if (half == 0) { W = w1 + (long)e*CC*II; Wt = w1t + (long)e*CC*II; K = CC; N = II; nbx = II/32; }
    else           { W = w2 + (long)e*II*CC; Wt = w2t + (long)e*II*CC; K = II; N = CC; nbx = CC/32; }
    const int bx = blockIdx.x;
    const int n0 = (bx % nbx) * 32, k0 = (bx / nbx) * 32;
    __shared__ float t[32][33];
    const int tx = threadIdx.x & 31, ty = threadIdx.x >> 5;
    #pragma unroll
    for (int i = 0; i < 4; i++)
        t[ty + i*8][tx] = W[(long)(k0 + ty + i*8)*N + n0 + tx];
    __syncthreads();
    #pragma unroll
    for (int i = 0; i < 4; i++)
        Wt[(long)(n0 + ty + i*8)*K + k0 + tx] = __float2bfloat16(t[tx][ty + i*8]);
}

// ---------------------------------------------------------------------------
// bf16 transpose for V: [b*T + t][C] (hi/lo) -> [(b*H + h)*64 + d][T] (hi/lo)
// ---------------------------------------------------------------------------
__global__ __launch_bounds__(256) void transpose_v_bf16(
        const __hip_bfloat16* __restrict__ Vh, const __hip_bfloat16* __restrict__ Vl,
        __hip_bfloat16* __restrict__ Vth, __hip_bfloat16* __restrict__ Vtl) {
    const int b = blockIdx.z;
    const int c0 = blockIdx.y * 32, t0 = blockIdx.x * 32;
    __shared__ unsigned short th[32][33], tl[32][33];
    const int tx = threadIdx.x & 31, ty = threadIdx.x >> 5;
    const unsigned short* vh = (const unsigned short*)Vh;
    const unsigned short* vl = (const unsigned short*)Vl;
    #pragma unroll
    for (int i = 0; i < 4; i++) {
        const long src = ((long)b*TT + t0 + ty + i*8)*CC + c0 + tx;
        th[ty + i*8][tx] = vh[src];
        tl[ty + i*8][tx] = vl[src];
    }
    __syncthreads();
    #pragma unroll
    for (int i = 0; i < 4; i++) {
        const int gc = c0 + ty + i*8;          // global channel
        const int hh = gc >> 6, d = gc & 63;
        const long dst = ((long)(b*HH + hh)*64 + d)*TT + t0 + tx;
        ((unsigned short*)Vth)[dst] = th[tx][ty + i*8];
        ((unsigned short*)Vtl)[dst] = tl[tx][ty + i*8];
    }
}

// ---------------------------------------------------------------------------
// fp32-accurate MFMA GEMM via bf16x3 split (AhBh + AhBl + AlBh) with
// PRE-SPLIT inputs: A = (Ah,Al)[M][K] bf16, B = (Bth,Btl)[z][N][K] bf16.
// Tile 64Mx128N, BK=32, 4 waves. EPI: 1 = fp32 +resid, 2 = split bf16 out
// ---------------------------------------------------------------------------
template<int EPI>
__global__ __launch_bounds__(256, 2) void gemm_split(
        const __hip_bfloat16* __restrict__ Ah,
        const __hip_bfloat16* __restrict__ Al,
        const __hip_bfloat16* __restrict__ Bh_base,
        const __hip_bfloat16* __restrict__ Bl_base,
        float* __restrict__ C_base,
        __hip_bfloat16* __restrict__ Ch_base,
        __hip_bfloat16* __restrict__ Cl_base,
        int M, int N, int K,
        const float* __restrict__ resid) {
    __shared__ __hip_bfloat16 Ash[64][40], Asl[64][40];
    __shared__ __hip_bfloat16 Bsh[128][40], Bsl[128][40];
    const int z = blockIdx.z;
    const __hip_bfloat16* Bth = Bh_base + (long)z * N * K;
    const __hip_bfloat16* Btl = Bl_base + (long)z * N * K;
    const int n0 = blockIdx.x * 128, m0 = blockIdx.y * 64;
    const int tid = threadIdx.x;
    const int wave = tid >> 6, lane = tid & 63;
    const int wm = (wave >> 1) * 32, wn = (wave & 1) * 64;
    const int l15 = lane & 15, quad = lane >> 4;

    f32x4 acc[2][4] = {};

    for (int k0 = 0; k0 < K; k0 += 32) {
        {   // A tile: 64 rows x 32 k, contiguous short8 per thread
            const int r = tid >> 2, kg = (tid & 3) * 8;
            *(short8*)&Ash[r][kg] = *(const short8*)(Ah + (long)(m0 + r)*K + k0 + kg);
            *(short8*)&Asl[r][kg] = *(const short8*)(Al + (long)(m0 + r)*K + k0 + kg);
        }
        #pragma unroll
        for (int it = 0; it < 2; it++) {   // B tile: 128 rows x 32 k
            const int idx = tid + it*256;
            const int r = idx >> 2, kg = (idx & 3) * 8;
            *(short8*)&Bsh[r][kg] = *(const short8*)(Bth + (long)(n0 + r)*K + k0 + kg);
            *(short8*)&Bsl[r][kg] = *(const short8*)(Btl + (long)(n0 + r)*K + k0 + kg);
        }
        __syncthreads();
        short8 ah[2], al[2], bh[4], bl[4];
        #pragma unroll
        for (int mi = 0; mi < 2; mi++) {
            ah[mi] = *(const short8*)&Ash[wm + mi*16 + l15][quad*8];
            al[mi] = *(const short8*)&Asl[wm + mi*16 + l15][quad*8];
        }
        #pragma unroll
        for (int ni = 0; ni < 4; ni++) {
            bh[ni] = *(const short8*)&Bsh[wn + ni*16 + l15][quad*8];
            bl[ni] = *(const short8*)&Bsl[wn + ni*16 + l15][quad*8];
        }
        #pragma unroll
        for (int mi = 0; mi < 2; mi++)
            #pragma unroll
            for (int ni = 0; ni < 4; ni++) {
                acc[mi][ni] = __builtin_amdgcn_mfma_f32_16x16x32_bf16(ah[mi], bh[ni], acc[mi][ni], 0,0,0);
                acc[mi][ni] = __builtin_amdgcn_mfma_f32_16x16x32_bf16(ah[mi], bl[ni], acc[mi][ni], 0,0,0);
                acc[mi][ni] = __builtin_amdgcn_mfma_f32_16x16x32_bf16(al[mi], bh[ni], acc[mi][ni], 0,0,0);
            }
        __syncthreads();
    }

    #pragma unroll
    for (int mi = 0; mi < 2; mi++)
        #pragma unroll
        for (int r = 0; r < 4; r++) {
            const int row = m0 + wm + mi*16 + quad*4 + r;
            #pragma unroll
            for (int ni = 0; ni < 4; ni++) {
                const int col = n0 + wn + ni*16 + l15;
                float val = acc[mi][ni][r];
                if (EPI == 2) {
                    short hh, ll; splitbf(val, hh, ll);
                    *(short*)&Ch_base[(long)z*M*N + (long)row*N + col] = hh;
                    *(short*)&Cl_base[(long)z*M*N + (long)row*N + col] = ll;
                } else {
                    if (EPI == 1) val += resid[(long)row*N + col];
                    C_base[(long)z*M*N + (long)row*N + col] = val;
                }
            }
        }
}

// ---------------------------------------------------------------------------
// bf16 MFMA GEMM (expert GEMM1): mid[e] = gelu(A @ Bt[e]^T) -> bf16
// ---------------------------------------------------------------------------
__global__ __launch_bounds__(256) void gemm_mfma1(
        const __hip_bfloat16* __restrict__ A,
        const __hip_bfloat16* __restrict__ Bt, long sBe,
        __hip_bfloat16* __restrict__ Cp, long sCe, int ldc,
        int M, int N, int K) {
    constexpr int LDK = 40;
    __shared__ __hip_bfloat16 As[128][LDK];
    __shared__ __hip_bfloat16 Bs[128][LDK];
    const int e = blockIdx.z;
    Bt += (long)e * sBe;
    const int n0 = blockIdx.x * 128, m0 = blockIdx.y * 128;
    const int tid = threadIdx.x;
    const int wave = tid >> 6, lane = tid & 63;
    const int wm = (wave >> 1) * 64, wn = (wave & 1) * 64;
    const int l15 = lane & 15, quad = lane >> 4;

    f32x4 acc[4][4] = {};

    for (int k0 = 0; k0 < K; k0 += 32) {
        #pragma unroll
        for (int it = 0; it < 2; it++) {
            int idx = tid + it*256;
            int r = idx >> 2, kg = idx & 3;
            short8 av = *(const short8*)(A  + (long)(m0 + r)*K + k0 + kg*8);
            short8 bv = *(const short8*)(Bt + (long)(n0 + r)*K + k0 + kg*8);
            *(short8*)&As[r][kg*8] = av;
            *(short8*)&Bs[r][kg*8] = bv;
        }
        __syncthreads();
        short8 af[4], bff[4];
        #pragma unroll
        for (int i = 0; i < 4; i++) {
            af[i]  = *(const short8*)&As[wm + i*16 + l15][quad*8];
            bff[i] = *(const short8*)&Bs[wn + i*16 + l15][quad*8];
        }
        #pragma unroll
        for (int mi = 0; mi < 4; mi++)
            #pragma unroll
            for (int ni = 0; ni < 4; ni++)
                acc[mi][ni] = __builtin_amdgcn_mfma_f32_16x16x32_bf16(
                                  af[mi], bff[ni], acc[mi][ni], 0, 0, 0);
        __syncthreads();
    }

    #pragma unroll
    for (int mi = 0; mi < 4; mi++) {
        #pragma unroll
        for (int r = 0; r < 4; r++) {
            const int row = m0 + wm + mi*16 + quad*4 + r;
            #pragma unroll
            for (int ni = 0; ni < 4; ni++) {
                const int col = n0 + wn + ni*16 + l15;
                float val = acc[mi][ni][r];
                val = 0.5f*val*(1.f + erff(val*0.70710678118f));
                Cp[(long)e*sCe + (long)row*ldc + col] = __float2bfloat16(val);
            }
        }
    }
}

// ---------------------------------------------------------------------------
// Expert GEMM2 fused with sum-over-experts: each block handles 4 experts
// (z = expert-group), writes eo[n,e,:] = (mid[e] @ w2[e]^T) * mask[n,e] and
// atomically adds the masked sum into xio (which holds x + attn residual).
// ---------------------------------------------------------------------------
__global__ __launch_bounds__(256) void gemm_moe2(
        const __hip_bfloat16* __restrict__ mid,   // [16][NN][II]
        const __hip_bfloat16* __restrict__ w2t,   // [16][CC][II]
        float* __restrict__ eo,                   // [NN][EE][CC]
        float* __restrict__ xio,                  // [NN][CC]
        const float* __restrict__ mask) {
    constexpr int LDK = 40;
    __shared__ __hip_bfloat16 As[128][LDK];
    __shared__ __hip_bfloat16 Bs[128][LDK];
    const int e0 = blockIdx.z * 4;
    const int n0 = blockIdx.x * 128, m0 = blockIdx.y * 128;
    const int tid = threadIdx.x;
    const int wave = tid >> 6, lane = tid & 63;
    const int wm = (wave >> 1) * 64, wn = (wave & 1) * 64;
    const int l15 = lane & 15, quad = lane >> 4;

    f32x4 sum[4][4] = {};

    for (int ei = 0; ei < 4; ei++) {
        const int e = e0 + ei;
        const __hip_bfloat16* A  = mid + (long)e*NN*II;
        const __hip_bfloat16* Bt = w2t + (long)e*CC*II;
        f32x4 acc[4][4] = {};
        for (int k0 = 0; k0 < II; k0 += 32) {
            #pragma unroll
            for (int it = 0; it < 2; it++) {
                int idx = tid + it*256;
                int r = idx >> 2, kg = idx & 3;
                short8 av = *(const short8*)(A  + (long)(m0 + r)*II + k0 + kg*8);
                short8 bv = *(const short8*)(Bt + (long)(n0 + r)*II + k0 + kg*8);
                *(short8*)&As[r][kg*8] = av;
                *(short8*)&Bs[r][kg*8] = bv;
            }
            __syncthreads();
            short8 af[4], bff[4];
            #pragma unroll
            for (int i = 0; i < 4; i++) {
                af[i]  = *(const short8*)&As[wm + i*16 + l15][quad*8];
                bff[i] = *(const short8*)&Bs[wn + i*16 + l15][quad*8];
            }
            #pragma unroll
            for (int mi = 0; mi < 4; mi++)
                #pragma unroll
                for (int ni = 0; ni < 4; ni++)
                    acc[mi][ni] = __builtin_amdgcn_mfma_f32_16x16x32_bf16(
                                      af[mi], bff[ni], acc[mi][ni], 0, 0, 0);
            __syncthreads();
        }
        // epilogue for this expert: write eo, accumulate masked sum
        #pragma unroll
        for (int mi = 0; mi < 4; mi++) {
            #pragma unroll
            for (int r = 0; r < 4; r++) {
                const int row = m0 + wm + mi*16 + quad*4 + r;
                const float mv = mask[(long)row*EE + e];
                #pragma unroll
                for (int ni = 0; ni < 4; ni++) {
                    const int col = n0 + wn + ni*16 + l15;
                    const float val = acc[mi][ni][r] * mv;
                    eo[((long)row*EE + e)*CC + col] = val;
                    sum[mi][ni][r] += val;
                }
            }
        }
    }

    // final: add this expert-group's partial sum into xio
    #pragma unroll
    for (int mi = 0; mi < 4; mi++)
        #pragma unroll
        for (int r = 0; r < 4; r++) {
            const int row = m0 + wm + mi*16 + quad*4 + r;
            #pragma unroll
            for (int ni = 0; ni < 4; ni++) {
                const int col = n0 + wn + ni*16 + l15;
                atomicAdd(&xio[(long)row*CC + col], sum[mi][ni][r]);
            }
        }
}

// ---------------------------------------------------------------------------
// Flash attention with bf16x3 MFMA for QK^T and PV. kt-split for balance.
// All inputs PRE-SPLIT bf16 hi/lo; V pre-transposed [(b*H+h)*64+d][T].
// Staging is pure contiguous short8 copies. Online softmax in registers.
// ---------------------------------------------------------------------------
__global__ __launch_bounds__(256, 4) void attn_split(
        const __hip_bfloat16* __restrict__ Qh, const __hip_bfloat16* __restrict__ Ql,
        const __hip_bfloat16* __restrict__ Kh, const __hip_bfloat16* __restrict__ Kl,
        const __hip_bfloat16* __restrict__ Vtg_h, const __hip_bfloat16* __restrict__ Vtg_l,
        float* __restrict__ Opart,
        float* __restrict__ mpart,
        float* __restrict__ lpart) {
    __shared__ __hip_bfloat16 KPh[64][LDA], KPl[64][LDA];   // K, then P
    __shared__ __hip_bfloat16 Vth[64][LDA], Vtl[64][LDA];   // V^T [d][kk]

    const int bx = blockIdx.x;                 // 0..31, heavy qt first
    const int qt = 15 - (bx >> 1), half = bx & 1;
    const int h = blockIdx.y, b = blockIdx.z;
    const int tid = threadIdx.x;
    const int wave = tid >> 6, lane = tid & 63;
    const int l15 = lane & 15, quad = lane >> 4;
    const int wm = wave * 16;                  // wave's 16 q-rows in the 64-tile
    const long tbase = (long)b * TT * CC + (long)h * DD;          // [token][C] slab
    const long vbase = (long)(b*HH + h) * 64 * TT;                // V^T slab
    const int pidx = ((b*HH + h)*16 + qt)*2 + half;
    float* Op = Opart + (long)pidx * 4096;

    const int n_kt = qt + 1, mid_kt = (n_kt + 1) >> 1;
    const int kt_lo = half ? mid_kt : 0;
    const int kt_hi = half ? n_kt   : mid_kt;

    if (kt_lo >= kt_hi) {      // empty half (qt=0): neutral partials
        for (int i = tid; i < 64*64; i += 256) Op[i] = 0.f;
        if (tid < 64) { mpart[(long)pidx*64 + tid] = -1e30f; lpart[(long)pidx*64 + tid] = 0.f; }
        return;
    }

    // Q A-fragments direct from pre-split global
    short8 qh[2], ql[2];
    {
        const long qoff = tbase + (long)(qt*64 + wm + l15)*CC;
        #pragma unroll
        for (int kc = 0; kc < 2; kc++) {
            qh[kc] = *(const short8*)(Qh + qoff + kc*32 + quad*8);
            ql[kc] = *(const short8*)(Ql + qoff + kc*32 + quad*8);
        }
    }

    f32x4 oacc[4] = {};            // 4 d-tiles, rows = quad*4+reg
    float m_run[4], l_run[4];
    #pragma unroll
    for (int r = 0; r < 4; r++) { m_run[r] = -1e30f; l_run[r] = 0.f; }

    for (int kt = kt_lo; kt < kt_hi; kt++) {
        __syncthreads();           // prev-iter PV reads of KP/Vt done
        #pragma unroll
        for (int it = 0; it < 2; it++) {
            const int idx = tid + it*256;
            const int r = idx >> 3, g = (idx & 7)*8;
            const long koff = tbase + (long)(kt*64 + r)*CC + g;
            const long voff = vbase + (long)r*TT + kt*64 + g;
            *(short8*)&KPh[r][g] = *(const short8*)(Kh + koff);
            *(short8*)&KPl[r][g] = *(const short8*)(Kl + koff);
            *(short8*)&Vth[r][g] = *(const short8*)(Vtg_h + voff);
            *(short8*)&Vtl[r][g] = *(const short8*)(Vtg_l + voff);
        }
        __syncthreads();

        // QK^T via MFMA: 4 key-tiles x 2 k-chunks x 3 split terms
        f32x4 s[4] = {};
        #pragma unroll
        for (int nt = 0; nt < 4; nt++)
            #pragma unroll
            for (int kc = 0; kc < 2; kc++) {
                short8 bh = *(const short8*)&KPh[nt*16 + l15][kc*32 + quad*8];
                short8 bl = *(const short8*)&KPl[nt*16 + l15][kc*32 + quad*8];
                s[nt] = __builtin_amdgcn_mfma_f32_16x16x32_bf16(qh[kc], bh, s[nt], 0,0,0);
                s[nt] = __builtin_amdgcn_mfma_f32_16x16x32_bf16(qh[kc], bl, s[nt], 0,0,0);
                s[nt] = __builtin_amdgcn_mfma_f32_16x16x32_bf16(ql[kc], bh, s[nt], 0,0,0);
            }

        // online softmax in regs; row = wm + quad*4 + r, col = nt*16 + l15
        const bool diag = (kt == qt);
        float alpha[4];
        float pr[4][4];
        #pragma unroll
        for (int r = 0; r < 4; r++) {
            const int rowg = wm + quad*4 + r;
            float sv[4], mx = -1e30f;
            #pragma unroll
            for (int nt = 0; nt < 4; nt++) {
                float val = s[nt][r] * 0.125f;
                if (diag && (nt*16 + l15) > rowg) val = -1e30f;
                sv[nt] = val;
                mx = fmaxf(mx, val);
            }
            #pragma unroll
            for (int off = 1; off < 16; off <<= 1) mx = fmaxf(mx, __shfl_xor(mx, off, 16));
            const float mnew = fmaxf(m_run[r], mx);
            alpha[r] = __expf(m_run[r] - mnew);
            float rs = 0.f;
            #pragma unroll
            for (int nt = 0; nt < 4; nt++) {
                float p = __expf(sv[nt] - mnew);
                pr[r][nt] = p;
                rs += p;
            }
            #pragma unroll
            for (int off = 1; off < 16; off <<= 1) rs += __shfl_xor(rs, off, 16);
            l_run[r] = l_run[r]*alpha[r] + rs;
            m_run[r] = mnew;
        }
        __syncthreads();           // all QK reads of KP done -> overwrite as P

        // write P split into KP region: row = wm+quad*4+r, col = nt*16+l15
        #pragma unroll
        for (int r = 0; r < 4; r++)
            #pragma unroll
            for (int nt = 0; nt < 4; nt++) {
                short hh, ll; splitbf(pr[r][nt], hh, ll);
                *(short*)&KPh[wm + quad*4 + r][nt*16 + l15] = hh;
                *(short*)&KPl[wm + quad*4 + r][nt*16 + l15] = ll;
            }
        // no barrier: PV reads only this wave's own 16 P-rows

        // rescale O and accumulate PV via MFMA
        #pragma unroll
        for (int dt = 0; dt < 4; dt++)
            #pragma unroll
            for (int r = 0; r < 4; r++)
                oacc[dt][r] *= alpha[r];
        #pragma unroll
        for (int kc = 0; kc < 2; kc++) {
            short8 ph = *(const short8*)&KPh[wm + l15][kc*32 + quad*8];
            short8 pl = *(const short8*)&KPl[wm + l15][kc*32 + quad*8];
            #pragma unroll
            for (int dt = 0; dt < 4; dt++) {
                short8 vh = *(const short8*)&Vth[dt*16 + l15][kc*32 + quad*8];
                short8 vl = *(const short8*)&Vtl[dt*16 + l15][kc*32 + quad*8];
                oacc[dt] = __builtin_amdgcn_mfma_f32_16x16x32_bf16(ph, vh, oacc[dt], 0,0,0);
                oacc[dt] = __builtin_amdgcn_mfma_f32_16x16x32_bf16(ph, vl, oacc[dt], 0,0,0);
                oacc[dt] = __builtin_amdgcn_mfma_f32_16x16x32_bf16(pl, vh, oacc[dt], 0,0,0);
            }
        }
    }

    // store unnormalized O partial + (m,l)
    #pragma unroll
    for (int dt = 0; dt < 4; dt++)
        #pragma unroll
        for (int r = 0; r < 4; r++)
            Op[(wm + quad*4 + r)*64 + dt*16 + l15] = oacc[dt][r];
    if (l15 == 0) {
        #pragma unroll
        for (int r = 0; r < 4; r++) {
            mpart[(long)pidx*64 + wm + quad*4 + r] = m_run[r];
            lpart[(long)pidx*64 + wm + quad*4 + r] = l_run[r];
        }
    }
}

// ---------------------------------------------------------------------------
// Merge the two kt-half partials -> normalized attention output, emitted as
// pre-split bf16 hi/lo (direct feed for the WO bf16x3 GEMM).
// ---------------------------------------------------------------------------
__global__ __launch_bounds__(256) void attn_merge(const float* __restrict__ Opart,
                                                  const float* __restrict__ mpart,
                                                  const float* __restrict__ lpart,
                                                  __hip_bfloat16* __restrict__ aoh,
                                                  __hip_bfloat16* __restrict__ aol) {
    const int qt = blockIdx.x, h = blockIdx.y, b = blockIdx.z;
    const int pA = ((b*HH + h)*16 + qt)*2, pB = pA + 1;
    const int tid = threadIdx.x;
    const int r = tid >> 2, c0 = (tid & 3) * 16;
    const float mA = mpart[(long)pA*64 + r], mB = mpart[(long)pB*64 + r];
    const float lA = lpart[(long)pA*64 + r], lB = lpart[(long)pB*64 + r];
    const float M  = fmaxf(mA, mB);
    const float wA = __expf(mA - M), wB = __expf(mB - M);
    const float inv = 1.f / (lA*wA + lB*wB);
    const float* OA = Opart + (long)pA*4096 + r*64 + c0;
    const float* OB = Opart + (long)pB*4096 + r*64 + c0;
    const long dst = (long)b*TT*CC + (long)(qt*64 + r)*CC + h*DD + c0;
    #pragma unroll
    for (int j = 0; j < 16; j += 4) {
        float4 oa = *(const float4*)(OA + j);
        float4 ob = *(const float4*)(OB + j);
        float xs[4];
        xs[0] = (oa.x*wA + ob.x*wB)*inv;
        xs[1] = (oa.y*wA + ob.y*wB)*inv;
        xs[2] = (oa.z*wA + ob.z*wB)*inv;
        xs[3] = (oa.w*wA + ob.w*wB)*inv;
        s16x4 hv, lv;
        #pragma unroll
        for (int t = 0; t < 4; t++) { short hh,ll; splitbf(xs[t],hh,ll); hv[t]=hh; lv[t]=ll; }
        *(s16x4*)(aoh + dst + j) = hv;
        *(s16x4*)(aol + dst + j) = lv;
    }
}

// ---------------------------------------------------------------------------
// Column norms of sim_matrix [C, E]
// ---------------------------------------------------------------------------
__global__ __launch_bounds__(256) void colnorm_kernel(const float* __restrict__ sim,
                                                      float* __restrict__ cn) {
    const int e = blockIdx.x, tid = threadIdx.x;
    __shared__ float red[256];
    float s = 0.f;
    for (int c = tid; c < CC; c += 256) {
        float vv = sim[(long)c*EE + e];
        s += vv*vv;
    }
    red[tid] = s; __syncthreads();
    for (int st = 128; st > 0; st >>= 1) {
        if (tid < st) red[tid] += red[tid+st];
        __syncthreads();
    }
    if (tid == 0) cn[e] = sqrtf(red[0]);
}

// ---------------------------------------------------------------------------
extern "C" void kernel_launch(void* const* d_in, const int* in_sizes, int n_in,
                              void* d_out, int out_size, void* d_ws, size_t ws_size,
                              hipStream_t stream) {
    const float* x     = (const float*)d_in[0];
    const float* ln1_g = (const float*)d_in[1];
    const float* ln1_b = (const float*)d_in[2];
    const float* ln2_g = (const float*)d_in[3];
    const float* ln2_b = (const float*)d_in[4];
    const float* wq    = (const float*)d_in[5];
    const float* wk    = (const float*)d_in[6];
    const float* wv    = (const float*)d_in[7];
    const float* wo    = (const float*)d_in[8];
    const float* sim   = (const float*)d_in[9];
    const float* thr   = (const float*)d_in[10];
    const float* w1    = (const float*)d_in[11];
    const float* w2    = (const float*)d_in[12];

    float* out_x      = (float*)d_out;
    float* out_scores = out_x + (long)NN*CC;
    float* out_eo     = out_scores + (long)NN*EE;
    float* out_kpt    = out_eo + (long)NN*EE*CC;

    const long MF = (long)NN*CC;     // 2M floats
    const long CK = (long)CC*CC;     // 1M elems per weight slab
    float* ws   = (float*)d_ws;
    // [0, MF): attn-out split bf16 (hi/lo)
    __hip_bfloat16* aoh = (__hip_bfloat16*)ws;
    __hip_bfloat16* aol = (__hip_bfloat16*)(ws + MF/2);
    // [MF, 4MF): QKV pre-split bf16 (3 slabs hi, 3 slabs lo)
    __hip_bfloat16* qkvh = (__hip_bfloat16*)(ws + MF);
    __hip_bfloat16* qkvl = (__hip_bfloat16*)(ws + MF + 3*MF/2);
    // [4MF, 5MF): V^T pre-split bf16
    __hip_bfloat16* vth = (__hip_bfloat16*)(ws + 4*MF);
    __hip_bfloat16* vtl = (__hip_bfloat16*)(ws + 4*MF + MF/2);
    // [5MF, 5.5MF): LN2 bf16 for expert GEMM
    __hip_bfloat16* h2b = (__hip_bfloat16*)(ws + 5*MF);
    // [5.5MF, 7.5MF): attn partials; hh/hl (LN1 split) + mid alias
    float* Opart = ws + 5*MF + MF/2;
    __hip_bfloat16* hh  = (__hip_bfloat16*)(ws + 5*MF + MF/2);       // dead after QKV GEMM
    __hip_bfloat16* hl  = (__hip_bfloat16*)(ws + 6*MF);
    __hip_bfloat16* mid = (__hip_bfloat16*)(ws + 5*MF + MF/2);       // after merge
    // [7.5MF, 9.5MF): QKVO weight splits; w1t/w2t alias (after WO GEMM)
    __hip_bfloat16* wsph = (__hip_bfloat16*)(ws + 7*MF + MF/2);      // [4][C][C] hi
    __hip_bfloat16* wspl = (__hip_bfloat16*)(ws + 8*MF + MF/2);      // [4][C][C] lo
    __hip_bfloat16* w1t  = (__hip_bfloat16*)(ws + 7*MF + MF/2);
    __hip_bfloat16* w2t  = (__hip_bfloat16*)(ws + 8*MF + MF/2);
    float* maskb = ws + 9*MF + MF/2;                                  // 32K
    float* cn    = maskb + (long)NN*EE;                               // 16
    float* mpart = cn + 16;                                           // 64K
    float* lpart = mpart + 1024L*64;                                  // 64K

    // 0. sim column norms (input-only dependency, schedule first)
    colnorm_kernel<<<EE, 256, 0, stream>>>(sim, cn);

    // 1. one-shot QKVO weight transpose + bf16x3 split (single launch)
    {
        dim3 gt(CC/32, CC/32, 4);
        transpose_split4<<<gt, 256, 0, stream>>>(wq, wk, wv, wo, wsph, wspl);
    }

    // 2. LN1 -> pre-split bf16 hi/lo
    ln_kernel<<<NN, 256, 0, stream>>>(x, ln1_g, ln1_b, hh, hl);

    // 3. fused QKV projection -> pre-split bf16 hi/lo outputs
    {
        dim3 gq(CC/128, NN/64, 3);
        gemm_split<2><<<gq, 256, 0, stream>>>(hh, hl, wsph, wspl,
                                              nullptr, qkvh, qkvl,
                                              NN, CC, CC, nullptr);
    }

    // 3.5 V transpose (bf16 hi/lo): [token][C] -> per-(b,h) [d][T]
    {
        dim3 gv(TT/32, CC/32, BB);
        transpose_v_bf16<<<gv, 256, 0, stream>>>(qkvh + 2*(long)NN*CC, qkvl + 2*(long)NN*CC,
                                                 vth, vtl);
    }

    // 4. causal attention (MFMA flash, kt-split, pre-split inputs) + merge
    {
        dim3 gattn(32, HH, BB);
        attn_split<<<gattn, 256, 0, stream>>>(qkvh, qkvl,
                                              qkvh + (long)NN*CC, qkvl + (long)NN*CC,
                                              vth, vtl, Opart, mpart, lpart);
        dim3 gmerge(16, HH, BB);
        attn_merge<<<gmerge, 256, 0, stream>>>(Opart, mpart, lpart, aoh, aol);
    }

    // 5. output projection + residual -> d_out x slot
    {
        dim3 go(CC/128, NN/64, 1);
        gemm_split<1><<<go, 256, 0, stream>>>(aoh, aol, wsph + 3*CK, wspl + 3*CK,
                                              out_x, nullptr, nullptr,
                                              NN, CC, CC, x);
    }

    // 6. expert weight transposes (single launch; safe to overwrite QKVO splits)
    {
        dim3 ge(256, 1, 2*EE);
        transpose_f2b_both<<<ge, 256, 0, stream>>>(w1, w2, w1t, w2t);
    }

    // 7. fused LN2 + router
    ln2_router<<<NN, 256, 0, stream>>>(out_x, ln2_g, ln2_b, sim, cn, thr,
                                       h2b, out_scores, out_kpt, maskb);

    // 8. expert GEMM 1: mid[e] = gelu(h2 @ w1[e]) -> bf16
    {
        dim3 g(II/128, NN/128, EE);
        gemm_mfma1<<<g, 256, 0, stream>>>(h2b, w1t, (long)II*CC,
                                          mid, (long)NN*II, II,
                                          NN, II, CC);
    }

    // 9. expert GEMM 2 fused with sum: eo + (x += sum_e eo)
    {
        dim3 g(CC/128, NN/128, EE/4);
        gemm_moe2<<<g, 256, 0, stream>>>(mid, w2t, out_eo, out_x, maskb);
    }
}

// Round 5
// 483.683 us; speedup vs baseline: 1.0047x; 1.0047x over previous
//
#include <hip/hip_runtime.h>
#include <hip/hip_bf16.h>
#include <math.h>

// Problem constants
#define BB 2
#define TT 1024
#define CC 1024
#define HH 16
#define DD 64
#define EE 16
#define II 256
#define NN (BB*TT)          // 2048 tokens
#define EPSLN 1e-5f
#define LDA 72              // bf16 LDS row stride: 144B rows, 16B-aligned

typedef __attribute__((ext_vector_type(8))) short short8;
typedef __attribute__((ext_vector_type(4))) short s16x4;
typedef __attribute__((ext_vector_type(4))) float f32x4;

__device__ inline void splitbf(float x, short& hi, short& lo) {
    __hip_bfloat16 h = __float2bfloat16(x);
    float hf = __bfloat162float(h);
    __hip_bfloat16 l = __float2bfloat16(x - hf);
    hi = *(short*)&h;
    lo = *(short*)&l;
}

// ---------------------------------------------------------------------------
// LayerNorm (LN1): one block per row. Emits pre-split bf16 hi/lo.
// ---------------------------------------------------------------------------
__global__ __launch_bounds__(256) void ln_kernel(const float* __restrict__ x,
                                                 const float* __restrict__ g,
                                                 const float* __restrict__ bta,
                                                 __hip_bfloat16* __restrict__ outh,
                                                 __hip_bfloat16* __restrict__ outl) {
    const int row = blockIdx.x, tid = threadIdx.x;
    __shared__ float r1[256], r2[256];
    const float* xr = x + (long)row * CC;
    float4 xv = ((const float4*)xr)[tid];
    float s  = xv.x + xv.y + xv.z + xv.w;
    float q2 = xv.x*xv.x + xv.y*xv.y + xv.z*xv.z + xv.w*xv.w;
    r1[tid] = s; r2[tid] = q2; __syncthreads();
    for (int st = 128; st > 0; st >>= 1) {
        if (tid < st) { r1[tid] += r1[tid+st]; r2[tid] += r2[tid+st]; }
        __syncthreads();
    }
    const float mu  = r1[0] * (1.f/CC);
    const float var = r2[0] * (1.f/CC) - mu*mu;
    const float rs  = rsqrtf(var + EPSLN);
    float4 gv = ((const float4*)g)[tid];
    float4 bv = ((const float4*)bta)[tid];
    float xs[4];
    xs[0] = (xv.x-mu)*rs*gv.x + bv.x;
    xs[1] = (xv.y-mu)*rs*gv.y + bv.y;
    xs[2] = (xv.z-mu)*rs*gv.z + bv.z;
    xs[3] = (xv.w-mu)*rs*gv.w + bv.w;
    s16x4 hv, lv;
    #pragma unroll
    for (int j = 0; j < 4; j++) { short h,l; splitbf(xs[j], h, l); hv[j]=h; lv[j]=l; }
    *(s16x4*)(outh + (long)row * CC + tid*4) = hv;
    *(s16x4*)(outl + (long)row * CC + tid*4) = lv;
}

// ---------------------------------------------------------------------------
// Fused LN2 + router: LN -> h2b bf16; scores/mask/k_per_token in one pass.
// ---------------------------------------------------------------------------
__global__ __launch_bounds__(256) void ln2_router(const float* __restrict__ xio,
                                                  const float* __restrict__ g,
                                                  const float* __restrict__ bta,
                                                  const float* __restrict__ sim,
                                                  const float* __restrict__ cn,
                                                  const float* __restrict__ thr,
                                                  __hip_bfloat16* __restrict__ h2b,
                                                  float* __restrict__ scores,
                                                  float* __restrict__ kpt,
                                                  float* __restrict__ maskb) {
    const int row = blockIdx.x, tid = threadIdx.x;
    __shared__ float r1[256], r2[256];
    __shared__ float red[256*17];
    float4 xv = ((const float4*)(xio + (long)row*CC))[tid];
    float s  = xv.x + xv.y + xv.z + xv.w;
    float q2 = xv.x*xv.x + xv.y*xv.y + xv.z*xv.z + xv.w*xv.w;
    r1[tid] = s; r2[tid] = q2; __syncthreads();
    for (int st = 128; st > 0; st >>= 1) {
        if (tid < st) { r1[tid] += r1[tid+st]; r2[tid] += r2[tid+st]; }
        __syncthreads();
    }
    const float mu  = r1[0] * (1.f/CC);
    const float var = r2[0] * (1.f/CC) - mu*mu;
    const float rs  = rsqrtf(var + EPSLN);
    float4 gv = ((const float4*)g)[tid];
    float4 bv = ((const float4*)bta)[tid];
    float ovs[4];
    ovs[0] = (xv.x-mu)*rs*gv.x + bv.x;
    ovs[1] = (xv.y-mu)*rs*gv.y + bv.y;
    ovs[2] = (xv.z-mu)*rs*gv.z + bv.z;
    ovs[3] = (xv.w-mu)*rs*gv.w + bv.w;
    {
        __hip_bfloat16* p = h2b + (long)row*CC + tid*4;
        p[0] = __float2bfloat16(ovs[0]); p[1] = __float2bfloat16(ovs[1]);
        p[2] = __float2bfloat16(ovs[2]); p[3] = __float2bfloat16(ovs[3]);
    }
    // router: this thread's 4 contiguous channels
    float acc[17] = {};
    #pragma unroll
    for (int j = 0; j < 4; j++) {
        const float v = ovs[j];
        acc[16] += v*v;
        const float* sr = sim + (long)(tid*4 + j)*EE;
        #pragma unroll
        for (int e2 = 0; e2 < EE; e2++) acc[e2] += v*sr[e2];
    }
    #pragma unroll
    for (int e2 = 0; e2 < 17; e2++) red[tid*17 + e2] = acc[e2];
    __syncthreads();
    for (int st = 128; st > 0; st >>= 1) {
        if (tid < st)
            for (int e2 = 0; e2 < 17; e2++) red[tid*17+e2] += red[(tid+st)*17+e2];
        __syncthreads();
    }
    if (tid < EE) {
        const float nrm = sqrtf(red[16]);
        const float sc  = red[tid] / (nrm * cn[tid]);
        scores[(long)row*EE + tid] = sc;
        const float mkv = sc > thr[0] ? 1.f : 0.f;
        maskb[(long)row*EE + tid] = mkv;
        red[tid] = mkv;
    }
    __syncthreads();
    if (tid == 0) {
        float c2 = 0.f;
        for (int e2 = 0; e2 < EE; e2++) c2 += red[e2];
        kpt[row] = c2;
    }
}

// ---------------------------------------------------------------------------
// One-shot QKVO weight prep (single launch, z selects weight):
// W[K][N] fp32 -> Wt[N][K] bf16 hi + lo (bf16x3 split).
// ---------------------------------------------------------------------------
__global__ __launch_bounds__(256) void transpose_split4(const float* __restrict__ W0,
                                                        const float* __restrict__ W1,
                                                        const float* __restrict__ W2,
                                                        const float* __restrict__ W3,
                                                        __hip_bfloat16* __restrict__ Wth_base,
                                                        __hip_bfloat16* __restrict__ Wtl_base) {
    const int z = blockIdx.z;
    const float* W = (z==0) ? W0 : (z==1) ? W1 : (z==2) ? W2 : W3;
    __hip_bfloat16* Wth = Wth_base + (long)z*CC*CC;
    __hip_bfloat16* Wtl = Wtl_base + (long)z*CC*CC;
    const int n0 = blockIdx.x * 32, k0 = blockIdx.y * 32;
    __shared__ float t[32][33];
    const int tx = threadIdx.x & 31, ty = threadIdx.x >> 5;
    #pragma unroll
    for (int i = 0; i < 4; i++)
        t[ty + i*8][tx] = W[(long)(k0 + ty + i*8)*CC + n0 + tx];
    __syncthreads();
    #pragma unroll
    for (int i = 0; i < 4; i++) {
        float v = t[tx][ty + i*8];
        short h, l; splitbf(v, h, l);
        *(short*)&Wth[(long)(n0 + ty + i*8)*CC + k0 + tx] = h;
        *(short*)&Wtl[(long)(n0 + ty + i*8)*CC + k0 + tx] = l;
    }
}

// ---------------------------------------------------------------------------
// Expert weight prep (single launch): z = half*16 + e. half0: w1 [C][I] ->
// w1t [I][C]; half1: w2 [I][C] -> w2t [C][I]. Flattened grid.x = 256 blocks/e.
// ---------------------------------------------------------------------------
__global__ __launch_bounds__(256) void transpose_f2b_both(const float* __restrict__ w1,
                                                          const float* __restrict__ w2,
                                                          __hip_bfloat16* __restrict__ w1t,
                                                          __hip_bfloat16* __restrict__ w2t) {
    const int zz = blockIdx.z;
    const int half = zz >> 4, e = zz & 15;
    const float* W; __hip_bfloat16* Wt; int K, N, nbx;
    if (half == 0) { W = w1 + (long)e*CC*II; Wt = w1t + (long)e*CC*II; K = CC; N = II; nbx = II/32; }
    else           { W = w2 + (long)e*II*CC; Wt = w2t + (long)e*II*CC; K = II; N = CC; nbx = CC/32; }
    const int bx = blockIdx.x;
    const int n0 = (bx % nbx) * 32, k0 = (bx / nbx) * 32;
    __shared__ float t[32][33];
    const int tx = threadIdx.x & 31, ty = threadIdx.x >> 5;
    #pragma unroll
    for (int i = 0; i < 4; i++)
        t[ty + i*8][tx] = W[(long)(k0 + ty + i*8)*N + n0 + tx];
    __syncthreads();
    #pragma unroll
    for (int i = 0; i < 4; i++)
        Wt[(long)(n0 + ty + i*8)*K + k0 + tx] = __float2bfloat16(t[tx][ty + i*8]);
}

// ---------------------------------------------------------------------------
// bf16 transpose for V: [b*T + t][C] (hi/lo) -> [(b*H + h)*64 + d][T] (hi/lo)
// ---------------------------------------------------------------------------
__global__ __launch_bounds__(256) void transpose_v_bf16(
        const __hip_bfloat16* __restrict__ Vh, const __hip_bfloat16* __restrict__ Vl,
        __hip_bfloat16* __restrict__ Vth, __hip_bfloat16* __restrict__ Vtl) {
    const int b = blockIdx.z;
    const int c0 = blockIdx.y * 32, t0 = blockIdx.x * 32;
    __shared__ unsigned short th[32][33], tl[32][33];
    const int tx = threadIdx.x & 31, ty = threadIdx.x >> 5;
    const unsigned short* vh = (const unsigned short*)Vh;
    const unsigned short* vl = (const unsigned short*)Vl;
    #pragma unroll
    for (int i = 0; i < 4; i++) {
        const long src = ((long)b*TT + t0 + ty + i*8)*CC + c0 + tx;
        th[ty + i*8][tx] = vh[src];
        tl[ty + i*8][tx] = vl[src];
    }
    __syncthreads();
    #pragma unroll
    for (int i = 0; i < 4; i++) {
        const int gc = c0 + ty + i*8;          // global channel
        const int hh = gc >> 6, d = gc & 63;
        const long dst = ((long)(b*HH + hh)*64 + d)*TT + t0 + tx;
        ((unsigned short*)Vth)[dst] = th[tx][ty + i*8];
        ((unsigned short*)Vtl)[dst] = tl[tx][ty + i*8];
    }
}

// ---------------------------------------------------------------------------
// Big-tile bf16x3 split GEMM (QKV): 128Mx128N, BK=32, 4 waves each 64x64.
// MFMA:ds_read = 48:16 per K-step (2x the 64-tile density). Per-output
// accumulation order identical to the 64-tile version -> bit-identical.
// Emits pre-split bf16 hi/lo (EPI=2 semantics).
// ---------------------------------------------------------------------------
__global__ __launch_bounds__(256, 2) void gemm_split_big(
        const __hip_bfloat16* __restrict__ Ah,
        const __hip_bfloat16* __restrict__ Al,
        const __hip_bfloat16* __restrict__ Bh_base,
        const __hip_bfloat16* __restrict__ Bl_base,
        __hip_bfloat16* __restrict__ Ch_base,
        __hip_bfloat16* __restrict__ Cl_base,
        int M, int N, int K) {
    __shared__ __hip_bfloat16 Ash[128][40], Asl[128][40];
    __shared__ __hip_bfloat16 Bsh[128][40], Bsl[128][40];
    const int z = blockIdx.z;
    const __hip_bfloat16* Bth = Bh_base + (long)z * N * K;
    const __hip_bfloat16* Btl = Bl_base + (long)z * N * K;
    const int n0 = blockIdx.x * 128, m0 = blockIdx.y * 128;
    const int tid = threadIdx.x;
    const int wave = tid >> 6, lane = tid & 63;
    const int wm = (wave >> 1) * 64, wn = (wave & 1) * 64;
    const int l15 = lane & 15, quad = lane >> 4;

    f32x4 acc[4][4] = {};

    for (int k0 = 0; k0 < K; k0 += 32) {
        #pragma unroll
        for (int it = 0; it < 2; it++) {
            const int idx = tid + it*256;
            const int r = idx >> 2, kg = (idx & 3) * 8;
            *(short8*)&Ash[r][kg] = *(const short8*)(Ah + (long)(m0 + r)*K + k0 + kg);
            *(short8*)&Asl[r][kg] = *(const short8*)(Al + (long)(m0 + r)*K + k0 + kg);
            *(short8*)&Bsh[r][kg] = *(const short8*)(Bth + (long)(n0 + r)*K + k0 + kg);
            *(short8*)&Bsl[r][kg] = *(const short8*)(Btl + (long)(n0 + r)*K + k0 + kg);
        }
        __syncthreads();
        short8 ah[4], al[4], bh[4], bl[4];
        #pragma unroll
        for (int i = 0; i < 4; i++) {
            ah[i] = *(const short8*)&Ash[wm + i*16 + l15][quad*8];
            al[i] = *(const short8*)&Asl[wm + i*16 + l15][quad*8];
            bh[i] = *(const short8*)&Bsh[wn + i*16 + l15][quad*8];
            bl[i] = *(const short8*)&Bsl[wn + i*16 + l15][quad*8];
        }
        #pragma unroll
        for (int mi = 0; mi < 4; mi++)
            #pragma unroll
            for (int ni = 0; ni < 4; ni++) {
                acc[mi][ni] = __builtin_amdgcn_mfma_f32_16x16x32_bf16(ah[mi], bh[ni], acc[mi][ni], 0,0,0);
                acc[mi][ni] = __builtin_amdgcn_mfma_f32_16x16x32_bf16(ah[mi], bl[ni], acc[mi][ni], 0,0,0);
                acc[mi][ni] = __builtin_amdgcn_mfma_f32_16x16x32_bf16(al[mi], bh[ni], acc[mi][ni], 0,0,0);
            }
        __syncthreads();
    }

    #pragma unroll
    for (int mi = 0; mi < 4; mi++)
        #pragma unroll
        for (int r = 0; r < 4; r++) {
            const int row = m0 + wm + mi*16 + quad*4 + r;
            #pragma unroll
            for (int ni = 0; ni < 4; ni++) {
                const int col = n0 + wn + ni*16 + l15;
                short hh, ll; splitbf(acc[mi][ni][r], hh, ll);
                *(short*)&Ch_base[(long)z*M*N + (long)row*N + col] = hh;
                *(short*)&Cl_base[(long)z*M*N + (long)row*N + col] = ll;
            }
        }
}

// ---------------------------------------------------------------------------
// fp32-accurate MFMA GEMM via bf16x3 split, 64Mx128N tile (WO path: keeps
// grid at 256 blocks for full CU coverage). EPI: 1 = fp32 +resid out.
// ---------------------------------------------------------------------------
__global__ __launch_bounds__(256, 2) void gemm_split(
        const __hip_bfloat16* __restrict__ Ah,
        const __hip_bfloat16* __restrict__ Al,
        const __hip_bfloat16* __restrict__ Bth,
        const __hip_bfloat16* __restrict__ Btl,
        float* __restrict__ Cp,
        int M, int N, int K,
        const float* __restrict__ resid) {
    __shared__ __hip_bfloat16 Ash[64][40], Asl[64][40];
    __shared__ __hip_bfloat16 Bsh[128][40], Bsl[128][40];
    const int n0 = blockIdx.x * 128, m0 = blockIdx.y * 64;
    const int tid = threadIdx.x;
    const int wave = tid >> 6, lane = tid & 63;
    const int wm = (wave >> 1) * 32, wn = (wave & 1) * 64;
    const int l15 = lane & 15, quad = lane >> 4;

    f32x4 acc[2][4] = {};

    for (int k0 = 0; k0 < K; k0 += 32) {
        {   // A tile: 64 rows x 32 k, contiguous short8 per thread
            const int r = tid >> 2, kg = (tid & 3) * 8;
            *(short8*)&Ash[r][kg] = *(const short8*)(Ah + (long)(m0 + r)*K + k0 + kg);
            *(short8*)&Asl[r][kg] = *(const short8*)(Al + (long)(m0 + r)*K + k0 + kg);
        }
        #pragma unroll
        for (int it = 0; it < 2; it++) {   // B tile: 128 rows x 32 k
            const int idx = tid + it*256;
            const int r = idx >> 2, kg = (idx & 3) * 8;
            *(short8*)&Bsh[r][kg] = *(const short8*)(Bth + (long)(n0 + r)*K + k0 + kg);
            *(short8*)&Bsl[r][kg] = *(const short8*)(Btl + (long)(n0 + r)*K + k0 + kg);
        }
        __syncthreads();
        short8 ah[2], al[2], bh[4], bl[4];
        #pragma unroll
        for (int mi = 0; mi < 2; mi++) {
            ah[mi] = *(const short8*)&Ash[wm + mi*16 + l15][quad*8];
            al[mi] = *(const short8*)&Asl[wm + mi*16 + l15][quad*8];
        }
        #pragma unroll
        for (int ni = 0; ni < 4; ni++) {
            bh[ni] = *(const short8*)&Bsh[wn + ni*16 + l15][quad*8];
            bl[ni] = *(const short8*)&Bsl[wn + ni*16 + l15][quad*8];
        }
        #pragma unroll
        for (int mi = 0; mi < 2; mi++)
            #pragma unroll
            for (int ni = 0; ni < 4; ni++) {
                acc[mi][ni] = __builtin_amdgcn_mfma_f32_16x16x32_bf16(ah[mi], bh[ni], acc[mi][ni], 0,0,0);
                acc[mi][ni] = __builtin_amdgcn_mfma_f32_16x16x32_bf16(ah[mi], bl[ni], acc[mi][ni], 0,0,0);
                acc[mi][ni] = __builtin_amdgcn_mfma_f32_16x16x32_bf16(al[mi], bh[ni], acc[mi][ni], 0,0,0);
            }
        __syncthreads();
    }

    #pragma unroll
    for (int mi = 0; mi < 2; mi++)
        #pragma unroll
        for (int r = 0; r < 4; r++) {
            const int row = m0 + wm + mi*16 + quad*4 + r;
            #pragma unroll
            for (int ni = 0; ni < 4; ni++) {
                const int col = n0 + wn + ni*16 + l15;
                Cp[(long)row*N + col] = acc[mi][ni][r] + resid[(long)row*N + col];
            }
        }
}

// ---------------------------------------------------------------------------
// bf16 MFMA GEMM (expert GEMM1): mid[e] = gelu(A @ Bt[e]^T) -> bf16
// ---------------------------------------------------------------------------
__global__ __launch_bounds__(256) void gemm_mfma1(
        const __hip_bfloat16* __restrict__ A,
        const __hip_bfloat16* __restrict__ Bt, long sBe,
        __hip_bfloat16* __restrict__ Cp, long sCe, int ldc,
        int M, int N, int K) {
    constexpr int LDK = 40;
    __shared__ __hip_bfloat16 As[128][LDK];
    __shared__ __hip_bfloat16 Bs[128][LDK];
    const int e = blockIdx.z;
    Bt += (long)e * sBe;
    const int n0 = blockIdx.x * 128, m0 = blockIdx.y * 128;
    const int tid = threadIdx.x;
    const int wave = tid >> 6, lane = tid & 63;
    const int wm = (wave >> 1) * 64, wn = (wave & 1) * 64;
    const int l15 = lane & 15, quad = lane >> 4;

    f32x4 acc[4][4] = {};

    for (int k0 = 0; k0 < K; k0 += 32) {
        #pragma unroll
        for (int it = 0; it < 2; it++) {
            int idx = tid + it*256;
            int r = idx >> 2, kg = idx & 3;
            short8 av = *(const short8*)(A  + (long)(m0 + r)*K + k0 + kg*8);
            short8 bv = *(const short8*)(Bt + (long)(n0 + r)*K + k0 + kg*8);
            *(short8*)&As[r][kg*8] = av;
            *(short8*)&Bs[r][kg*8] = bv;
        }
        __syncthreads();
        short8 af[4], bff[4];
        #pragma unroll
        for (int i = 0; i < 4; i++) {
            af[i]  = *(const short8*)&As[wm + i*16 + l15][quad*8];
            bff[i] = *(const short8*)&Bs[wn + i*16 + l15][quad*8];
        }
        #pragma unroll
        for (int mi = 0; mi < 4; mi++)
            #pragma unroll
            for (int ni = 0; ni < 4; ni++)
                acc[mi][ni] = __builtin_amdgcn_mfma_f32_16x16x32_bf16(
                                  af[mi], bff[ni], acc[mi][ni], 0, 0, 0);
        __syncthreads();
    }

    #pragma unroll
    for (int mi = 0; mi < 4; mi++) {
        #pragma unroll
        for (int r = 0; r < 4; r++) {
            const int row = m0 + wm + mi*16 + quad*4 + r;
            #pragma unroll
            for (int ni = 0; ni < 4; ni++) {
                const int col = n0 + wn + ni*16 + l15;
                float val = acc[mi][ni][r];
                val = 0.5f*val*(1.f + erff(val*0.70710678118f));
                Cp[(long)e*sCe + (long)row*ldc + col] = __float2bfloat16(val);
            }
        }
    }
}

// ---------------------------------------------------------------------------
// Expert GEMM2 fused with sum-over-experts: each block handles 4 experts
// (z = expert-group), writes eo[n,e,:] = (mid[e] @ w2[e]^T) * mask[n,e] and
// atomically adds the masked sum into xio (which holds x + attn residual).
// ---------------------------------------------------------------------------
__global__ __launch_bounds__(256) void gemm_moe2(
        const __hip_bfloat16* __restrict__ mid,   // [16][NN][II]
        const __hip_bfloat16* __restrict__ w2t,   // [16][CC][II]
        float* __restrict__ eo,                   // [NN][EE][CC]
        float* __restrict__ xio,                  // [NN][CC]
        const float* __restrict__ mask) {
    constexpr int LDK = 40;
    __shared__ __hip_bfloat16 As[128][LDK];
    __shared__ __hip_bfloat16 Bs[128][LDK];
    const int e0 = blockIdx.z * 4;
    const int n0 = blockIdx.x * 128, m0 = blockIdx.y * 128;
    const int tid = threadIdx.x;
    const int wave = tid >> 6, lane = tid & 63;
    const int wm = (wave >> 1) * 64, wn = (wave & 1) * 64;
    const int l15 = lane & 15, quad = lane >> 4;

    f32x4 sum[4][4] = {};

    for (int ei = 0; ei < 4; ei++) {
        const int e = e0 + ei;
        const __hip_bfloat16* A  = mid + (long)e*NN*II;
        const __hip_bfloat16* Bt = w2t + (long)e*CC*II;
        f32x4 acc[4][4] = {};
        for (int k0 = 0; k0 < II; k0 += 32) {
            #pragma unroll
            for (int it = 0; it < 2; it++) {
                int idx = tid + it*256;
                int r = idx >> 2, kg = idx & 3;
                short8 av = *(const short8*)(A  + (long)(m0 + r)*II + k0 + kg*8);
                short8 bv = *(const short8*)(Bt + (long)(n0 + r)*II + k0 + kg*8);
                *(short8*)&As[r][kg*8] = av;
                *(short8*)&Bs[r][kg*8] = bv;
            }
            __syncthreads();
            short8 af[4], bff[4];
            #pragma unroll
            for (int i = 0; i < 4; i++) {
                af[i]  = *(const short8*)&As[wm + i*16 + l15][quad*8];
                bff[i] = *(const short8*)&Bs[wn + i*16 + l15][quad*8];
            }
            #pragma unroll
            for (int mi = 0; mi < 4; mi++)
                #pragma unroll
                for (int ni = 0; ni < 4; ni++)
                    acc[mi][ni] = __builtin_amdgcn_mfma_f32_16x16x32_bf16(
                                      af[mi], bff[ni], acc[mi][ni], 0, 0, 0);
            __syncthreads();
        }
        // epilogue for this expert: write eo, accumulate masked sum
        #pragma unroll
        for (int mi = 0; mi < 4; mi++) {
            #pragma unroll
            for (int r = 0; r < 4; r++) {
                const int row = m0 + wm + mi*16 + quad*4 + r;
                const float mv = mask[(long)row*EE + e];
                #pragma unroll
                for (int ni = 0; ni < 4; ni++) {
                    const int col = n0 + wn + ni*16 + l15;
                    const float val = acc[mi][ni][r] * mv;
                    eo[((long)row*EE + e)*CC + col] = val;
                    sum[mi][ni][r] += val;
                }
            }
        }
    }

    // final: add this expert-group's partial sum into xio
    #pragma unroll
    for (int mi = 0; mi < 4; mi++)
        #pragma unroll
        for (int r = 0; r < 4; r++) {
            const int row = m0 + wm + mi*16 + quad*4 + r;
            #pragma unroll
            for (int ni = 0; ni < 4; ni++) {
                const int col = n0 + wn + ni*16 + l15;
                atomicAdd(&xio[(long)row*CC + col], sum[mi][ni][r]);
            }
        }
}

// ---------------------------------------------------------------------------
// Flash attention with bf16x3 MFMA for QK^T and PV. kt-split for balance.
// All inputs PRE-SPLIT bf16 hi/lo; V pre-transposed [(b*H+h)*64+d][T].
// Staging is pure contiguous short8 copies. Online softmax in registers.
// ---------------------------------------------------------------------------
__global__ __launch_bounds__(256, 4) void attn_split(
        const __hip_bfloat16* __restrict__ Qh, const __hip_bfloat16* __restrict__ Ql,
        const __hip_bfloat16* __restrict__ Kh, const __hip_bfloat16* __restrict__ Kl,
        const __hip_bfloat16* __restrict__ Vtg_h, const __hip_bfloat16* __restrict__ Vtg_l,
        float* __restrict__ Opart,
        float* __restrict__ mpart,
        float* __restrict__ lpart) {
    __shared__ __hip_bfloat16 KPh[64][LDA], KPl[64][LDA];   // K, then P
    __shared__ __hip_bfloat16 Vth[64][LDA], Vtl[64][LDA];   // V^T [d][kk]

    const int bx = blockIdx.x;                 // 0..31, heavy qt first
    const int qt = 15 - (bx >> 1), half = bx & 1;
    const int h = blockIdx.y, b = blockIdx.z;
    const int tid = threadIdx.x;
    const int wave = tid >> 6, lane = tid & 63;
    const int l15 = lane & 15, quad = lane >> 4;
    const int wm = wave * 16;                  // wave's 16 q-rows in the 64-tile
    const long tbase = (long)b * TT * CC + (long)h * DD;          // [token][C] slab
    const long vbase = (long)(b*HH + h) * 64 * TT;                // V^T slab
    const int pidx = ((b*HH + h)*16 + qt)*2 + half;
    float* Op = Opart + (long)pidx * 4096;

    const int n_kt = qt + 1, mid_kt = (n_kt + 1) >> 1;
    const int kt_lo = half ? mid_kt : 0;
    const int kt_hi = half ? n_kt   : mid_kt;

    if (kt_lo >= kt_hi) {      // empty half (qt=0): neutral partials
        for (int i = tid; i < 64*64; i += 256) Op[i] = 0.f;
        if (tid < 64) { mpart[(long)pidx*64 + tid] = -1e30f; lpart[(long)pidx*64 + tid] = 0.f; }
        return;
    }

    // Q A-fragments direct from pre-split global
    short8 qh[2], ql[2];
    {
        const long qoff = tbase + (long)(qt*64 + wm + l15)*CC;
        #pragma unroll
        for (int kc = 0; kc < 2; kc++) {
            qh[kc] = *(const short8*)(Qh + qoff + kc*32 + quad*8);
            ql[kc] = *(const short8*)(Ql + qoff + kc*32 + quad*8);
        }
    }

    f32x4 oacc[4] = {};            // 4 d-tiles, rows = quad*4+reg
    float m_run[4], l_run[4];
    #pragma unroll
    for (int r = 0; r < 4; r++) { m_run[r] = -1e30f; l_run[r] = 0.f; }

    for (int kt = kt_lo; kt < kt_hi; kt++) {
        __syncthreads();           // prev-iter PV reads of KP/Vt done
        #pragma unroll
        for (int it = 0; it < 2; it++) {
            const int idx = tid + it*256;
            const int r = idx >> 3, g = (idx & 7)*8;
            const long koff = tbase + (long)(kt*64 + r)*CC + g;
            const long voff = vbase + (long)r*TT + kt*64 + g;
            *(short8*)&KPh[r][g] = *(const short8*)(Kh + koff);
            *(short8*)&KPl[r][g] = *(const short8*)(Kl + koff);
            *(short8*)&Vth[r][g] = *(const short8*)(Vtg_h + voff);
            *(short8*)&Vtl[r][g] = *(const short8*)(Vtg_l + voff);
        }
        __syncthreads();

        // QK^T via MFMA: 4 key-tiles x 2 k-chunks x 3 split terms
        f32x4 s[4] = {};
        #pragma unroll
        for (int nt = 0; nt < 4; nt++)
            #pragma unroll
            for (int kc = 0; kc < 2; kc++) {
                short8 bh = *(const short8*)&KPh[nt*16 + l15][kc*32 + quad*8];
                short8 bl = *(const short8*)&KPl[nt*16 + l15][kc*32 + quad*8];
                s[nt] = __builtin_amdgcn_mfma_f32_16x16x32_bf16(qh[kc], bh, s[nt], 0,0,0);
                s[nt] = __builtin_amdgcn_mfma_f32_16x16x32_bf16(qh[kc], bl, s[nt], 0,0,0);
                s[nt] = __builtin_amdgcn_mfma_f32_16x16x32_bf16(ql[kc], bh, s[nt], 0,0,0);
            }

        // online softmax in regs; row = wm + quad*4 + r, col = nt*16 + l15
        const bool diag = (kt == qt);
        float alpha[4];
        float pr[4][4];
        #pragma unroll
        for (int r = 0; r < 4; r++) {
            const int rowg = wm + quad*4 + r;
            float sv[4], mx = -1e30f;
            #pragma unroll
            for (int nt = 0; nt < 4; nt++) {
                float val = s[nt][r] * 0.125f;
                if (diag && (nt*16 + l15) > rowg) val = -1e30f;
                sv[nt] = val;
                mx = fmaxf(mx, val);
            }
            #pragma unroll
            for (int off = 1; off < 16; off <<= 1) mx = fmaxf(mx, __shfl_xor(mx, off, 16));
            const float mnew = fmaxf(m_run[r], mx);
            alpha[r] = __expf(m_run[r] - mnew);
            float rs = 0.f;
            #pragma unroll
            for (int nt = 0; nt < 4; nt++) {
                float p = __expf(sv[nt] - mnew);
                pr[r][nt] = p;
                rs += p;
            }
            #pragma unroll
            for (int off = 1; off < 16; off <<= 1) rs += __shfl_xor(rs, off, 16);
            l_run[r] = l_run[r]*alpha[r] + rs;
            m_run[r] = mnew;
        }
        __syncthreads();           // all QK reads of KP done -> overwrite as P

        // write P split into KP region: row = wm+quad*4+r, col = nt*16+l15
        #pragma unroll
        for (int r = 0; r < 4; r++)
            #pragma unroll
            for (int nt = 0; nt < 4; nt++) {
                short hh, ll; splitbf(pr[r][nt], hh, ll);
                *(short*)&KPh[wm + quad*4 + r][nt*16 + l15] = hh;
                *(short*)&KPl[wm + quad*4 + r][nt*16 + l15] = ll;
            }
        // no barrier: PV reads only this wave's own 16 P-rows

        // rescale O and accumulate PV via MFMA
        #pragma unroll
        for (int dt = 0; dt < 4; dt++)
            #pragma unroll
            for (int r = 0; r < 4; r++)
                oacc[dt][r] *= alpha[r];
        #pragma unroll
        for (int kc = 0; kc < 2; kc++) {
            short8 ph = *(const short8*)&KPh[wm + l15][kc*32 + quad*8];
            short8 pl = *(const short8*)&KPl[wm + l15][kc*32 + quad*8];
            #pragma unroll
            for (int dt = 0; dt < 4; dt++) {
                short8 vh = *(const short8*)&Vth[dt*16 + l15][kc*32 + quad*8];
                short8 vl = *(const short8*)&Vtl[dt*16 + l15][kc*32 + quad*8];
                oacc[dt] = __builtin_amdgcn_mfma_f32_16x16x32_bf16(ph, vh, oacc[dt], 0,0,0);
                oacc[dt] = __builtin_amdgcn_mfma_f32_16x16x32_bf16(ph, vl, oacc[dt], 0,0,0);
                oacc[dt] = __builtin_amdgcn_mfma_f32_16x16x32_bf16(pl, vh, oacc[dt], 0,0,0);
            }
        }
    }

    // store unnormalized O partial + (m,l)
    #pragma unroll
    for (int dt = 0; dt < 4; dt++)
        #pragma unroll
        for (int r = 0; r < 4; r++)
            Op[(wm + quad*4 + r)*64 + dt*16 + l15] = oacc[dt][r];
    if (l15 == 0) {
        #pragma unroll
        for (int r = 0; r < 4; r++) {
            mpart[(long)pidx*64 + wm + quad*4 + r] = m_run[r];
            lpart[(long)pidx*64 + wm + quad*4 + r] = l_run[r];
        }
    }
}

// ---------------------------------------------------------------------------
// Merge the two kt-half partials -> normalized attention output, emitted as
// pre-split bf16 hi/lo (direct feed for the WO bf16x3 GEMM).
// ---------------------------------------------------------------------------
__global__ __launch_bounds__(256) void attn_merge(const float* __restrict__ Opart,
                                                  const float* __restrict__ mpart,
                                                  const float* __restrict__ lpart,
                                                  __hip_bfloat16* __restrict__ aoh,
                                                  __hip_bfloat16* __restrict__ aol) {
    const int qt = blockIdx.x, h = blockIdx.y, b = blockIdx.z;
    const int pA = ((b*HH + h)*16 + qt)*2, pB = pA + 1;
    const int tid = threadIdx.x;
    const int r = tid >> 2, c0 = (tid & 3) * 16;
    const float mA = mpart[(long)pA*64 + r], mB = mpart[(long)pB*64 + r];
    const float lA = lpart[(long)pA*64 + r], lB = lpart[(long)pB*64 + r];
    const float M  = fmaxf(mA, mB);
    const float wA = __expf(mA - M), wB = __expf(mB - M);
    const float inv = 1.f / (lA*wA + lB*wB);
    const float* OA = Opart + (long)pA*4096 + r*64 + c0;
    const float* OB = Opart + (long)pB*4096 + r*64 + c0;
    const long dst = (long)b*TT*CC + (long)(qt*64 + r)*CC + h*DD + c0;
    #pragma unroll
    for (int j = 0; j < 16; j += 4) {
        float4 oa = *(const float4*)(OA + j);
        float4 ob = *(const float4*)(OB + j);
        float xs[4];
        xs[0] = (oa.x*wA + ob.x*wB)*inv;
        xs[1] = (oa.y*wA + ob.y*wB)*inv;
        xs[2] = (oa.z*wA + ob.z*wB)*inv;
        xs[3] = (oa.w*wA + ob.w*wB)*inv;
        s16x4 hv, lv;
        #pragma unroll
        for (int t = 0; t < 4; t++) { short hh,ll; splitbf(xs[t],hh,ll); hv[t]=hh; lv[t]=ll; }
        *(s16x4*)(aoh + dst + j) = hv;
        *(s16x4*)(aol + dst + j) = lv;
    }
}

// ---------------------------------------------------------------------------
// Column norms of sim_matrix [C, E]
// ---------------------------------------------------------------------------
__global__ __launch_bounds__(256) void colnorm_kernel(const float* __restrict__ sim,
                                                      float* __restrict__ cn) {
    const int e = blockIdx.x, tid = threadIdx.x;
    __shared__ float red[256];
    float s = 0.f;
    for (int c = tid; c < CC; c += 256) {
        float vv = sim[(long)c*EE + e];
        s += vv*vv;
    }
    red[tid] = s; __syncthreads();
    for (int st = 128; st > 0; st >>= 1) {
        if (tid < st) red[tid] += red[tid+st];
        __syncthreads();
    }
    if (tid == 0) cn[e] = sqrtf(red[0]);
}

// ---------------------------------------------------------------------------
extern "C" void kernel_launch(void* const* d_in, const int* in_sizes, int n_in,
                              void* d_out, int out_size, void* d_ws, size_t ws_size,
                              hipStream_t stream) {
    const float* x     = (const float*)d_in[0];
    const float* ln1_g = (const float*)d_in[1];
    const float* ln1_b = (const float*)d_in[2];
    const float* ln2_g = (const float*)d_in[3];
    const float* ln2_b = (const float*)d_in[4];
    const float* wq    = (const float*)d_in[5];
    const float* wk    = (const float*)d_in[6];
    const float* wv    = (const float*)d_in[7];
    const float* wo    = (const float*)d_in[8];
    const float* sim   = (const float*)d_in[9];
    const float* thr   = (const float*)d_in[10];
    const float* w1    = (const float*)d_in[11];
    const float* w2    = (const float*)d_in[12];

    float* out_x      = (float*)d_out;
    float* out_scores = out_x + (long)NN*CC;
    float* out_eo     = out_scores + (long)NN*EE;
    float* out_kpt    = out_eo + (long)NN*EE*CC;

    const long MF = (long)NN*CC;     // 2M floats
    const long CK = (long)CC*CC;     // 1M elems per weight slab
    float* ws   = (float*)d_ws;
    // [0, MF): attn-out split bf16 (hi/lo)
    __hip_bfloat16* aoh = (__hip_bfloat16*)ws;
    __hip_bfloat16* aol = (__hip_bfloat16*)(ws + MF/2);
    // [MF, 4MF): QKV pre-split bf16 (3 slabs hi, 3 slabs lo)
    __hip_bfloat16* qkvh = (__hip_bfloat16*)(ws + MF);
    __hip_bfloat16* qkvl = (__hip_bfloat16*)(ws + MF + 3*MF/2);
    // [4MF, 5MF): V^T pre-split bf16
    __hip_bfloat16* vth = (__hip_bfloat16*)(ws + 4*MF);
    __hip_bfloat16* vtl = (__hip_bfloat16*)(ws + 4*MF + MF/2);
    // [5MF, 5.5MF): LN2 bf16 for expert GEMM
    __hip_bfloat16* h2b = (__hip_bfloat16*)(ws + 5*MF);
    // [5.5MF, 7.5MF): attn partials; hh/hl (LN1 split) + mid alias
    float* Opart = ws + 5*MF + MF/2;
    __hip_bfloat16* hh  = (__hip_bfloat16*)(ws + 5*MF + MF/2);       // dead after QKV GEMM
    __hip_bfloat16* hl  = (__hip_bfloat16*)(ws + 6*MF);
    __hip_bfloat16* mid = (__hip_bfloat16*)(ws + 5*MF + MF/2);       // after merge
    // [7.5MF, 9.5MF): QKVO weight splits; w1t/w2t alias (after WO GEMM)
    __hip_bfloat16* wsph = (__hip_bfloat16*)(ws + 7*MF + MF/2);      // [4][C][C] hi
    __hip_bfloat16* wspl = (__hip_bfloat16*)(ws + 8*MF + MF/2);      // [4][C][C] lo
    __hip_bfloat16* w1t  = (__hip_bfloat16*)(ws + 7*MF + MF/2);
    __hip_bfloat16* w2t  = (__hip_bfloat16*)(ws + 8*MF + MF/2);
    float* maskb = ws + 9*MF + MF/2;                                  // 32K
    float* cn    = maskb + (long)NN*EE;                               // 16
    float* mpart = cn + 16;                                           // 64K
    float* lpart = mpart + 1024L*64;                                  // 64K

    // 0. sim column norms (input-only dependency, schedule first)
    colnorm_kernel<<<EE, 256, 0, stream>>>(sim, cn);

    // 1. one-shot QKVO weight transpose + bf16x3 split (single launch)
    {
        dim3 gt(CC/32, CC/32, 4);
        transpose_split4<<<gt, 256, 0, stream>>>(wq, wk, wv, wo, wsph, wspl);
    }

    // 2. LN1 -> pre-split bf16 hi/lo
    ln_kernel<<<NN, 256, 0, stream>>>(x, ln1_g, ln1_b, hh, hl);

    // 3. fused QKV projection, 128x128 tile -> pre-split bf16 hi/lo outputs
    {
        dim3 gq(CC/128, NN/128, 3);
        gemm_split_big<<<gq, 256, 0, stream>>>(hh, hl, wsph, wspl,
                                               qkvh, qkvl, NN, CC, CC);
    }

    // 3.5 V transpose (bf16 hi/lo): [token][C] -> per-(b,h) [d][T]
    {
        dim3 gv(TT/32, CC/32, BB);
        transpose_v_bf16<<<gv, 256, 0, stream>>>(qkvh + 2*(long)NN*CC, qkvl + 2*(long)NN*CC,
                                                 vth, vtl);
    }

    // 4. causal attention (MFMA flash, kt-split, pre-split inputs) + merge
    {
        dim3 gattn(32, HH, BB);
        attn_split<<<gattn, 256, 0, stream>>>(qkvh, qkvl,
                                              qkvh + (long)NN*CC, qkvl + (long)NN*CC,
                                              vth, vtl, Opart, mpart, lpart);
        dim3 gmerge(16, HH, BB);
        attn_merge<<<gmerge, 256, 0, stream>>>(Opart, mpart, lpart, aoh, aol);
    }

    // 5. output projection + residual -> d_out x slot (64x128 tile: 256 blocks)
    {
        dim3 go(CC/128, NN/64, 1);
        gemm_split<<<go, 256, 0, stream>>>(aoh, aol, wsph + 3*CK, wspl + 3*CK,
                                           out_x, NN, CC, CC, x);
    }

    // 6. expert weight transposes (single launch; safe to overwrite QKVO splits)
    {
        dim3 ge(256, 1, 2*EE);
        transpose_f2b_both<<<ge, 256, 0, stream>>>(w1, w2, w1t, w2t);
    }

    // 7. fused LN2 + router
    ln2_router<<<NN, 256, 0, stream>>>(out_x, ln2_g, ln2_b, sim, cn, thr,
                                       h2b, out_scores, out_kpt, maskb);

    // 8. expert GEMM 1: mid[e] = gelu(h2 @ w1[e]) -> bf16
    {
        dim3 g(II/128, NN/128, EE);
        gemm_mfma1<<<g, 256, 0, stream>>>(h2b, w1t, (long)II*CC,
                                          mid, (long)NN*II, II,
                                          NN, II, CC);
    }

    // 9. expert GEMM 2 fused with sum: eo + (x += sum_e eo)
    {
        dim3 g(CC/128, NN/128, EE/4);
        gemm_moe2<<<g, 256, 0, stream>>>(mid, w2t, out_eo, out_x, maskb);
    }
}

// Round 6
// 469.990 us; speedup vs baseline: 1.0340x; 1.0291x over previous
//
#include <hip/hip_runtime.h>
#include <hip/hip_bf16.h>
#include <math.h>

// Problem constants
#define BB 2
#define TT 1024
#define CC 1024
#define HH 16
#define DD 64
#define EE 16
#define II 256
#define NN (BB*TT)          // 2048 tokens
#define EPSLN 1e-5f
#define LDA 72              // bf16 LDS row stride: 144B rows, 16B-aligned

typedef __attribute__((ext_vector_type(8))) short short8;
typedef __attribute__((ext_vector_type(4))) short s16x4;
typedef __attribute__((ext_vector_type(4))) float f32x4;

__device__ inline void splitbf(float x, short& hi, short& lo) {
    __hip_bfloat16 h = __float2bfloat16(x);
    float hf = __bfloat162float(h);
    __hip_bfloat16 l = __float2bfloat16(x - hf);
    hi = *(short*)&h;
    lo = *(short*)&l;
}

// ---------------------------------------------------------------------------
// LayerNorm (LN1): one block per row. Emits pre-split bf16 hi/lo.
// ---------------------------------------------------------------------------
__global__ __launch_bounds__(256) void ln_kernel(const float* __restrict__ x,
                                                 const float* __restrict__ g,
                                                 const float* __restrict__ bta,
                                                 __hip_bfloat16* __restrict__ outh,
                                                 __hip_bfloat16* __restrict__ outl) {
    const int row = blockIdx.x, tid = threadIdx.x;
    __shared__ float r1[256], r2[256];
    const float* xr = x + (long)row * CC;
    float4 xv = ((const float4*)xr)[tid];
    float s  = xv.x + xv.y + xv.z + xv.w;
    float q2 = xv.x*xv.x + xv.y*xv.y + xv.z*xv.z + xv.w*xv.w;
    r1[tid] = s; r2[tid] = q2; __syncthreads();
    for (int st = 128; st > 0; st >>= 1) {
        if (tid < st) { r1[tid] += r1[tid+st]; r2[tid] += r2[tid+st]; }
        __syncthreads();
    }
    const float mu  = r1[0] * (1.f/CC);
    const float var = r2[0] * (1.f/CC) - mu*mu;
    const float rs  = rsqrtf(var + EPSLN);
    float4 gv = ((const float4*)g)[tid];
    float4 bv = ((const float4*)bta)[tid];
    float xs[4];
    xs[0] = (xv.x-mu)*rs*gv.x + bv.x;
    xs[1] = (xv.y-mu)*rs*gv.y + bv.y;
    xs[2] = (xv.z-mu)*rs*gv.z + bv.z;
    xs[3] = (xv.w-mu)*rs*gv.w + bv.w;
    s16x4 hv, lv;
    #pragma unroll
    for (int j = 0; j < 4; j++) { short h,l; splitbf(xs[j], h, l); hv[j]=h; lv[j]=l; }
    *(s16x4*)(outh + (long)row * CC + tid*4) = hv;
    *(s16x4*)(outl + (long)row * CC + tid*4) = lv;
}

// ---------------------------------------------------------------------------
// Fused LN2 + router: LN -> h2b bf16; scores/mask/k_per_token; and per-expert
// active-token compaction lists (order-free: values don't depend on order).
// ---------------------------------------------------------------------------
__global__ __launch_bounds__(256) void ln2_router(const float* __restrict__ xio,
                                                  const float* __restrict__ g,
                                                  const float* __restrict__ bta,
                                                  const float* __restrict__ sim,
                                                  const float* __restrict__ cn,
                                                  const float* __restrict__ thr,
                                                  __hip_bfloat16* __restrict__ h2b,
                                                  float* __restrict__ scores,
                                                  float* __restrict__ kpt,
                                                  float* __restrict__ maskb,
                                                  int* __restrict__ cnt,
                                                  int* __restrict__ elist) {
    const int row = blockIdx.x, tid = threadIdx.x;
    __shared__ float r1[256], r2[256];
    __shared__ float red[256*17];
    float4 xv = ((const float4*)(xio + (long)row*CC))[tid];
    float s  = xv.x + xv.y + xv.z + xv.w;
    float q2 = xv.x*xv.x + xv.y*xv.y + xv.z*xv.z + xv.w*xv.w;
    r1[tid] = s; r2[tid] = q2; __syncthreads();
    for (int st = 128; st > 0; st >>= 1) {
        if (tid < st) { r1[tid] += r1[tid+st]; r2[tid] += r2[tid+st]; }
        __syncthreads();
    }
    const float mu  = r1[0] * (1.f/CC);
    const float var = r2[0] * (1.f/CC) - mu*mu;
    const float rs  = rsqrtf(var + EPSLN);
    float4 gv = ((const float4*)g)[tid];
    float4 bv = ((const float4*)bta)[tid];
    float ovs[4];
    ovs[0] = (xv.x-mu)*rs*gv.x + bv.x;
    ovs[1] = (xv.y-mu)*rs*gv.y + bv.y;
    ovs[2] = (xv.z-mu)*rs*gv.z + bv.z;
    ovs[3] = (xv.w-mu)*rs*gv.w + bv.w;
    {
        __hip_bfloat16* p = h2b + (long)row*CC + tid*4;
        p[0] = __float2bfloat16(ovs[0]); p[1] = __float2bfloat16(ovs[1]);
        p[2] = __float2bfloat16(ovs[2]); p[3] = __float2bfloat16(ovs[3]);
    }
    // router: this thread's 4 contiguous channels
    float acc[17] = {};
    #pragma unroll
    for (int j = 0; j < 4; j++) {
        const float v = ovs[j];
        acc[16] += v*v;
        const float* sr = sim + (long)(tid*4 + j)*EE;
        #pragma unroll
        for (int e2 = 0; e2 < EE; e2++) acc[e2] += v*sr[e2];
    }
    #pragma unroll
    for (int e2 = 0; e2 < 17; e2++) red[tid*17 + e2] = acc[e2];
    __syncthreads();
    for (int st = 128; st > 0; st >>= 1) {
        if (tid < st)
            for (int e2 = 0; e2 < 17; e2++) red[tid*17+e2] += red[(tid+st)*17+e2];
        __syncthreads();
    }
    if (tid < EE) {
        const float nrm = sqrtf(red[16]);
        const float sc  = red[tid] / (nrm * cn[tid]);
        scores[(long)row*EE + tid] = sc;
        const float mkv = sc > thr[0] ? 1.f : 0.f;
        maskb[(long)row*EE + tid] = mkv;
        red[tid] = mkv;
        if (mkv > 0.f) {
            int slot = atomicAdd(&cnt[tid], 1);
            elist[(long)tid*NN + slot] = row;
        }
    }
    __syncthreads();
    if (tid == 0) {
        float c2 = 0.f;
        for (int e2 = 0; e2 < EE; e2++) c2 += red[e2];
        kpt[row] = c2;
    }
}

// ---------------------------------------------------------------------------
// One-shot QKVO weight prep (single launch, z selects weight):
// W[K][N] fp32 -> Wt[N][K] bf16 hi + lo (bf16x3 split).
// ---------------------------------------------------------------------------
__global__ __launch_bounds__(256) void transpose_split4(const float* __restrict__ W0,
                                                        const float* __restrict__ W1,
                                                        const float* __restrict__ W2,
                                                        const float* __restrict__ W3,
                                                        __hip_bfloat16* __restrict__ Wth_base,
                                                        __hip_bfloat16* __restrict__ Wtl_base) {
    const int z = blockIdx.z;
    const float* W = (z==0) ? W0 : (z==1) ? W1 : (z==2) ? W2 : W3;
    __hip_bfloat16* Wth = Wth_base + (long)z*CC*CC;
    __hip_bfloat16* Wtl = Wtl_base + (long)z*CC*CC;
    const int n0 = blockIdx.x * 32, k0 = blockIdx.y * 32;
    __shared__ float t[32][33];
    const int tx = threadIdx.x & 31, ty = threadIdx.x >> 5;
    #pragma unroll
    for (int i = 0; i < 4; i++)
        t[ty + i*8][tx] = W[(long)(k0 + ty + i*8)*CC + n0 + tx];
    __syncthreads();
    #pragma unroll
    for (int i = 0; i < 4; i++) {
        float v = t[tx][ty + i*8];
        short h, l; splitbf(v, h, l);
        *(short*)&Wth[(long)(n0 + ty + i*8)*CC + k0 + tx] = h;
        *(short*)&Wtl[(long)(n0 + ty + i*8)*CC + k0 + tx] = l;
    }
}

// ---------------------------------------------------------------------------
// Expert weight prep (single launch): z = half*16 + e. half0: w1 [C][I] ->
// w1t [I][C]; half1: w2 [I][C] -> w2t [C][I]. Flattened grid.x = 256 blocks/e.
// ---------------------------------------------------------------------------
__global__ __launch_bounds__(256) void transpose_f2b_both(const float* __restrict__ w1,
                                                          const float* __restrict__ w2,
                                                          __hip_bfloat16* __restrict__ w1t,
                                                          __hip_bfloat16* __restrict__ w2t) {
    const int zz = blockIdx.z;
    const int half = zz >> 4, e = zz & 15;
    const float* W; __hip_bfloat16* Wt; int K, N, nbx;
    if (half == 0) { W = w1 + (long)e*CC*II; Wt = w1t + (long)e*CC*II; K = CC; N = II; nbx = II/32; }
    else           { W = w2 + (long)e*II*CC; Wt = w2t + (long)e*II*CC; K = II; N = CC; nbx = CC/32; }
    const int bx = blockIdx.x;
    const int n0 = (bx % nbx) * 32, k0 = (bx / nbx) * 32;
    __shared__ float t[32][33];
    const int tx = threadIdx.x & 31, ty = threadIdx.x >> 5;
    #pragma unroll
    for (int i = 0; i < 4; i++)
        t[ty + i*8][tx] = W[(long)(k0 + ty + i*8)*N + n0 + tx];
    __syncthreads();
    #pragma unroll
    for (int i = 0; i < 4; i++)
        Wt[(long)(n0 + ty + i*8)*K + k0 + tx] = __float2bfloat16(t[tx][ty + i*8]);
}

// ---------------------------------------------------------------------------
// bf16 transpose for V: [b*T + t][C] (hi/lo) -> [(b*H + h)*64 + d][T] (hi/lo)
// ---------------------------------------------------------------------------
__global__ __launch_bounds__(256) void transpose_v_bf16(
        const __hip_bfloat16* __restrict__ Vh, const __hip_bfloat16* __restrict__ Vl,
        __hip_bfloat16* __restrict__ Vth, __hip_bfloat16* __restrict__ Vtl) {
    const int b = blockIdx.z;
    const int c0 = blockIdx.y * 32, t0 = blockIdx.x * 32;
    __shared__ unsigned short th[32][33], tl[32][33];
    const int tx = threadIdx.x & 31, ty = threadIdx.x >> 5;
    const unsigned short* vh = (const unsigned short*)Vh;
    const unsigned short* vl = (const unsigned short*)Vl;
    #pragma unroll
    for (int i = 0; i < 4; i++) {
        const long src = ((long)b*TT + t0 + ty + i*8)*CC + c0 + tx;
        th[ty + i*8][tx] = vh[src];
        tl[ty + i*8][tx] = vl[src];
    }
    __syncthreads();
    #pragma unroll
    for (int i = 0; i < 4; i++) {
        const int gc = c0 + ty + i*8;          // global channel
        const int hh = gc >> 6, d = gc & 63;
        const long dst = ((long)(b*HH + hh)*64 + d)*TT + t0 + tx;
        ((unsigned short*)Vth)[dst] = th[tx][ty + i*8];
        ((unsigned short*)Vtl)[dst] = tl[tx][ty + i*8];
    }
}

// ---------------------------------------------------------------------------
// Big-tile bf16x3 split GEMM (QKV): 128Mx128N, BK=32, 4 waves each 64x64.
// Emits pre-split bf16 hi/lo.
// ---------------------------------------------------------------------------
__global__ __launch_bounds__(256, 2) void gemm_split_big(
        const __hip_bfloat16* __restrict__ Ah,
        const __hip_bfloat16* __restrict__ Al,
        const __hip_bfloat16* __restrict__ Bh_base,
        const __hip_bfloat16* __restrict__ Bl_base,
        __hip_bfloat16* __restrict__ Ch_base,
        __hip_bfloat16* __restrict__ Cl_base,
        int M, int N, int K) {
    __shared__ __hip_bfloat16 Ash[128][40], Asl[128][40];
    __shared__ __hip_bfloat16 Bsh[128][40], Bsl[128][40];
    const int z = blockIdx.z;
    const __hip_bfloat16* Bth = Bh_base + (long)z * N * K;
    const __hip_bfloat16* Btl = Bl_base + (long)z * N * K;
    const int n0 = blockIdx.x * 128, m0 = blockIdx.y * 128;
    const int tid = threadIdx.x;
    const int wave = tid >> 6, lane = tid & 63;
    const int wm = (wave >> 1) * 64, wn = (wave & 1) * 64;
    const int l15 = lane & 15, quad = lane >> 4;

    f32x4 acc[4][4] = {};

    for (int k0 = 0; k0 < K; k0 += 32) {
        #pragma unroll
        for (int it = 0; it < 2; it++) {
            const int idx = tid + it*256;
            const int r = idx >> 2, kg = (idx & 3) * 8;
            *(short8*)&Ash[r][kg] = *(const short8*)(Ah + (long)(m0 + r)*K + k0 + kg);
            *(short8*)&Asl[r][kg] = *(const short8*)(Al + (long)(m0 + r)*K + k0 + kg);
            *(short8*)&Bsh[r][kg] = *(const short8*)(Bth + (long)(n0 + r)*K + k0 + kg);
            *(short8*)&Bsl[r][kg] = *(const short8*)(Btl + (long)(n0 + r)*K + k0 + kg);
        }
        __syncthreads();
        short8 ah[4], al[4], bh[4], bl[4];
        #pragma unroll
        for (int i = 0; i < 4; i++) {
            ah[i] = *(const short8*)&Ash[wm + i*16 + l15][quad*8];
            al[i] = *(const short8*)&Asl[wm + i*16 + l15][quad*8];
            bh[i] = *(const short8*)&Bsh[wn + i*16 + l15][quad*8];
            bl[i] = *(const short8*)&Bsl[wn + i*16 + l15][quad*8];
        }
        #pragma unroll
        for (int mi = 0; mi < 4; mi++)
            #pragma unroll
            for (int ni = 0; ni < 4; ni++) {
                acc[mi][ni] = __builtin_amdgcn_mfma_f32_16x16x32_bf16(ah[mi], bh[ni], acc[mi][ni], 0,0,0);
                acc[mi][ni] = __builtin_amdgcn_mfma_f32_16x16x32_bf16(ah[mi], bl[ni], acc[mi][ni], 0,0,0);
                acc[mi][ni] = __builtin_amdgcn_mfma_f32_16x16x32_bf16(al[mi], bh[ni], acc[mi][ni], 0,0,0);
            }
        __syncthreads();
    }

    #pragma unroll
    for (int mi = 0; mi < 4; mi++)
        #pragma unroll
        for (int r = 0; r < 4; r++) {
            const int row = m0 + wm + mi*16 + quad*4 + r;
            #pragma unroll
            for (int ni = 0; ni < 4; ni++) {
                const int col = n0 + wn + ni*16 + l15;
                short hh, ll; splitbf(acc[mi][ni][r], hh, ll);
                *(short*)&Ch_base[(long)z*M*N + (long)row*N + col] = hh;
                *(short*)&Cl_base[(long)z*M*N + (long)row*N + col] = ll;
            }
        }
}

// ---------------------------------------------------------------------------
// fp32-accurate MFMA GEMM via bf16x3 split, 64Mx128N tile (WO path).
// ---------------------------------------------------------------------------
__global__ __launch_bounds__(256, 2) void gemm_split(
        const __hip_bfloat16* __restrict__ Ah,
        const __hip_bfloat16* __restrict__ Al,
        const __hip_bfloat16* __restrict__ Bth,
        const __hip_bfloat16* __restrict__ Btl,
        float* __restrict__ Cp,
        int M, int N, int K,
        const float* __restrict__ resid) {
    __shared__ __hip_bfloat16 Ash[64][40], Asl[64][40];
    __shared__ __hip_bfloat16 Bsh[128][40], Bsl[128][40];
    const int n0 = blockIdx.x * 128, m0 = blockIdx.y * 64;
    const int tid = threadIdx.x;
    const int wave = tid >> 6, lane = tid & 63;
    const int wm = (wave >> 1) * 32, wn = (wave & 1) * 64;
    const int l15 = lane & 15, quad = lane >> 4;

    f32x4 acc[2][4] = {};

    for (int k0 = 0; k0 < K; k0 += 32) {
        {   // A tile: 64 rows x 32 k, contiguous short8 per thread
            const int r = tid >> 2, kg = (tid & 3) * 8;
            *(short8*)&Ash[r][kg] = *(const short8*)(Ah + (long)(m0 + r)*K + k0 + kg);
            *(short8*)&Asl[r][kg] = *(const short8*)(Al + (long)(m0 + r)*K + k0 + kg);
        }
        #pragma unroll
        for (int it = 0; it < 2; it++) {   // B tile: 128 rows x 32 k
            const int idx = tid + it*256;
            const int r = idx >> 2, kg = (idx & 3) * 8;
            *(short8*)&Bsh[r][kg] = *(const short8*)(Bth + (long)(n0 + r)*K + k0 + kg);
            *(short8*)&Bsl[r][kg] = *(const short8*)(Btl + (long)(n0 + r)*K + k0 + kg);
        }
        __syncthreads();
        short8 ah[2], al[2], bh[4], bl[4];
        #pragma unroll
        for (int mi = 0; mi < 2; mi++) {
            ah[mi] = *(const short8*)&Ash[wm + mi*16 + l15][quad*8];
            al[mi] = *(const short8*)&Asl[wm + mi*16 + l15][quad*8];
        }
        #pragma unroll
        for (int ni = 0; ni < 4; ni++) {
            bh[ni] = *(const short8*)&Bsh[wn + ni*16 + l15][quad*8];
            bl[ni] = *(const short8*)&Bsl[wn + ni*16 + l15][quad*8];
        }
        #pragma unroll
        for (int mi = 0; mi < 2; mi++)
            #pragma unroll
            for (int ni = 0; ni < 4; ni++) {
                acc[mi][ni] = __builtin_amdgcn_mfma_f32_16x16x32_bf16(ah[mi], bh[ni], acc[mi][ni], 0,0,0);
                acc[mi][ni] = __builtin_amdgcn_mfma_f32_16x16x32_bf16(ah[mi], bl[ni], acc[mi][ni], 0,0,0);
                acc[mi][ni] = __builtin_amdgcn_mfma_f32_16x16x32_bf16(al[mi], bh[ni], acc[mi][ni], 0,0,0);
            }
        __syncthreads();
    }

    #pragma unroll
    for (int mi = 0; mi < 2; mi++)
        #pragma unroll
        for (int r = 0; r < 4; r++) {
            const int row = m0 + wm + mi*16 + quad*4 + r;
            #pragma unroll
            for (int ni = 0; ni < 4; ni++) {
                const int col = n0 + wn + ni*16 + l15;
                Cp[(long)row*N + col] = acc[mi][ni][r] + resid[(long)row*N + col];
            }
        }
}

// ---------------------------------------------------------------------------
// Sparse expert GEMM1: mid[e][slot] = gelu(h2b[tok(slot)] @ w1t[e]^T), bf16.
// M = compacted active tokens of expert e; blocks beyond cnt[e] exit.
// ---------------------------------------------------------------------------
__global__ __launch_bounds__(256) void gemm_moe1_sparse(
        const __hip_bfloat16* __restrict__ A,      // h2b [NN][CC]
        const __hip_bfloat16* __restrict__ w1t,    // [16][II][CC]
        __hip_bfloat16* __restrict__ mid,          // [16][NN][II] compacted
        const int* __restrict__ cnt,
        const int* __restrict__ elist) {
    constexpr int LDK = 40;
    __shared__ __hip_bfloat16 As[128][LDK];
    __shared__ __hip_bfloat16 Bs[128][LDK];
    __shared__ int rowmap[128];
    const int e = blockIdx.z;
    const int count = cnt[e];
    const int m0 = blockIdx.y * 128;
    if (m0 >= count) return;
    const int n0 = blockIdx.x * 128;
    const __hip_bfloat16* Bt = w1t + (long)e*II*CC;
    const int* lst = elist + (long)e*NN;
    const int tid = threadIdx.x;
    if (tid < 128) rowmap[tid] = lst[min(m0 + tid, count - 1)];
    __syncthreads();
    const int wave = tid >> 6, lane = tid & 63;
    const int wm = (wave >> 1) * 64, wn = (wave & 1) * 64;
    const int l15 = lane & 15, quad = lane >> 4;

    f32x4 acc[4][4] = {};

    for (int k0 = 0; k0 < CC; k0 += 32) {
        #pragma unroll
        for (int it = 0; it < 2; it++) {
            int idx = tid + it*256;
            int r = idx >> 2, kg = idx & 3;
            short8 av = *(const short8*)(A  + (long)rowmap[r]*CC + k0 + kg*8);
            short8 bv = *(const short8*)(Bt + (long)(n0 + r)*CC + k0 + kg*8);
            *(short8*)&As[r][kg*8] = av;
            *(short8*)&Bs[r][kg*8] = bv;
        }
        __syncthreads();
        short8 af[4], bff[4];
        #pragma unroll
        for (int i = 0; i < 4; i++) {
            af[i]  = *(const short8*)&As[wm + i*16 + l15][quad*8];
            bff[i] = *(const short8*)&Bs[wn + i*16 + l15][quad*8];
        }
        #pragma unroll
        for (int mi = 0; mi < 4; mi++)
            #pragma unroll
            for (int ni = 0; ni < 4; ni++)
                acc[mi][ni] = __builtin_amdgcn_mfma_f32_16x16x32_bf16(
                                  af[mi], bff[ni], acc[mi][ni], 0, 0, 0);
        __syncthreads();
    }

    #pragma unroll
    for (int mi = 0; mi < 4; mi++) {
        #pragma unroll
        for (int r = 0; r < 4; r++) {
            const int slot = m0 + wm + mi*16 + quad*4 + r;
            if (slot < count) {
                #pragma unroll
                for (int ni = 0; ni < 4; ni++) {
                    const int col = n0 + wn + ni*16 + l15;
                    float val = acc[mi][ni][r];
                    val = 0.5f*val*(1.f + erff(val*0.70710678118f));
                    mid[((long)e*NN + slot)*II + col] = __float2bfloat16(val);
                }
            }
        }
    }
}

// ---------------------------------------------------------------------------
// Sparse expert GEMM2: eo[tok(slot), e, :] = mid[e][slot] @ w2t[e]^T
// (mask == 1 on active slots by construction; no atomics).
// ---------------------------------------------------------------------------
__global__ __launch_bounds__(256) void gemm_moe2_sparse(
        const __hip_bfloat16* __restrict__ mid,    // [16][NN][II] compacted
        const __hip_bfloat16* __restrict__ w2t,    // [16][CC][II]
        float* __restrict__ eo,                    // [NN][EE][CC]
        const int* __restrict__ cnt,
        const int* __restrict__ elist) {
    constexpr int LDK = 40;
    __shared__ __hip_bfloat16 As[128][LDK];
    __shared__ __hip_bfloat16 Bs[128][LDK];
    __shared__ int rowmap[128];
    const int e = blockIdx.z;
    const int count = cnt[e];
    const int m0 = blockIdx.y * 128;
    if (m0 >= count) return;
    const int n0 = blockIdx.x * 128;
    const __hip_bfloat16* A  = mid + (long)e*NN*II;
    const __hip_bfloat16* Bt = w2t + (long)e*CC*II;
    const int* lst = elist + (long)e*NN;
    const int tid = threadIdx.x;
    if (tid < 128) rowmap[tid] = lst[min(m0 + tid, count - 1)];
    __syncthreads();
    const int wave = tid >> 6, lane = tid & 63;
    const int wm = (wave >> 1) * 64, wn = (wave & 1) * 64;
    const int l15 = lane & 15, quad = lane >> 4;

    f32x4 acc[4][4] = {};

    for (int k0 = 0; k0 < II; k0 += 32) {
        #pragma unroll
        for (int it = 0; it < 2; it++) {
            int idx = tid + it*256;
            int r = idx >> 2, kg = idx & 3;
            short8 av = *(const short8*)(A  + (long)(m0 + r)*II + k0 + kg*8);
            short8 bv = *(const short8*)(Bt + (long)(n0 + r)*II + k0 + kg*8);
            *(short8*)&As[r][kg*8] = av;
            *(short8*)&Bs[r][kg*8] = bv;
        }
        __syncthreads();
        short8 af[4], bff[4];
        #pragma unroll
        for (int i = 0; i < 4; i++) {
            af[i]  = *(const short8*)&As[wm + i*16 + l15][quad*8];
            bff[i] = *(const short8*)&Bs[wn + i*16 + l15][quad*8];
        }
        #pragma unroll
        for (int mi = 0; mi < 4; mi++)
            #pragma unroll
            for (int ni = 0; ni < 4; ni++)
                acc[mi][ni] = __builtin_amdgcn_mfma_f32_16x16x32_bf16(
                                  af[mi], bff[ni], acc[mi][ni], 0, 0, 0);
        __syncthreads();
    }

    #pragma unroll
    for (int mi = 0; mi < 4; mi++) {
        #pragma unroll
        for (int r = 0; r < 4; r++) {
            const int slot = m0 + wm + mi*16 + quad*4 + r;
            if (slot < count) {
                const int tok = rowmap[wm + mi*16 + quad*4 + r];
                #pragma unroll
                for (int ni = 0; ni < 4; ni++) {
                    const int col = n0 + wn + ni*16 + l15;
                    eo[((long)tok*EE + e)*CC + col] = acc[mi][ni][r];
                }
            }
        }
    }
}

// ---------------------------------------------------------------------------
// Zero-fill eo rows for inactive (token, expert) pairs.
// ---------------------------------------------------------------------------
__global__ __launch_bounds__(256) void eo_zero(const float* __restrict__ maskb,
                                               float* __restrict__ eo) {
    const int row = blockIdx.x, tid = threadIdx.x;
    const float4 z4 = {0.f, 0.f, 0.f, 0.f};
    #pragma unroll
    for (int e = 0; e < EE; e++) {
        if (maskb[(long)row*EE + e] == 0.f)
            ((float4*)(eo + ((long)row*EE + e)*CC))[tid] = z4;
    }
}

// ---------------------------------------------------------------------------
// final[n,:] = sum over active e of eo[n,e,:]; xio += final. Deterministic
// e-ascending order (skipping exact zeros is bitwise-identical).
// ---------------------------------------------------------------------------
__global__ __launch_bounds__(256) void moe_sum_masked(const float* __restrict__ maskb,
                                                      const float* __restrict__ eo,
                                                      float* __restrict__ xio) {
    const int row = blockIdx.x, tid = threadIdx.x;
    float4 s = {0.f, 0.f, 0.f, 0.f};
    #pragma unroll
    for (int e = 0; e < EE; e++) {
        if (maskb[(long)row*EE + e] != 0.f) {
            float4 v = ((const float4*)(eo + ((long)row*EE + e)*CC))[tid];
            s.x += v.x; s.y += v.y; s.z += v.z; s.w += v.w;
        }
    }
    float4 xv = ((float4*)(xio + (long)row*CC))[tid];
    xv.x += s.x; xv.y += s.y; xv.z += s.z; xv.w += s.w;
    ((float4*)(xio + (long)row*CC))[tid] = xv;
}

// ---------------------------------------------------------------------------
// Flash attention with bf16x3 MFMA for QK^T and PV. kt-split for balance.
// All inputs PRE-SPLIT bf16 hi/lo; V pre-transposed [(b*H+h)*64+d][T].
// ---------------------------------------------------------------------------
__global__ __launch_bounds__(256, 4) void attn_split(
        const __hip_bfloat16* __restrict__ Qh, const __hip_bfloat16* __restrict__ Ql,
        const __hip_bfloat16* __restrict__ Kh, const __hip_bfloat16* __restrict__ Kl,
        const __hip_bfloat16* __restrict__ Vtg_h, const __hip_bfloat16* __restrict__ Vtg_l,
        float* __restrict__ Opart,
        float* __restrict__ mpart,
        float* __restrict__ lpart) {
    __shared__ __hip_bfloat16 KPh[64][LDA], KPl[64][LDA];   // K, then P
    __shared__ __hip_bfloat16 Vth[64][LDA], Vtl[64][LDA];   // V^T [d][kk]

    const int bx = blockIdx.x;                 // 0..31, heavy qt first
    const int qt = 15 - (bx >> 1), half = bx & 1;
    const int h = blockIdx.y, b = blockIdx.z;
    const int tid = threadIdx.x;
    const int wave = tid >> 6, lane = tid & 63;
    const int l15 = lane & 15, quad = lane >> 4;
    const int wm = wave * 16;                  // wave's 16 q-rows in the 64-tile
    const long tbase = (long)b * TT * CC + (long)h * DD;          // [token][C] slab
    const long vbase = (long)(b*HH + h) * 64 * TT;                // V^T slab
    const int pidx = ((b*HH + h)*16 + qt)*2 + half;
    float* Op = Opart + (long)pidx * 4096;

    const int n_kt = qt + 1, mid_kt = (n_kt + 1) >> 1;
    const int kt_lo = half ? mid_kt : 0;
    const int kt_hi = half ? n_kt   : mid_kt;

    if (kt_lo >= kt_hi) {      // empty half (qt=0): neutral partials
        for (int i = tid; i < 64*64; i += 256) Op[i] = 0.f;
        if (tid < 64) { mpart[(long)pidx*64 + tid] = -1e30f; lpart[(long)pidx*64 + tid] = 0.f; }
        return;
    }

    // Q A-fragments direct from pre-split global
    short8 qh[2], ql[2];
    {
        const long qoff = tbase + (long)(qt*64 + wm + l15)*CC;
        #pragma unroll
        for (int kc = 0; kc < 2; kc++) {
            qh[kc] = *(const short8*)(Qh + qoff + kc*32 + quad*8);
            ql[kc] = *(const short8*)(Ql + qoff + kc*32 + quad*8);
        }
    }

    f32x4 oacc[4] = {};            // 4 d-tiles, rows = quad*4+reg
    float m_run[4], l_run[4];
    #pragma unroll
    for (int r = 0; r < 4; r++) { m_run[r] = -1e30f; l_run[r] = 0.f; }

    for (int kt = kt_lo; kt < kt_hi; kt++) {
        __syncthreads();           // prev-iter PV reads of KP/Vt done
        #pragma unroll
        for (int it = 0; it < 2; it++) {
            const int idx = tid + it*256;
            const int r = idx >> 3, g = (idx & 7)*8;
            const long koff = tbase + (long)(kt*64 + r)*CC + g;
            const long voff = vbase + (long)r*TT + kt*64 + g;
            *(short8*)&KPh[r][g] = *(const short8*)(Kh + koff);
            *(short8*)&KPl[r][g] = *(const short8*)(Kl + koff);
            *(short8*)&Vth[r][g] = *(const short8*)(Vtg_h + voff);
            *(short8*)&Vtl[r][g] = *(const short8*)(Vtg_l + voff);
        }
        __syncthreads();

        // QK^T via MFMA: 4 key-tiles x 2 k-chunks x 3 split terms
        f32x4 s[4] = {};
        #pragma unroll
        for (int nt = 0; nt < 4; nt++)
            #pragma unroll
            for (int kc = 0; kc < 2; kc++) {
                short8 bh = *(const short8*)&KPh[nt*16 + l15][kc*32 + quad*8];
                short8 bl = *(const short8*)&KPl[nt*16 + l15][kc*32 + quad*8];
                s[nt] = __builtin_amdgcn_mfma_f32_16x16x32_bf16(qh[kc], bh, s[nt], 0,0,0);
                s[nt] = __builtin_amdgcn_mfma_f32_16x16x32_bf16(qh[kc], bl, s[nt], 0,0,0);
                s[nt] = __builtin_amdgcn_mfma_f32_16x16x32_bf16(ql[kc], bh, s[nt], 0,0,0);
            }

        // online softmax in regs; row = wm + quad*4 + r, col = nt*16 + l15
        const bool diag = (kt == qt);
        float alpha[4];
        float pr[4][4];
        #pragma unroll
        for (int r = 0; r < 4; r++) {
            const int rowg = wm + quad*4 + r;
            float sv[4], mx = -1e30f;
            #pragma unroll
            for (int nt = 0; nt < 4; nt++) {
                float val = s[nt][r] * 0.125f;
                if (diag && (nt*16 + l15) > rowg) val = -1e30f;
                sv[nt] = val;
                mx = fmaxf(mx, val);
            }
            #pragma unroll
            for (int off = 1; off < 16; off <<= 1) mx = fmaxf(mx, __shfl_xor(mx, off, 16));
            const float mnew = fmaxf(m_run[r], mx);
            alpha[r] = __expf(m_run[r] - mnew);
            float rs = 0.f;
            #pragma unroll
            for (int nt = 0; nt < 4; nt++) {
                float p = __expf(sv[nt] - mnew);
                pr[r][nt] = p;
                rs += p;
            }
            #pragma unroll
            for (int off = 1; off < 16; off <<= 1) rs += __shfl_xor(rs, off, 16);
            l_run[r] = l_run[r]*alpha[r] + rs;
            m_run[r] = mnew;
        }
        __syncthreads();           // all QK reads of KP done -> overwrite as P

        // write P split into KP region: row = wm+quad*4+r, col = nt*16+l15
        #pragma unroll
        for (int r = 0; r < 4; r++)
            #pragma unroll
            for (int nt = 0; nt < 4; nt++) {
                short hh, ll; splitbf(pr[r][nt], hh, ll);
                *(short*)&KPh[wm + quad*4 + r][nt*16 + l15] = hh;
                *(short*)&KPl[wm + quad*4 + r][nt*16 + l15] = ll;
            }
        // no barrier: PV reads only this wave's own 16 P-rows

        // rescale O and accumulate PV via MFMA
        #pragma unroll
        for (int dt = 0; dt < 4; dt++)
            #pragma unroll
            for (int r = 0; r < 4; r++)
                oacc[dt][r] *= alpha[r];
        #pragma unroll
        for (int kc = 0; kc < 2; kc++) {
            short8 ph = *(const short8*)&KPh[wm + l15][kc*32 + quad*8];
            short8 pl = *(const short8*)&KPl[wm + l15][kc*32 + quad*8];
            #pragma unroll
            for (int dt = 0; dt < 4; dt++) {
                short8 vh = *(const short8*)&Vth[dt*16 + l15][kc*32 + quad*8];
                short8 vl = *(const short8*)&Vtl[dt*16 + l15][kc*32 + quad*8];
                oacc[dt] = __builtin_amdgcn_mfma_f32_16x16x32_bf16(ph, vh, oacc[dt], 0,0,0);
                oacc[dt] = __builtin_amdgcn_mfma_f32_16x16x32_bf16(ph, vl, oacc[dt], 0,0,0);
                oacc[dt] = __builtin_amdgcn_mfma_f32_16x16x32_bf16(pl, vh, oacc[dt], 0,0,0);
            }
        }
    }

    // store unnormalized O partial + (m,l)
    #pragma unroll
    for (int dt = 0; dt < 4; dt++)
        #pragma unroll
        for (int r = 0; r < 4; r++)
            Op[(wm + quad*4 + r)*64 + dt*16 + l15] = oacc[dt][r];
    if (l15 == 0) {
        #pragma unroll
        for (int r = 0; r < 4; r++) {
            mpart[(long)pidx*64 + wm + quad*4 + r] = m_run[r];
            lpart[(long)pidx*64 + wm + quad*4 + r] = l_run[r];
        }
    }
}

// ---------------------------------------------------------------------------
// Merge the two kt-half partials -> normalized attention output, emitted as
// pre-split bf16 hi/lo (direct feed for the WO bf16x3 GEMM).
// ---------------------------------------------------------------------------
__global__ __launch_bounds__(256) void attn_merge(const float* __restrict__ Opart,
                                                  const float* __restrict__ mpart,
                                                  const float* __restrict__ lpart,
                                                  __hip_bfloat16* __restrict__ aoh,
                                                  __hip_bfloat16* __restrict__ aol) {
    const int qt = blockIdx.x, h = blockIdx.y, b = blockIdx.z;
    const int pA = ((b*HH + h)*16 + qt)*2, pB = pA + 1;
    const int tid = threadIdx.x;
    const int r = tid >> 2, c0 = (tid & 3) * 16;
    const float mA = mpart[(long)pA*64 + r], mB = mpart[(long)pB*64 + r];
    const float lA = lpart[(long)pA*64 + r], lB = lpart[(long)pB*64 + r];
    const float M  = fmaxf(mA, mB);
    const float wA = __expf(mA - M), wB = __expf(mB - M);
    const float inv = 1.f / (lA*wA + lB*wB);
    const float* OA = Opart + (long)pA*4096 + r*64 + c0;
    const float* OB = Opart + (long)pB*4096 + r*64 + c0;
    const long dst = (long)b*TT*CC + (long)(qt*64 + r)*CC + h*DD + c0;
    #pragma unroll
    for (int j = 0; j < 16; j += 4) {
        float4 oa = *(const float4*)(OA + j);
        float4 ob = *(const float4*)(OB + j);
        float xs[4];
        xs[0] = (oa.x*wA + ob.x*wB)*inv;
        xs[1] = (oa.y*wA + ob.y*wB)*inv;
        xs[2] = (oa.z*wA + ob.z*wB)*inv;
        xs[3] = (oa.w*wA + ob.w*wB)*inv;
        s16x4 hv, lv;
        #pragma unroll
        for (int t = 0; t < 4; t++) { short hh,ll; splitbf(xs[t],hh,ll); hv[t]=hh; lv[t]=ll; }
        *(s16x4*)(aoh + dst + j) = hv;
        *(s16x4*)(aol + dst + j) = lv;
    }
}

// ---------------------------------------------------------------------------
// Column norms of sim_matrix [C, E]; also zeros the compaction counters.
// ---------------------------------------------------------------------------
__global__ __launch_bounds__(256) void colnorm_kernel(const float* __restrict__ sim,
                                                      float* __restrict__ cn,
                                                      int* __restrict__ cnt) {
    const int e = blockIdx.x, tid = threadIdx.x;
    __shared__ float red[256];
    float s = 0.f;
    for (int c = tid; c < CC; c += 256) {
        float vv = sim[(long)c*EE + e];
        s += vv*vv;
    }
    red[tid] = s; __syncthreads();
    for (int st = 128; st > 0; st >>= 1) {
        if (tid < st) red[tid] += red[tid+st];
        __syncthreads();
    }
    if (tid == 0) { cn[e] = sqrtf(red[0]); cnt[e] = 0; }
}

// ---------------------------------------------------------------------------
extern "C" void kernel_launch(void* const* d_in, const int* in_sizes, int n_in,
                              void* d_out, int out_size, void* d_ws, size_t ws_size,
                              hipStream_t stream) {
    const float* x     = (const float*)d_in[0];
    const float* ln1_g = (const float*)d_in[1];
    const float* ln1_b = (const float*)d_in[2];
    const float* ln2_g = (const float*)d_in[3];
    const float* ln2_b = (const float*)d_in[4];
    const float* wq    = (const float*)d_in[5];
    const float* wk    = (const float*)d_in[6];
    const float* wv    = (const float*)d_in[7];
    const float* wo    = (const float*)d_in[8];
    const float* sim   = (const float*)d_in[9];
    const float* thr   = (const float*)d_in[10];
    const float* w1    = (const float*)d_in[11];
    const float* w2    = (const float*)d_in[12];

    float* out_x      = (float*)d_out;
    float* out_scores = out_x + (long)NN*CC;
    float* out_eo     = out_scores + (long)NN*EE;
    float* out_kpt    = out_eo + (long)NN*EE*CC;

    const long MF = (long)NN*CC;     // 2M floats
    const long CK = (long)CC*CC;     // 1M elems per weight slab
    float* ws   = (float*)d_ws;
    // [0, MF): attn-out split bf16 (hi/lo)
    __hip_bfloat16* aoh = (__hip_bfloat16*)ws;
    __hip_bfloat16* aol = (__hip_bfloat16*)(ws + MF/2);
    // [MF, 4MF): QKV pre-split bf16 (3 slabs hi, 3 slabs lo)
    __hip_bfloat16* qkvh = (__hip_bfloat16*)(ws + MF);
    __hip_bfloat16* qkvl = (__hip_bfloat16*)(ws + MF + 3*MF/2);
    // [4MF, 5MF): V^T pre-split bf16
    __hip_bfloat16* vth = (__hip_bfloat16*)(ws + 4*MF);
    __hip_bfloat16* vtl = (__hip_bfloat16*)(ws + 4*MF + MF/2);
    // [5MF, 5.5MF): LN2 bf16 for expert GEMM
    __hip_bfloat16* h2b = (__hip_bfloat16*)(ws + 5*MF);
    // [5.5MF, 7.5MF): attn partials; hh/hl (LN1 split) + mid alias
    float* Opart = ws + 5*MF + MF/2;
    __hip_bfloat16* hh  = (__hip_bfloat16*)(ws + 5*MF + MF/2);       // dead after QKV GEMM
    __hip_bfloat16* hl  = (__hip_bfloat16*)(ws + 6*MF);
    __hip_bfloat16* mid = (__hip_bfloat16*)(ws + 5*MF + MF/2);       // after merge
    // [7.5MF, 9.5MF): QKVO weight splits; w1t/w2t alias (after WO GEMM)
    __hip_bfloat16* wsph = (__hip_bfloat16*)(ws + 7*MF + MF/2);      // [4][C][C] hi
    __hip_bfloat16* wspl = (__hip_bfloat16*)(ws + 8*MF + MF/2);      // [4][C][C] lo
    __hip_bfloat16* w1t  = (__hip_bfloat16*)(ws + 7*MF + MF/2);
    __hip_bfloat16* w2t  = (__hip_bfloat16*)(ws + 8*MF + MF/2);
    float* maskb = ws + 9*MF + MF/2;                                  // 32K floats
    float* cn    = maskb + (long)NN*EE;                               // 16
    float* mpart = cn + 16;                                           // 64K
    float* lpart = mpart + 1024L*64;                                  // 64K
    int*   cnt   = (int*)(lpart + 1024L*64);                          // 16 ints
    int*   elist = cnt + 16;                                          // EE*NN ints

    // 0. sim column norms + zero compaction counters
    colnorm_kernel<<<EE, 256, 0, stream>>>(sim, cn, cnt);

    // 1. one-shot QKVO weight transpose + bf16x3 split (single launch)
    {
        dim3 gt(CC/32, CC/32, 4);
        transpose_split4<<<gt, 256, 0, stream>>>(wq, wk, wv, wo, wsph, wspl);
    }

    // 2. LN1 -> pre-split bf16 hi/lo
    ln_kernel<<<NN, 256, 0, stream>>>(x, ln1_g, ln1_b, hh, hl);

    // 3. fused QKV projection, 128x128 tile -> pre-split bf16 hi/lo outputs
    {
        dim3 gq(CC/128, NN/128, 3);
        gemm_split_big<<<gq, 256, 0, stream>>>(hh, hl, wsph, wspl,
                                               qkvh, qkvl, NN, CC, CC);
    }

    // 3.5 V transpose (bf16 hi/lo): [token][C] -> per-(b,h) [d][T]
    {
        dim3 gv(TT/32, CC/32, BB);
        transpose_v_bf16<<<gv, 256, 0, stream>>>(qkvh + 2*(long)NN*CC, qkvl + 2*(long)NN*CC,
                                                 vth, vtl);
    }

    // 4. causal attention (MFMA flash, kt-split, pre-split inputs) + merge
    {
        dim3 gattn(32, HH, BB);
        attn_split<<<gattn, 256, 0, stream>>>(qkvh, qkvl,
                                              qkvh + (long)NN*CC, qkvl + (long)NN*CC,
                                              vth, vtl, Opart, mpart, lpart);
        dim3 gmerge(16, HH, BB);
        attn_merge<<<gmerge, 256, 0, stream>>>(Opart, mpart, lpart, aoh, aol);
    }

    // 5. output projection + residual -> d_out x slot (64x128 tile: 256 blocks)
    {
        dim3 go(CC/128, NN/64, 1);
        gemm_split<<<go, 256, 0, stream>>>(aoh, aol, wsph + 3*CK, wspl + 3*CK,
                                           out_x, NN, CC, CC, x);
    }

    // 6. expert weight transposes (single launch; safe to overwrite QKVO splits)
    {
        dim3 ge(256, 1, 2*EE);
        transpose_f2b_both<<<ge, 256, 0, stream>>>(w1, w2, w1t, w2t);
    }

    // 7. fused LN2 + router + active-token compaction
    ln2_router<<<NN, 256, 0, stream>>>(out_x, ln2_g, ln2_b, sim, cn, thr,
                                       h2b, out_scores, out_kpt, maskb,
                                       cnt, elist);

    // 7.5 zero inactive eo rows (values for inactive pairs are exactly 0)
    eo_zero<<<NN, 256, 0, stream>>>(maskb, out_eo);

    // 8. sparse expert GEMM 1: mid[e][slot] = gelu(h2[tok] @ w1[e])
    {
        dim3 g(II/128, NN/128, EE);
        gemm_moe1_sparse<<<g, 256, 0, stream>>>(h2b, w1t, mid, cnt, elist);
    }

    // 9. sparse expert GEMM 2: eo[tok,e,:] = mid[e][slot] @ w2[e]
    {
        dim3 g(CC/128, NN/128, EE);
        gemm_moe2_sparse<<<g, 256, 0, stream>>>(mid, w2t, out_eo, cnt, elist);
    }

    // 10. final = sum over active e; x += final (deterministic order)
    moe_sum_masked<<<NN, 256, 0, stream>>>(maskb, out_eo, out_x);
}

// Round 7
// 458.721 us; speedup vs baseline: 1.0594x; 1.0246x over previous
//
#include <hip/hip_runtime.h>
#include <hip/hip_bf16.h>
#include <math.h>

// Problem constants
#define BB 2
#define TT 1024
#define CC 1024
#define HH 16
#define DD 64
#define EE 16
#define II 256
#define NN (BB*TT)          // 2048 tokens
#define EPSLN 1e-5f
#define LDA 72              // bf16 LDS row stride: 144B rows, 16B-aligned

typedef __attribute__((ext_vector_type(8))) short short8;
typedef __attribute__((ext_vector_type(4))) short s16x4;
typedef __attribute__((ext_vector_type(4))) float f32x4;

// Direct global->LDS 16B copy: LDS dest = uniform base + lane*16.
#define GLOAD_LDS16(g, l) \
    __builtin_amdgcn_global_load_lds((const __attribute__((address_space(1))) void*)(g), \
                                     (__attribute__((address_space(3))) void*)(l), 16, 0, 0)

__device__ inline void splitbf(float x, short& hi, short& lo) {
    __hip_bfloat16 h = __float2bfloat16(x);
    float hf = __bfloat162float(h);
    __hip_bfloat16 l = __float2bfloat16(x - hf);
    hi = *(short*)&h;
    lo = *(short*)&l;
}

// ---------------------------------------------------------------------------
// LayerNorm (LN1): one block per row. Emits pre-split bf16 hi/lo.
// ---------------------------------------------------------------------------
__global__ __launch_bounds__(256) void ln_kernel(const float* __restrict__ x,
                                                 const float* __restrict__ g,
                                                 const float* __restrict__ bta,
                                                 __hip_bfloat16* __restrict__ outh,
                                                 __hip_bfloat16* __restrict__ outl) {
    const int row = blockIdx.x, tid = threadIdx.x;
    __shared__ float r1[256], r2[256];
    const float* xr = x + (long)row * CC;
    float4 xv = ((const float4*)xr)[tid];
    float s  = xv.x + xv.y + xv.z + xv.w;
    float q2 = xv.x*xv.x + xv.y*xv.y + xv.z*xv.z + xv.w*xv.w;
    r1[tid] = s; r2[tid] = q2; __syncthreads();
    for (int st = 128; st > 0; st >>= 1) {
        if (tid < st) { r1[tid] += r1[tid+st]; r2[tid] += r2[tid+st]; }
        __syncthreads();
    }
    const float mu  = r1[0] * (1.f/CC);
    const float var = r2[0] * (1.f/CC) - mu*mu;
    const float rs  = rsqrtf(var + EPSLN);
    float4 gv = ((const float4*)g)[tid];
    float4 bv = ((const float4*)bta)[tid];
    float xs[4];
    xs[0] = (xv.x-mu)*rs*gv.x + bv.x;
    xs[1] = (xv.y-mu)*rs*gv.y + bv.y;
    xs[2] = (xv.z-mu)*rs*gv.z + bv.z;
    xs[3] = (xv.w-mu)*rs*gv.w + bv.w;
    s16x4 hv, lv;
    #pragma unroll
    for (int j = 0; j < 4; j++) { short h,l; splitbf(xs[j], h, l); hv[j]=h; lv[j]=l; }
    *(s16x4*)(outh + (long)row * CC + tid*4) = hv;
    *(s16x4*)(outl + (long)row * CC + tid*4) = lv;
}

// ---------------------------------------------------------------------------
// Fused LN2 + router: LN -> h2b bf16; scores/mask/k_per_token; and per-expert
// active-token compaction lists (order-free: values don't depend on order).
// ---------------------------------------------------------------------------
__global__ __launch_bounds__(256) void ln2_router(const float* __restrict__ xio,
                                                  const float* __restrict__ g,
                                                  const float* __restrict__ bta,
                                                  const float* __restrict__ sim,
                                                  const float* __restrict__ cn,
                                                  const float* __restrict__ thr,
                                                  __hip_bfloat16* __restrict__ h2b,
                                                  float* __restrict__ scores,
                                                  float* __restrict__ kpt,
                                                  float* __restrict__ maskb,
                                                  int* __restrict__ cnt,
                                                  int* __restrict__ elist) {
    const int row = blockIdx.x, tid = threadIdx.x;
    __shared__ float r1[256], r2[256];
    __shared__ float red[256*17];
    float4 xv = ((const float4*)(xio + (long)row*CC))[tid];
    float s  = xv.x + xv.y + xv.z + xv.w;
    float q2 = xv.x*xv.x + xv.y*xv.y + xv.z*xv.z + xv.w*xv.w;
    r1[tid] = s; r2[tid] = q2; __syncthreads();
    for (int st = 128; st > 0; st >>= 1) {
        if (tid < st) { r1[tid] += r1[tid+st]; r2[tid] += r2[tid+st]; }
        __syncthreads();
    }
    const float mu  = r1[0] * (1.f/CC);
    const float var = r2[0] * (1.f/CC) - mu*mu;
    const float rs  = rsqrtf(var + EPSLN);
    float4 gv = ((const float4*)g)[tid];
    float4 bv = ((const float4*)bta)[tid];
    float ovs[4];
    ovs[0] = (xv.x-mu)*rs*gv.x + bv.x;
    ovs[1] = (xv.y-mu)*rs*gv.y + bv.y;
    ovs[2] = (xv.z-mu)*rs*gv.z + bv.z;
    ovs[3] = (xv.w-mu)*rs*gv.w + bv.w;
    {
        __hip_bfloat16* p = h2b + (long)row*CC + tid*4;
        p[0] = __float2bfloat16(ovs[0]); p[1] = __float2bfloat16(ovs[1]);
        p[2] = __float2bfloat16(ovs[2]); p[3] = __float2bfloat16(ovs[3]);
    }
    // router: this thread's 4 contiguous channels
    float acc[17] = {};
    #pragma unroll
    for (int j = 0; j < 4; j++) {
        const float v = ovs[j];
        acc[16] += v*v;
        const float* sr = sim + (long)(tid*4 + j)*EE;
        #pragma unroll
        for (int e2 = 0; e2 < EE; e2++) acc[e2] += v*sr[e2];
    }
    #pragma unroll
    for (int e2 = 0; e2 < 17; e2++) red[tid*17 + e2] = acc[e2];
    __syncthreads();
    for (int st = 128; st > 0; st >>= 1) {
        if (tid < st)
            for (int e2 = 0; e2 < 17; e2++) red[tid*17+e2] += red[(tid+st)*17+e2];
        __syncthreads();
    }
    if (tid < EE) {
        const float nrm = sqrtf(red[16]);
        const float sc  = red[tid] / (nrm * cn[tid]);
        scores[(long)row*EE + tid] = sc;
        const float mkv = sc > thr[0] ? 1.f : 0.f;
        maskb[(long)row*EE + tid] = mkv;
        red[tid] = mkv;
        if (mkv > 0.f) {
            int slot = atomicAdd(&cnt[tid], 1);
            elist[(long)tid*NN + slot] = row;
        }
    }
    __syncthreads();
    if (tid == 0) {
        float c2 = 0.f;
        for (int e2 = 0; e2 < EE; e2++) c2 += red[e2];
        kpt[row] = c2;
    }
}

// ---------------------------------------------------------------------------
// One-shot QKVO weight prep (single launch, z selects weight):
// W[K][N] fp32 -> Wt[N][K] bf16 hi + lo (bf16x3 split).
// ---------------------------------------------------------------------------
__global__ __launch_bounds__(256) void transpose_split4(const float* __restrict__ W0,
                                                        const float* __restrict__ W1,
                                                        const float* __restrict__ W2,
                                                        const float* __restrict__ W3,
                                                        __hip_bfloat16* __restrict__ Wth_base,
                                                        __hip_bfloat16* __restrict__ Wtl_base) {
    const int z = blockIdx.z;
    const float* W = (z==0) ? W0 : (z==1) ? W1 : (z==2) ? W2 : W3;
    __hip_bfloat16* Wth = Wth_base + (long)z*CC*CC;
    __hip_bfloat16* Wtl = Wtl_base + (long)z*CC*CC;
    const int n0 = blockIdx.x * 32, k0 = blockIdx.y * 32;
    __shared__ float t[32][33];
    const int tx = threadIdx.x & 31, ty = threadIdx.x >> 5;
    #pragma unroll
    for (int i = 0; i < 4; i++)
        t[ty + i*8][tx] = W[(long)(k0 + ty + i*8)*CC + n0 + tx];
    __syncthreads();
    #pragma unroll
    for (int i = 0; i < 4; i++) {
        float v = t[tx][ty + i*8];
        short h, l; splitbf(v, h, l);
        *(short*)&Wth[(long)(n0 + ty + i*8)*CC + k0 + tx] = h;
        *(short*)&Wtl[(long)(n0 + ty + i*8)*CC + k0 + tx] = l;
    }
}

// ---------------------------------------------------------------------------
// Expert weight prep (single launch): z = half*16 + e. half0: w1 [C][I] ->
// w1t [I][C]; half1: w2 [I][C] -> w2t [C][I]. Flattened grid.x = 256 blocks/e.
// ---------------------------------------------------------------------------
__global__ __launch_bounds__(256) void transpose_f2b_both(const float* __restrict__ w1,
                                                          const float* __restrict__ w2,
                                                          __hip_bfloat16* __restrict__ w1t,
                                                          __hip_bfloat16* __restrict__ w2t) {
    const int zz = blockIdx.z;
    const int half = zz >> 4, e = zz & 15;
    const float* W; __hip_bfloat16* Wt; int K, N, nbx;
    if (half == 0) { W = w1 + (long)e*CC*II; Wt = w1t + (long)e*CC*II; K = CC; N = II; nbx = II/32; }
    else           { W = w2 + (long)e*II*CC; Wt = w2t + (long)e*II*CC; K = II; N = CC; nbx = CC/32; }
    const int bx = blockIdx.x;
    const int n0 = (bx % nbx) * 32, k0 = (bx / nbx) * 32;
    __shared__ float t[32][33];
    const int tx = threadIdx.x & 31, ty = threadIdx.x >> 5;
    #pragma unroll
    for (int i = 0; i < 4; i++)
        t[ty + i*8][tx] = W[(long)(k0 + ty + i*8)*N + n0 + tx];
    __syncthreads();
    #pragma unroll
    for (int i = 0; i < 4; i++)
        Wt[(long)(n0 + ty + i*8)*K + k0 + tx] = __float2bfloat16(t[tx][ty + i*8]);
}

// ---------------------------------------------------------------------------
// bf16 transpose for V: [b*T + t][C] (hi/lo) -> [(b*H + h)*64 + d][T] (hi/lo)
// ---------------------------------------------------------------------------
__global__ __launch_bounds__(256) void transpose_v_bf16(
        const __hip_bfloat16* __restrict__ Vh, const __hip_bfloat16* __restrict__ Vl,
        __hip_bfloat16* __restrict__ Vth, __hip_bfloat16* __restrict__ Vtl) {
    const int b = blockIdx.z;
    const int c0 = blockIdx.y * 32, t0 = blockIdx.x * 32;
    __shared__ unsigned short th[32][33], tl[32][33];
    const int tx = threadIdx.x & 31, ty = threadIdx.x >> 5;
    const unsigned short* vh = (const unsigned short*)Vh;
    const unsigned short* vl = (const unsigned short*)Vl;
    #pragma unroll
    for (int i = 0; i < 4; i++) {
        const long src = ((long)b*TT + t0 + ty + i*8)*CC + c0 + tx;
        th[ty + i*8][tx] = vh[src];
        tl[ty + i*8][tx] = vl[src];
    }
    __syncthreads();
    #pragma unroll
    for (int i = 0; i < 4; i++) {
        const int gc = c0 + ty + i*8;          // global channel
        const int hh = gc >> 6, d = gc & 63;
        const long dst = ((long)(b*HH + hh)*64 + d)*TT + t0 + tx;
        ((unsigned short*)Vth)[dst] = th[tx][ty + i*8];
        ((unsigned short*)Vtl)[dst] = tl[tx][ty + i*8];
    }
}

// ---------------------------------------------------------------------------
// Big-tile bf16x3 split GEMM (QKV): 128Mx128N, BK=32, 4 waves each 64x64.
// Staging via global_load_lds width=16 (direct HBM->LDS, no VGPR round trip).
// LDS is LINEAR [128][32] (required: dest = wave-uniform base + lane*16).
// Emits pre-split bf16 hi/lo. Same bytes, same MFMA order -> bit-identical.
// ---------------------------------------------------------------------------
__global__ __launch_bounds__(256, 2) void gemm_split_big(
        const __hip_bfloat16* __restrict__ Ah,
        const __hip_bfloat16* __restrict__ Al,
        const __hip_bfloat16* __restrict__ Bh_base,
        const __hip_bfloat16* __restrict__ Bl_base,
        __hip_bfloat16* __restrict__ Ch_base,
        __hip_bfloat16* __restrict__ Cl_base,
        int M, int N, int K) {
    __shared__ __hip_bfloat16 Ash[128][32], Asl[128][32];
    __shared__ __hip_bfloat16 Bsh[128][32], Bsl[128][32];
    const int z = blockIdx.z;
    const __hip_bfloat16* Bth = Bh_base + (long)z * N * K;
    const __hip_bfloat16* Btl = Bl_base + (long)z * N * K;
    const int n0 = blockIdx.x * 128, m0 = blockIdx.y * 128;
    const int tid = threadIdx.x;
    const int wave = tid >> 6, lane = tid & 63;
    const int wm = (wave >> 1) * 64, wn = (wave & 1) * 64;
    const int l15 = lane & 15, quad = lane >> 4;

    f32x4 acc[4][4] = {};

    for (int k0 = 0; k0 < K; k0 += 32) {
        // stage 4 buffers: each = 128 rows x 32 k x 2B = 8 KB = 8 wave-loads.
        // wave w issues chunks {2w, 2w+1}; lane maps row=(lane>>2), col=(lane&3)*8.
        #pragma unroll
        for (int i = 0; i < 2; i++) {
            const int chunk = wave*2 + i;              // 0..7
            const int r = chunk*16 + (lane >> 2);
            const int c8 = (lane & 3) * 8;
            const long aoff = (long)(m0 + r)*K + k0 + c8;
            const long boff = (long)(n0 + r)*K + k0 + c8;
            GLOAD_LDS16(Ah  + aoff, &Ash[chunk*16][0]);
            GLOAD_LDS16(Al  + aoff, &Asl[chunk*16][0]);
            GLOAD_LDS16(Bth + boff, &Bsh[chunk*16][0]);
            GLOAD_LDS16(Btl + boff, &Bsl[chunk*16][0]);
        }
        __syncthreads();
        short8 ah[4], al[4], bh[4], bl[4];
        #pragma unroll
        for (int i = 0; i < 4; i++) {
            ah[i] = *(const short8*)&Ash[wm + i*16 + l15][quad*8];
            al[i] = *(const short8*)&Asl[wm + i*16 + l15][quad*8];
            bh[i] = *(const short8*)&Bsh[wn + i*16 + l15][quad*8];
            bl[i] = *(const short8*)&Bsl[wn + i*16 + l15][quad*8];
        }
        #pragma unroll
        for (int mi = 0; mi < 4; mi++)
            #pragma unroll
            for (int ni = 0; ni < 4; ni++) {
                acc[mi][ni] = __builtin_amdgcn_mfma_f32_16x16x32_bf16(ah[mi], bh[ni], acc[mi][ni], 0,0,0);
                acc[mi][ni] = __builtin_amdgcn_mfma_f32_16x16x32_bf16(ah[mi], bl[ni], acc[mi][ni], 0,0,0);
                acc[mi][ni] = __builtin_amdgcn_mfma_f32_16x16x32_bf16(al[mi], bh[ni], acc[mi][ni], 0,0,0);
            }
        __syncthreads();
    }

    #pragma unroll
    for (int mi = 0; mi < 4; mi++)
        #pragma unroll
        for (int r = 0; r < 4; r++) {
            const int row = m0 + wm + mi*16 + quad*4 + r;
            #pragma unroll
            for (int ni = 0; ni < 4; ni++) {
                const int col = n0 + wn + ni*16 + l15;
                short hh, ll; splitbf(acc[mi][ni][r], hh, ll);
                *(short*)&Ch_base[(long)z*M*N + (long)row*N + col] = hh;
                *(short*)&Cl_base[(long)z*M*N + (long)row*N + col] = ll;
            }
        }
}

// ---------------------------------------------------------------------------
// fp32-accurate MFMA GEMM via bf16x3 split, 64Mx128N tile (WO path).
// ---------------------------------------------------------------------------
__global__ __launch_bounds__(256, 2) void gemm_split(
        const __hip_bfloat16* __restrict__ Ah,
        const __hip_bfloat16* __restrict__ Al,
        const __hip_bfloat16* __restrict__ Bth,
        const __hip_bfloat16* __restrict__ Btl,
        float* __restrict__ Cp,
        int M, int N, int K,
        const float* __restrict__ resid) {
    __shared__ __hip_bfloat16 Ash[64][40], Asl[64][40];
    __shared__ __hip_bfloat16 Bsh[128][40], Bsl[128][40];
    const int n0 = blockIdx.x * 128, m0 = blockIdx.y * 64;
    const int tid = threadIdx.x;
    const int wave = tid >> 6, lane = tid & 63;
    const int wm = (wave >> 1) * 32, wn = (wave & 1) * 64;
    const int l15 = lane & 15, quad = lane >> 4;

    f32x4 acc[2][4] = {};

    for (int k0 = 0; k0 < K; k0 += 32) {
        {   // A tile: 64 rows x 32 k, contiguous short8 per thread
            const int r = tid >> 2, kg = (tid & 3) * 8;
            *(short8*)&Ash[r][kg] = *(const short8*)(Ah + (long)(m0 + r)*K + k0 + kg);
            *(short8*)&Asl[r][kg] = *(const short8*)(Al + (long)(m0 + r)*K + k0 + kg);
        }
        #pragma unroll
        for (int it = 0; it < 2; it++) {   // B tile: 128 rows x 32 k
            const int idx = tid + it*256;
            const int r = idx >> 2, kg = (idx & 3) * 8;
            *(short8*)&Bsh[r][kg] = *(const short8*)(Bth + (long)(n0 + r)*K + k0 + kg);
            *(short8*)&Bsl[r][kg] = *(const short8*)(Btl + (long)(n0 + r)*K + k0 + kg);
        }
        __syncthreads();
        short8 ah[2], al[2], bh[4], bl[4];
        #pragma unroll
        for (int mi = 0; mi < 2; mi++) {
            ah[mi] = *(const short8*)&Ash[wm + mi*16 + l15][quad*8];
            al[mi] = *(const short8*)&Asl[wm + mi*16 + l15][quad*8];
        }
        #pragma unroll
        for (int ni = 0; ni < 4; ni++) {
            bh[ni] = *(const short8*)&Bsh[wn + ni*16 + l15][quad*8];
            bl[ni] = *(const short8*)&Bsl[wn + ni*16 + l15][quad*8];
        }
        #pragma unroll
        for (int mi = 0; mi < 2; mi++)
            #pragma unroll
            for (int ni = 0; ni < 4; ni++) {
                acc[mi][ni] = __builtin_amdgcn_mfma_f32_16x16x32_bf16(ah[mi], bh[ni], acc[mi][ni], 0,0,0);
                acc[mi][ni] = __builtin_amdgcn_mfma_f32_16x16x32_bf16(ah[mi], bl[ni], acc[mi][ni], 0,0,0);
                acc[mi][ni] = __builtin_amdgcn_mfma_f32_16x16x32_bf16(al[mi], bh[ni], acc[mi][ni], 0,0,0);
            }
        __syncthreads();
    }

    #pragma unroll
    for (int mi = 0; mi < 2; mi++)
        #pragma unroll
        for (int r = 0; r < 4; r++) {
            const int row = m0 + wm + mi*16 + quad*4 + r;
            #pragma unroll
            for (int ni = 0; ni < 4; ni++) {
                const int col = n0 + wn + ni*16 + l15;
                Cp[(long)row*N + col] = acc[mi][ni][r] + resid[(long)row*N + col];
            }
        }
}

// ---------------------------------------------------------------------------
// Sparse expert GEMM1: mid[e][slot] = gelu(h2b[tok(slot)] @ w1t[e]^T), bf16.
// M = compacted active tokens of expert e; blocks beyond cnt[e] exit.
// ---------------------------------------------------------------------------
__global__ __launch_bounds__(256) void gemm_moe1_sparse(
        const __hip_bfloat16* __restrict__ A,      // h2b [NN][CC]
        const __hip_bfloat16* __restrict__ w1t,    // [16][II][CC]
        __hip_bfloat16* __restrict__ mid,          // [16][NN][II] compacted
        const int* __restrict__ cnt,
        const int* __restrict__ elist) {
    constexpr int LDK = 40;
    __shared__ __hip_bfloat16 As[128][LDK];
    __shared__ __hip_bfloat16 Bs[128][LDK];
    __shared__ int rowmap[128];
    const int e = blockIdx.z;
    const int count = cnt[e];
    const int m0 = blockIdx.y * 128;
    if (m0 >= count) return;
    const int n0 = blockIdx.x * 128;
    const __hip_bfloat16* Bt = w1t + (long)e*II*CC;
    const int* lst = elist + (long)e*NN;
    const int tid = threadIdx.x;
    if (tid < 128) rowmap[tid] = lst[min(m0 + tid, count - 1)];
    __syncthreads();
    const int wave = tid >> 6, lane = tid & 63;
    const int wm = (wave >> 1) * 64, wn = (wave & 1) * 64;
    const int l15 = lane & 15, quad = lane >> 4;

    f32x4 acc[4][4] = {};

    for (int k0 = 0; k0 < CC; k0 += 32) {
        #pragma unroll
        for (int it = 0; it < 2; it++) {
            int idx = tid + it*256;
            int r = idx >> 2, kg = idx & 3;
            short8 av = *(const short8*)(A  + (long)rowmap[r]*CC + k0 + kg*8);
            short8 bv = *(const short8*)(Bt + (long)(n0 + r)*CC + k0 + kg*8);
            *(short8*)&As[r][kg*8] = av;
            *(short8*)&Bs[r][kg*8] = bv;
        }
        __syncthreads();
        short8 af[4], bff[4];
        #pragma unroll
        for (int i = 0; i < 4; i++) {
            af[i]  = *(const short8*)&As[wm + i*16 + l15][quad*8];
            bff[i] = *(const short8*)&Bs[wn + i*16 + l15][quad*8];
        }
        #pragma unroll
        for (int mi = 0; mi < 4; mi++)
            #pragma unroll
            for (int ni = 0; ni < 4; ni++)
                acc[mi][ni] = __builtin_amdgcn_mfma_f32_16x16x32_bf16(
                                  af[mi], bff[ni], acc[mi][ni], 0, 0, 0);
        __syncthreads();
    }

    #pragma unroll
    for (int mi = 0; mi < 4; mi++) {
        #pragma unroll
        for (int r = 0; r < 4; r++) {
            const int slot = m0 + wm + mi*16 + quad*4 + r;
            if (slot < count) {
                #pragma unroll
                for (int ni = 0; ni < 4; ni++) {
                    const int col = n0 + wn + ni*16 + l15;
                    float val = acc[mi][ni][r];
                    val = 0.5f*val*(1.f + erff(val*0.70710678118f));
                    mid[((long)e*NN + slot)*II + col] = __float2bfloat16(val);
                }
            }
        }
    }
}

// ---------------------------------------------------------------------------
// Sparse expert GEMM2: eo[tok(slot), e, :] = mid[e][slot] @ w2t[e]^T
// (mask == 1 on active slots by construction; no atomics).
// ---------------------------------------------------------------------------
__global__ __launch_bounds__(256) void gemm_moe2_sparse(
        const __hip_bfloat16* __restrict__ mid,    // [16][NN][II] compacted
        const __hip_bfloat16* __restrict__ w2t,    // [16][CC][II]
        float* __restrict__ eo,                    // [NN][EE][CC]
        const int* __restrict__ cnt,
        const int* __restrict__ elist) {
    constexpr int LDK = 40;
    __shared__ __hip_bfloat16 As[128][LDK];
    __shared__ __hip_bfloat16 Bs[128][LDK];
    __shared__ int rowmap[128];
    const int e = blockIdx.z;
    const int count = cnt[e];
    const int m0 = blockIdx.y * 128;
    if (m0 >= count) return;
    const int n0 = blockIdx.x * 128;
    const __hip_bfloat16* A  = mid + (long)e*NN*II;
    const __hip_bfloat16* Bt = w2t + (long)e*CC*II;
    const int* lst = elist + (long)e*NN;
    const int tid = threadIdx.x;
    if (tid < 128) rowmap[tid] = lst[min(m0 + tid, count - 1)];
    __syncthreads();
    const int wave = tid >> 6, lane = tid & 63;
    const int wm = (wave >> 1) * 64, wn = (wave & 1) * 64;
    const int l15 = lane & 15, quad = lane >> 4;

    f32x4 acc[4][4] = {};

    for (int k0 = 0; k0 < II; k0 += 32) {
        #pragma unroll
        for (int it = 0; it < 2; it++) {
            int idx = tid + it*256;
            int r = idx >> 2, kg = idx & 3;
            short8 av = *(const short8*)(A  + (long)(m0 + r)*II + k0 + kg*8);
            short8 bv = *(const short8*)(Bt + (long)(n0 + r)*II + k0 + kg*8);
            *(short8*)&As[r][kg*8] = av;
            *(short8*)&Bs[r][kg*8] = bv;
        }
        __syncthreads();
        short8 af[4], bff[4];
        #pragma unroll
        for (int i = 0; i < 4; i++) {
            af[i]  = *(const short8*)&As[wm + i*16 + l15][quad*8];
            bff[i] = *(const short8*)&Bs[wn + i*16 + l15][quad*8];
        }
        #pragma unroll
        for (int mi = 0; mi < 4; mi++)
            #pragma unroll
            for (int ni = 0; ni < 4; ni++)
                acc[mi][ni] = __builtin_amdgcn_mfma_f32_16x16x32_bf16(
                                  af[mi], bff[ni], acc[mi][ni], 0, 0, 0);
        __syncthreads();
    }

    #pragma unroll
    for (int mi = 0; mi < 4; mi++) {
        #pragma unroll
        for (int r = 0; r < 4; r++) {
            const int slot = m0 + wm + mi*16 + quad*4 + r;
            if (slot < count) {
                const int tok = rowmap[wm + mi*16 + quad*4 + r];
                #pragma unroll
                for (int ni = 0; ni < 4; ni++) {
                    const int col = n0 + wn + ni*16 + l15;
                    eo[((long)tok*EE + e)*CC + col] = acc[mi][ni][r];
                }
            }
        }
    }
}

// ---------------------------------------------------------------------------
// Fused: zero inactive eo rows + final[n,:] = sum over active e of eo[n,e,:];
// xio += final. Deterministic e-ascending order (skipping exact zeros is
// bitwise-identical to summing them).
// ---------------------------------------------------------------------------
__global__ __launch_bounds__(256) void moe_sum_zero(const float* __restrict__ maskb,
                                                    float* __restrict__ eo,
                                                    float* __restrict__ xio) {
    const int row = blockIdx.x, tid = threadIdx.x;
    float4 s = {0.f, 0.f, 0.f, 0.f};
    const float4 z4 = {0.f, 0.f, 0.f, 0.f};
    #pragma unroll
    for (int e = 0; e < EE; e++) {
        float4* p = ((float4*)(eo + ((long)row*EE + e)*CC)) + tid;
        if (maskb[(long)row*EE + e] != 0.f) {
            float4 v = *p;
            s.x += v.x; s.y += v.y; s.z += v.z; s.w += v.w;
        } else {
            *p = z4;
        }
    }
    float4 xv = ((float4*)(xio + (long)row*CC))[tid];
    xv.x += s.x; xv.y += s.y; xv.z += s.z; xv.w += s.w;
    ((float4*)(xio + (long)row*CC))[tid] = xv;
}

// ---------------------------------------------------------------------------
// Flash attention with bf16x3 MFMA for QK^T and PV. kt-split for balance.
// All inputs PRE-SPLIT bf16 hi/lo; V pre-transposed [(b*H+h)*64+d][T].
// ---------------------------------------------------------------------------
__global__ __launch_bounds__(256, 4) void attn_split(
        const __hip_bfloat16* __restrict__ Qh, const __hip_bfloat16* __restrict__ Ql,
        const __hip_bfloat16* __restrict__ Kh, const __hip_bfloat16* __restrict__ Kl,
        const __hip_bfloat16* __restrict__ Vtg_h, const __hip_bfloat16* __restrict__ Vtg_l,
        float* __restrict__ Opart,
        float* __restrict__ mpart,
        float* __restrict__ lpart) {
    __shared__ __hip_bfloat16 KPh[64][LDA], KPl[64][LDA];   // K, then P
    __shared__ __hip_bfloat16 Vth[64][LDA], Vtl[64][LDA];   // V^T [d][kk]

    const int bx = blockIdx.x;                 // 0..31, heavy qt first
    const int qt = 15 - (bx >> 1), half = bx & 1;
    const int h = blockIdx.y, b = blockIdx.z;
    const int tid = threadIdx.x;
    const int wave = tid >> 6, lane = tid & 63;
    const int l15 = lane & 15, quad = lane >> 4;
    const int wm = wave * 16;                  // wave's 16 q-rows in the 64-tile
    const long tbase = (long)b * TT * CC + (long)h * DD;          // [token][C] slab
    const long vbase = (long)(b*HH + h) * 64 * TT;                // V^T slab
    const int pidx = ((b*HH + h)*16 + qt)*2 + half;
    float* Op = Opart + (long)pidx * 4096;

    const int n_kt = qt + 1, mid_kt = (n_kt + 1) >> 1;
    const int kt_lo = half ? mid_kt : 0;
    const int kt_hi = half ? n_kt   : mid_kt;

    if (kt_lo >= kt_hi) {      // empty half (qt=0): neutral partials
        for (int i = tid; i < 64*64; i += 256) Op[i] = 0.f;
        if (tid < 64) { mpart[(long)pidx*64 + tid] = -1e30f; lpart[(long)pidx*64 + tid] = 0.f; }
        return;
    }

    // Q A-fragments direct from pre-split global
    short8 qh[2], ql[2];
    {
        const long qoff = tbase + (long)(qt*64 + wm + l15)*CC;
        #pragma unroll
        for (int kc = 0; kc < 2; kc++) {
            qh[kc] = *(const short8*)(Qh + qoff + kc*32 + quad*8);
            ql[kc] = *(const short8*)(Ql + qoff + kc*32 + quad*8);
        }
    }

    f32x4 oacc[4] = {};            // 4 d-tiles, rows = quad*4+reg
    float m_run[4], l_run[4];
    #pragma unroll
    for (int r = 0; r < 4; r++) { m_run[r] = -1e30f; l_run[r] = 0.f; }

    for (int kt = kt_lo; kt < kt_hi; kt++) {
        __syncthreads();           // prev-iter PV reads of KP/Vt done
        #pragma unroll
        for (int it = 0; it < 2; it++) {
            const int idx = tid + it*256;
            const int r = idx >> 3, g = (idx & 7)*8;
            const long koff = tbase + (long)(kt*64 + r)*CC + g;
            const long voff = vbase + (long)r*TT + kt*64 + g;
            *(short8*)&KPh[r][g] = *(const short8*)(Kh + koff);
            *(short8*)&KPl[r][g] = *(const short8*)(Kl + koff);
            *(short8*)&Vth[r][g] = *(const short8*)(Vtg_h + voff);
            *(short8*)&Vtl[r][g] = *(const short8*)(Vtg_l + voff);
        }
        __syncthreads();

        // QK^T via MFMA: 4 key-tiles x 2 k-chunks x 3 split terms
        f32x4 s[4] = {};
        #pragma unroll
        for (int nt = 0; nt < 4; nt++)
            #pragma unroll
            for (int kc = 0; kc < 2; kc++) {
                short8 bh = *(const short8*)&KPh[nt*16 + l15][kc*32 + quad*8];
                short8 bl = *(const short8*)&KPl[nt*16 + l15][kc*32 + quad*8];
                s[nt] = __builtin_amdgcn_mfma_f32_16x16x32_bf16(qh[kc], bh, s[nt], 0,0,0);
                s[nt] = __builtin_amdgcn_mfma_f32_16x16x32_bf16(qh[kc], bl, s[nt], 0,0,0);
                s[nt] = __builtin_amdgcn_mfma_f32_16x16x32_bf16(ql[kc], bh, s[nt], 0,0,0);
            }

        // online softmax in regs; row = wm + quad*4 + r, col = nt*16 + l15
        const bool diag = (kt == qt);
        float alpha[4];
        float pr[4][4];
        #pragma unroll
        for (int r = 0; r < 4; r++) {
            const int rowg = wm + quad*4 + r;
            float sv[4], mx = -1e30f;
            #pragma unroll
            for (int nt = 0; nt < 4; nt++) {
                float val = s[nt][r] * 0.125f;
                if (diag && (nt*16 + l15) > rowg) val = -1e30f;
                sv[nt] = val;
                mx = fmaxf(mx, val);
            }
            #pragma unroll
            for (int off = 1; off < 16; off <<= 1) mx = fmaxf(mx, __shfl_xor(mx, off, 16));
            const float mnew = fmaxf(m_run[r], mx);
            alpha[r] = __expf(m_run[r] - mnew);
            float rs = 0.f;
            #pragma unroll
            for (int nt = 0; nt < 4; nt++) {
                float p = __expf(sv[nt] - mnew);
                pr[r][nt] = p;
                rs += p;
            }
            #pragma unroll
            for (int off = 1; off < 16; off <<= 1) rs += __shfl_xor(rs, off, 16);
            l_run[r] = l_run[r]*alpha[r] + rs;
            m_run[r] = mnew;
        }
        __syncthreads();           // all QK reads of KP done -> overwrite as P

        // write P split into KP region: row = wm+quad*4+r, col = nt*16+l15
        #pragma unroll
        for (int r = 0; r < 4; r++)
            #pragma unroll
            for (int nt = 0; nt < 4; nt++) {
                short hh, ll; splitbf(pr[r][nt], hh, ll);
                *(short*)&KPh[wm + quad*4 + r][nt*16 + l15] = hh;
                *(short*)&KPl[wm + quad*4 + r][nt*16 + l15] = ll;
            }
        // no barrier: PV reads only this wave's own 16 P-rows

        // rescale O and accumulate PV via MFMA
        #pragma unroll
        for (int dt = 0; dt < 4; dt++)
            #pragma unroll
            for (int r = 0; r < 4; r++)
                oacc[dt][r] *= alpha[r];
        #pragma unroll
        for (int kc = 0; kc < 2; kc++) {
            short8 ph = *(const short8*)&KPh[wm + l15][kc*32 + quad*8];
            short8 pl = *(const short8*)&KPl[wm + l15][kc*32 + quad*8];
            #pragma unroll
            for (int dt = 0; dt < 4; dt++) {
                short8 vh = *(const short8*)&Vth[dt*16 + l15][kc*32 + quad*8];
                short8 vl = *(const short8*)&Vtl[dt*16 + l15][kc*32 + quad*8];
                oacc[dt] = __builtin_amdgcn_mfma_f32_16x16x32_bf16(ph, vh, oacc[dt], 0,0,0);
                oacc[dt] = __builtin_amdgcn_mfma_f32_16x16x32_bf16(ph, vl, oacc[dt], 0,0,0);
                oacc[dt] = __builtin_amdgcn_mfma_f32_16x16x32_bf16(pl, vh, oacc[dt], 0,0,0);
            }
        }
    }

    // store unnormalized O partial + (m,l)
    #pragma unroll
    for (int dt = 0; dt < 4; dt++)
        #pragma unroll
        for (int r = 0; r < 4; r++)
            Op[(wm + quad*4 + r)*64 + dt*16 + l15] = oacc[dt][r];
    if (l15 == 0) {
        #pragma unroll
        for (int r = 0; r < 4; r++) {
            mpart[(long)pidx*64 + wm + quad*4 + r] = m_run[r];
            lpart[(long)pidx*64 + wm + quad*4 + r] = l_run[r];
        }
    }
}

// ---------------------------------------------------------------------------
// Merge the two kt-half partials -> normalized attention output, emitted as
// pre-split bf16 hi/lo (direct feed for the WO bf16x3 GEMM).
// ---------------------------------------------------------------------------
__global__ __launch_bounds__(256) void attn_merge(const float* __restrict__ Opart,
                                                  const float* __restrict__ mpart,
                                                  const float* __restrict__ lpart,
                                                  __hip_bfloat16* __restrict__ aoh,
                                                  __hip_bfloat16* __restrict__ aol) {
    const int qt = blockIdx.x, h = blockIdx.y, b = blockIdx.z;
    const int pA = ((b*HH + h)*16 + qt)*2, pB = pA + 1;
    const int tid = threadIdx.x;
    const int r = tid >> 2, c0 = (tid & 3) * 16;
    const float mA = mpart[(long)pA*64 + r], mB = mpart[(long)pB*64 + r];
    const float lA = lpart[(long)pA*64 + r], lB = lpart[(long)pB*64 + r];
    const float M  = fmaxf(mA, mB);
    const float wA = __expf(mA - M), wB = __expf(mB - M);
    const float inv = 1.f / (lA*wA + lB*wB);
    const float* OA = Opart + (long)pA*4096 + r*64 + c0;
    const float* OB = Opart + (long)pB*4096 + r*64 + c0;
    const long dst = (long)b*TT*CC + (long)(qt*64 + r)*CC + h*DD + c0;
    #pragma unroll
    for (int j = 0; j < 16; j += 4) {
        float4 oa = *(const float4*)(OA + j);
        float4 ob = *(const float4*)(OB + j);
        float xs[4];
        xs[0] = (oa.x*wA + ob.x*wB)*inv;
        xs[1] = (oa.y*wA + ob.y*wB)*inv;
        xs[2] = (oa.z*wA + ob.z*wB)*inv;
        xs[3] = (oa.w*wA + ob.w*wB)*inv;
        s16x4 hv, lv;
        #pragma unroll
        for (int t = 0; t < 4; t++) { short hh,ll; splitbf(xs[t],hh,ll); hv[t]=hh; lv[t]=ll; }
        *(s16x4*)(aoh + dst + j) = hv;
        *(s16x4*)(aol + dst + j) = lv;
    }
}

// ---------------------------------------------------------------------------
// Column norms of sim_matrix [C, E]; also zeros the compaction counters.
// ---------------------------------------------------------------------------
__global__ __launch_bounds__(256) void colnorm_kernel(const float* __restrict__ sim,
                                                      float* __restrict__ cn,
                                                      int* __restrict__ cnt) {
    const int e = blockIdx.x, tid = threadIdx.x;
    __shared__ float red[256];
    float s = 0.f;
    for (int c = tid; c < CC; c += 256) {
        float vv = sim[(long)c*EE + e];
        s += vv*vv;
    }
    red[tid] = s; __syncthreads();
    for (int st = 128; st > 0; st >>= 1) {
        if (tid < st) red[tid] += red[tid+st];
        __syncthreads();
    }
    if (tid == 0) { cn[e] = sqrtf(red[0]); cnt[e] = 0; }
}

// ---------------------------------------------------------------------------
extern "C" void kernel_launch(void* const* d_in, const int* in_sizes, int n_in,
                              void* d_out, int out_size, void* d_ws, size_t ws_size,
                              hipStream_t stream) {
    const float* x     = (const float*)d_in[0];
    const float* ln1_g = (const float*)d_in[1];
    const float* ln1_b = (const float*)d_in[2];
    const float* ln2_g = (const float*)d_in[3];
    const float* ln2_b = (const float*)d_in[4];
    const float* wq    = (const float*)d_in[5];
    const float* wk    = (const float*)d_in[6];
    const float* wv    = (const float*)d_in[7];
    const float* wo    = (const float*)d_in[8];
    const float* sim   = (const float*)d_in[9];
    const float* thr   = (const float*)d_in[10];
    const float* w1    = (const float*)d_in[11];
    const float* w2    = (const float*)d_in[12];

    float* out_x      = (float*)d_out;
    float* out_scores = out_x + (long)NN*CC;
    float* out_eo     = out_scores + (long)NN*EE;
    float* out_kpt    = out_eo + (long)NN*EE*CC;

    const long MF = (long)NN*CC;     // 2M floats
    const long CK = (long)CC*CC;     // 1M elems per weight slab
    float* ws   = (float*)d_ws;
    // [0, MF): attn-out split bf16 (hi/lo)
    __hip_bfloat16* aoh = (__hip_bfloat16*)ws;
    __hip_bfloat16* aol = (__hip_bfloat16*)(ws + MF/2);
    // [MF, 4MF): QKV pre-split bf16 (3 slabs hi, 3 slabs lo)
    __hip_bfloat16* qkvh = (__hip_bfloat16*)(ws + MF);
    __hip_bfloat16* qkvl = (__hip_bfloat16*)(ws + MF + 3*MF/2);
    // [4MF, 5MF): V^T pre-split bf16
    __hip_bfloat16* vth = (__hip_bfloat16*)(ws + 4*MF);
    __hip_bfloat16* vtl = (__hip_bfloat16*)(ws + 4*MF + MF/2);
    // [5MF, 5.5MF): LN2 bf16 for expert GEMM
    __hip_bfloat16* h2b = (__hip_bfloat16*)(ws + 5*MF);
    // [5.5MF, 7.5MF): attn partials; hh/hl (LN1 split) + mid alias
    float* Opart = ws + 5*MF + MF/2;
    __hip_bfloat16* hh  = (__hip_bfloat16*)(ws + 5*MF + MF/2);       // dead after QKV GEMM
    __hip_bfloat16* hl  = (__hip_bfloat16*)(ws + 6*MF);
    __hip_bfloat16* mid = (__hip_bfloat16*)(ws + 5*MF + MF/2);       // after merge
    // [7.5MF, 9.5MF): QKVO weight splits; w1t/w2t alias (after WO GEMM)
    __hip_bfloat16* wsph = (__hip_bfloat16*)(ws + 7*MF + MF/2);      // [4][C][C] hi
    __hip_bfloat16* wspl = (__hip_bfloat16*)(ws + 8*MF + MF/2);      // [4][C][C] lo
    __hip_bfloat16* w1t  = (__hip_bfloat16*)(ws + 7*MF + MF/2);
    __hip_bfloat16* w2t  = (__hip_bfloat16*)(ws + 8*MF + MF/2);
    float* maskb = ws + 9*MF + MF/2;                                  // 32K floats
    float* cn    = maskb + (long)NN*EE;                               // 16
    float* mpart = cn + 16;                                           // 64K
    float* lpart = mpart + 1024L*64;                                  // 64K
    int*   cnt   = (int*)(lpart + 1024L*64);                          // 16 ints
    int*   elist = cnt + 16;                                          // EE*NN ints

    // 0. sim column norms + zero compaction counters
    colnorm_kernel<<<EE, 256, 0, stream>>>(sim, cn, cnt);

    // 1. one-shot QKVO weight transpose + bf16x3 split (single launch)
    {
        dim3 gt(CC/32, CC/32, 4);
        transpose_split4<<<gt, 256, 0, stream>>>(wq, wk, wv, wo, wsph, wspl);
    }

    // 2. LN1 -> pre-split bf16 hi/lo
    ln_kernel<<<NN, 256, 0, stream>>>(x, ln1_g, ln1_b, hh, hl);

    // 3. fused QKV projection, 128x128 tile, global_load_lds staging
    {
        dim3 gq(CC/128, NN/128, 3);
        gemm_split_big<<<gq, 256, 0, stream>>>(hh, hl, wsph, wspl,
                                               qkvh, qkvl, NN, CC, CC);
    }

    // 3.5 V transpose (bf16 hi/lo): [token][C] -> per-(b,h) [d][T]
    {
        dim3 gv(TT/32, CC/32, BB);
        transpose_v_bf16<<<gv, 256, 0, stream>>>(qkvh + 2*(long)NN*CC, qkvl + 2*(long)NN*CC,
                                                 vth, vtl);
    }

    // 4. causal attention (MFMA flash, kt-split, pre-split inputs) + merge
    {
        dim3 gattn(32, HH, BB);
        attn_split<<<gattn, 256, 0, stream>>>(qkvh, qkvl,
                                              qkvh + (long)NN*CC, qkvl + (long)NN*CC,
                                              vth, vtl, Opart, mpart, lpart);
        dim3 gmerge(16, HH, BB);
        attn_merge<<<gmerge, 256, 0, stream>>>(Opart, mpart, lpart, aoh, aol);
    }

    // 5. output projection + residual -> d_out x slot (64x128 tile: 256 blocks)
    {
        dim3 go(CC/128, NN/64, 1);
        gemm_split<<<go, 256, 0, stream>>>(aoh, aol, wsph + 3*CK, wspl + 3*CK,
                                           out_x, NN, CC, CC, x);
    }

    // 6. expert weight transposes (single launch; safe to overwrite QKVO splits)
    {
        dim3 ge(256, 1, 2*EE);
        transpose_f2b_both<<<ge, 256, 0, stream>>>(w1, w2, w1t, w2t);
    }

    // 7. fused LN2 + router + active-token compaction
    ln2_router<<<NN, 256, 0, stream>>>(out_x, ln2_g, ln2_b, sim, cn, thr,
                                       h2b, out_scores, out_kpt, maskb,
                                       cnt, elist);

    // 8. sparse expert GEMM 1: mid[e][slot] = gelu(h2[tok] @ w1[e])
    {
        dim3 g(II/128, NN/128, EE);
        gemm_moe1_sparse<<<g, 256, 0, stream>>>(h2b, w1t, mid, cnt, elist);
    }

    // 9. sparse expert GEMM 2: eo[tok,e,:] = mid[e][slot] @ w2[e]
    {
        dim3 g(CC/128, NN/128, EE);
        gemm_moe2_sparse<<<g, 256, 0, stream>>>(mid, w2t, out_eo, cnt, elist);
    }

    // 10. fused: zero inactive eo rows + sum active -> x (deterministic order)
    moe_sum_zero<<<NN, 256, 0, stream>>>(maskb, out_eo, out_x);
}

// Round 8
// 455.883 us; speedup vs baseline: 1.0660x; 1.0062x over previous
//
#include <hip/hip_runtime.h>
#include <hip/hip_bf16.h>
#include <math.h>

// Problem constants
#define BB 2
#define TT 1024
#define CC 1024
#define HH 16
#define DD 64
#define EE 16
#define II 256
#define NN (BB*TT)          // 2048 tokens
#define EPSLN 1e-5f
#define LDA 72              // bf16 LDS row stride: 144B rows, 16B-aligned

typedef __attribute__((ext_vector_type(8))) short short8;
typedef __attribute__((ext_vector_type(4))) short s16x4;
typedef __attribute__((ext_vector_type(4))) float f32x4;

// Direct global->LDS 16B copy: LDS dest = uniform base + lane*16.
#define GLOAD_LDS16(g, l) \
    __builtin_amdgcn_global_load_lds((const __attribute__((address_space(1))) void*)(g), \
                                     (__attribute__((address_space(3))) void*)(l), 16, 0, 0)

__device__ inline void splitbf(float x, short& hi, short& lo) {
    __hip_bfloat16 h = __float2bfloat16(x);
    float hf = __bfloat162float(h);
    __hip_bfloat16 l = __float2bfloat16(x - hf);
    hi = *(short*)&h;
    lo = *(short*)&l;
}

// ---------------------------------------------------------------------------
// LayerNorm (LN1): one block per row. Emits pre-split bf16 hi/lo.
// ---------------------------------------------------------------------------
__global__ __launch_bounds__(256) void ln_kernel(const float* __restrict__ x,
                                                 const float* __restrict__ g,
                                                 const float* __restrict__ bta,
                                                 __hip_bfloat16* __restrict__ outh,
                                                 __hip_bfloat16* __restrict__ outl) {
    const int row = blockIdx.x, tid = threadIdx.x;
    __shared__ float r1[256], r2[256];
    const float* xr = x + (long)row * CC;
    float4 xv = ((const float4*)xr)[tid];
    float s  = xv.x + xv.y + xv.z + xv.w;
    float q2 = xv.x*xv.x + xv.y*xv.y + xv.z*xv.z + xv.w*xv.w;
    r1[tid] = s; r2[tid] = q2; __syncthreads();
    for (int st = 128; st > 0; st >>= 1) {
        if (tid < st) { r1[tid] += r1[tid+st]; r2[tid] += r2[tid+st]; }
        __syncthreads();
    }
    const float mu  = r1[0] * (1.f/CC);
    const float var = r2[0] * (1.f/CC) - mu*mu;
    const float rs  = rsqrtf(var + EPSLN);
    float4 gv = ((const float4*)g)[tid];
    float4 bv = ((const float4*)bta)[tid];
    float xs[4];
    xs[0] = (xv.x-mu)*rs*gv.x + bv.x;
    xs[1] = (xv.y-mu)*rs*gv.y + bv.y;
    xs[2] = (xv.z-mu)*rs*gv.z + bv.z;
    xs[3] = (xv.w-mu)*rs*gv.w + bv.w;
    s16x4 hv, lv;
    #pragma unroll
    for (int j = 0; j < 4; j++) { short h,l; splitbf(xs[j], h, l); hv[j]=h; lv[j]=l; }
    *(s16x4*)(outh + (long)row * CC + tid*4) = hv;
    *(s16x4*)(outl + (long)row * CC + tid*4) = lv;
}

// ---------------------------------------------------------------------------
// Fused LN2 + router: LN -> h2b bf16; scores/mask/k_per_token; and per-expert
// active-token compaction lists (order-free: values don't depend on order).
// ---------------------------------------------------------------------------
__global__ __launch_bounds__(256) void ln2_router(const float* __restrict__ xio,
                                                  const float* __restrict__ g,
                                                  const float* __restrict__ bta,
                                                  const float* __restrict__ sim,
                                                  const float* __restrict__ cn,
                                                  const float* __restrict__ thr,
                                                  __hip_bfloat16* __restrict__ h2b,
                                                  float* __restrict__ scores,
                                                  float* __restrict__ kpt,
                                                  float* __restrict__ maskb,
                                                  int* __restrict__ cnt,
                                                  int* __restrict__ elist) {
    const int row = blockIdx.x, tid = threadIdx.x;
    __shared__ float r1[256], r2[256];
    __shared__ float red[256*17];
    float4 xv = ((const float4*)(xio + (long)row*CC))[tid];
    float s  = xv.x + xv.y + xv.z + xv.w;
    float q2 = xv.x*xv.x + xv.y*xv.y + xv.z*xv.z + xv.w*xv.w;
    r1[tid] = s; r2[tid] = q2; __syncthreads();
    for (int st = 128; st > 0; st >>= 1) {
        if (tid < st) { r1[tid] += r1[tid+st]; r2[tid] += r2[tid+st]; }
        __syncthreads();
    }
    const float mu  = r1[0] * (1.f/CC);
    const float var = r2[0] * (1.f/CC) - mu*mu;
    const float rs  = rsqrtf(var + EPSLN);
    float4 gv = ((const float4*)g)[tid];
    float4 bv = ((const float4*)bta)[tid];
    float ovs[4];
    ovs[0] = (xv.x-mu)*rs*gv.x + bv.x;
    ovs[1] = (xv.y-mu)*rs*gv.y + bv.y;
    ovs[2] = (xv.z-mu)*rs*gv.z + bv.z;
    ovs[3] = (xv.w-mu)*rs*gv.w + bv.w;
    {
        __hip_bfloat16* p = h2b + (long)row*CC + tid*4;
        p[0] = __float2bfloat16(ovs[0]); p[1] = __float2bfloat16(ovs[1]);
        p[2] = __float2bfloat16(ovs[2]); p[3] = __float2bfloat16(ovs[3]);
    }
    // router: this thread's 4 contiguous channels
    float acc[17] = {};
    #pragma unroll
    for (int j = 0; j < 4; j++) {
        const float v = ovs[j];
        acc[16] += v*v;
        const float* sr = sim + (long)(tid*4 + j)*EE;
        #pragma unroll
        for (int e2 = 0; e2 < EE; e2++) acc[e2] += v*sr[e2];
    }
    #pragma unroll
    for (int e2 = 0; e2 < 17; e2++) red[tid*17 + e2] = acc[e2];
    __syncthreads();
    for (int st = 128; st > 0; st >>= 1) {
        if (tid < st)
            for (int e2 = 0; e2 < 17; e2++) red[tid*17+e2] += red[(tid+st)*17+e2];
        __syncthreads();
    }
    if (tid < EE) {
        const float nrm = sqrtf(red[16]);
        const float sc  = red[tid] / (nrm * cn[tid]);
        scores[(long)row*EE + tid] = sc;
        const float mkv = sc > thr[0] ? 1.f : 0.f;
        maskb[(long)row*EE + tid] = mkv;
        red[tid] = mkv;
        if (mkv > 0.f) {
            int slot = atomicAdd(&cnt[tid], 1);
            elist[(long)tid*NN + slot] = row;
        }
    }
    __syncthreads();
    if (tid == 0) {
        float c2 = 0.f;
        for (int e2 = 0; e2 < EE; e2++) c2 += red[e2];
        kpt[row] = c2;
    }
}

// ---------------------------------------------------------------------------
// One-shot QKVO weight prep (single launch, z selects weight):
// W[K][N] fp32 -> Wt[N][K] bf16 hi + lo (bf16x3 split).
// ---------------------------------------------------------------------------
__global__ __launch_bounds__(256) void transpose_split4(const float* __restrict__ W0,
                                                        const float* __restrict__ W1,
                                                        const float* __restrict__ W2,
                                                        const float* __restrict__ W3,
                                                        __hip_bfloat16* __restrict__ Wth_base,
                                                        __hip_bfloat16* __restrict__ Wtl_base) {
    const int z = blockIdx.z;
    const float* W = (z==0) ? W0 : (z==1) ? W1 : (z==2) ? W2 : W3;
    __hip_bfloat16* Wth = Wth_base + (long)z*CC*CC;
    __hip_bfloat16* Wtl = Wtl_base + (long)z*CC*CC;
    const int n0 = blockIdx.x * 32, k0 = blockIdx.y * 32;
    __shared__ float t[32][33];
    const int tx = threadIdx.x & 31, ty = threadIdx.x >> 5;
    #pragma unroll
    for (int i = 0; i < 4; i++)
        t[ty + i*8][tx] = W[(long)(k0 + ty + i*8)*CC + n0 + tx];
    __syncthreads();
    #pragma unroll
    for (int i = 0; i < 4; i++) {
        float v = t[tx][ty + i*8];
        short h, l; splitbf(v, h, l);
        *(short*)&Wth[(long)(n0 + ty + i*8)*CC + k0 + tx] = h;
        *(short*)&Wtl[(long)(n0 + ty + i*8)*CC + k0 + tx] = l;
    }
}

// ---------------------------------------------------------------------------
// Expert weight prep (single launch): z = half*16 + e. half0: w1 [C][I] ->
// w1t [I][C]; half1: w2 [I][C] -> w2t [C][I]. Flattened grid.x = 256 blocks/e.
// ---------------------------------------------------------------------------
__global__ __launch_bounds__(256) void transpose_f2b_both(const float* __restrict__ w1,
                                                          const float* __restrict__ w2,
                                                          __hip_bfloat16* __restrict__ w1t,
                                                          __hip_bfloat16* __restrict__ w2t) {
    const int zz = blockIdx.z;
    const int half = zz >> 4, e = zz & 15;
    const float* W; __hip_bfloat16* Wt; int K, N, nbx;
    if (half == 0) { W = w1 + (long)e*CC*II; Wt = w1t + (long)e*CC*II; K = CC; N = II; nbx = II/32; }
    else           { W = w2 + (long)e*II*CC; Wt = w2t + (long)e*II*CC; K = II; N = CC; nbx = CC/32; }
    const int bx = blockIdx.x;
    const int n0 = (bx % nbx) * 32, k0 = (bx / nbx) * 32;
    __shared__ float t[32][33];
    const int tx = threadIdx.x & 31, ty = threadIdx.x >> 5;
    #pragma unroll
    for (int i = 0; i < 4; i++)
        t[ty + i*8][tx] = W[(long)(k0 + ty + i*8)*N + n0 + tx];
    __syncthreads();
    #pragma unroll
    for (int i = 0; i < 4; i++)
        Wt[(long)(n0 + ty + i*8)*K + k0 + tx] = __float2bfloat16(t[tx][ty + i*8]);
}

// ---------------------------------------------------------------------------
// bf16 transpose for V: [b*T + t][C] (hi/lo) -> [(b*H + h)*64 + d][T] (hi/lo)
// ---------------------------------------------------------------------------
__global__ __launch_bounds__(256) void transpose_v_bf16(
        const __hip_bfloat16* __restrict__ Vh, const __hip_bfloat16* __restrict__ Vl,
        __hip_bfloat16* __restrict__ Vth, __hip_bfloat16* __restrict__ Vtl) {
    const int b = blockIdx.z;
    const int c0 = blockIdx.y * 32, t0 = blockIdx.x * 32;
    __shared__ unsigned short th[32][33], tl[32][33];
    const int tx = threadIdx.x & 31, ty = threadIdx.x >> 5;
    const unsigned short* vh = (const unsigned short*)Vh;
    const unsigned short* vl = (const unsigned short*)Vl;
    #pragma unroll
    for (int i = 0; i < 4; i++) {
        const long src = ((long)b*TT + t0 + ty + i*8)*CC + c0 + tx;
        th[ty + i*8][tx] = vh[src];
        tl[ty + i*8][tx] = vl[src];
    }
    __syncthreads();
    #pragma unroll
    for (int i = 0; i < 4; i++) {
        const int gc = c0 + ty + i*8;          // global channel
        const int hh = gc >> 6, d = gc & 63;
        const long dst = ((long)(b*HH + hh)*64 + d)*TT + t0 + tx;
        ((unsigned short*)Vth)[dst] = th[tx][ty + i*8];
        ((unsigned short*)Vtl)[dst] = tl[tx][ty + i*8];
    }
}

// ---------------------------------------------------------------------------
// Big-tile bf16x3 split GEMM (QKV): 128Mx128N, BK=32, 4 waves each 64x64.
// Staging via global_load_lds width=16 (direct HBM->LDS, no VGPR round trip).
// LDS is LINEAR [128][32] (required: dest = wave-uniform base + lane*16).
// Emits pre-split bf16 hi/lo. Same bytes, same MFMA order -> bit-identical.
// ---------------------------------------------------------------------------
__global__ __launch_bounds__(256, 2) void gemm_split_big(
        const __hip_bfloat16* __restrict__ Ah,
        const __hip_bfloat16* __restrict__ Al,
        const __hip_bfloat16* __restrict__ Bh_base,
        const __hip_bfloat16* __restrict__ Bl_base,
        __hip_bfloat16* __restrict__ Ch_base,
        __hip_bfloat16* __restrict__ Cl_base,
        int M, int N, int K) {
    __shared__ __hip_bfloat16 Ash[128][32], Asl[128][32];
    __shared__ __hip_bfloat16 Bsh[128][32], Bsl[128][32];
    const int z = blockIdx.z;
    const __hip_bfloat16* Bth = Bh_base + (long)z * N * K;
    const __hip_bfloat16* Btl = Bl_base + (long)z * N * K;
    const int n0 = blockIdx.x * 128, m0 = blockIdx.y * 128;
    const int tid = threadIdx.x;
    const int wave = tid >> 6, lane = tid & 63;
    const int wm = (wave >> 1) * 64, wn = (wave & 1) * 64;
    const int l15 = lane & 15, quad = lane >> 4;

    f32x4 acc[4][4] = {};

    for (int k0 = 0; k0 < K; k0 += 32) {
        // stage 4 buffers: each = 128 rows x 32 k x 2B = 8 KB = 8 wave-loads.
        // wave w issues chunks {2w, 2w+1}; lane maps row=(lane>>2), col=(lane&3)*8.
        #pragma unroll
        for (int i = 0; i < 2; i++) {
            const int chunk = wave*2 + i;              // 0..7
            const int r = chunk*16 + (lane >> 2);
            const int c8 = (lane & 3) * 8;
            const long aoff = (long)(m0 + r)*K + k0 + c8;
            const long boff = (long)(n0 + r)*K + k0 + c8;
            GLOAD_LDS16(Ah  + aoff, &Ash[chunk*16][0]);
            GLOAD_LDS16(Al  + aoff, &Asl[chunk*16][0]);
            GLOAD_LDS16(Bth + boff, &Bsh[chunk*16][0]);
            GLOAD_LDS16(Btl + boff, &Bsl[chunk*16][0]);
        }
        __syncthreads();
        short8 ah[4], al[4], bh[4], bl[4];
        #pragma unroll
        for (int i = 0; i < 4; i++) {
            ah[i] = *(const short8*)&Ash[wm + i*16 + l15][quad*8];
            al[i] = *(const short8*)&Asl[wm + i*16 + l15][quad*8];
            bh[i] = *(const short8*)&Bsh[wn + i*16 + l15][quad*8];
            bl[i] = *(const short8*)&Bsl[wn + i*16 + l15][quad*8];
        }
        #pragma unroll
        for (int mi = 0; mi < 4; mi++)
            #pragma unroll
            for (int ni = 0; ni < 4; ni++) {
                acc[mi][ni] = __builtin_amdgcn_mfma_f32_16x16x32_bf16(ah[mi], bh[ni], acc[mi][ni], 0,0,0);
                acc[mi][ni] = __builtin_amdgcn_mfma_f32_16x16x32_bf16(ah[mi], bl[ni], acc[mi][ni], 0,0,0);
                acc[mi][ni] = __builtin_amdgcn_mfma_f32_16x16x32_bf16(al[mi], bh[ni], acc[mi][ni], 0,0,0);
            }
        __syncthreads();
    }

    #pragma unroll
    for (int mi = 0; mi < 4; mi++)
        #pragma unroll
        for (int r = 0; r < 4; r++) {
            const int row = m0 + wm + mi*16 + quad*4 + r;
            #pragma unroll
            for (int ni = 0; ni < 4; ni++) {
                const int col = n0 + wn + ni*16 + l15;
                short hh, ll; splitbf(acc[mi][ni][r], hh, ll);
                *(short*)&Ch_base[(long)z*M*N + (long)row*N + col] = hh;
                *(short*)&Cl_base[(long)z*M*N + (long)row*N + col] = ll;
            }
        }
}

// ---------------------------------------------------------------------------
// fp32-accurate MFMA GEMM via bf16x3 split, 64Mx128N tile (WO path), with
// global_load_lds staging (linear LDS).
// ---------------------------------------------------------------------------
__global__ __launch_bounds__(256, 2) void gemm_split(
        const __hip_bfloat16* __restrict__ Ah,
        const __hip_bfloat16* __restrict__ Al,
        const __hip_bfloat16* __restrict__ Bth,
        const __hip_bfloat16* __restrict__ Btl,
        float* __restrict__ Cp,
        int M, int N, int K,
        const float* __restrict__ resid) {
    __shared__ __hip_bfloat16 Ash[64][32], Asl[64][32];
    __shared__ __hip_bfloat16 Bsh[128][32], Bsl[128][32];
    const int n0 = blockIdx.x * 128, m0 = blockIdx.y * 64;
    const int tid = threadIdx.x;
    const int wave = tid >> 6, lane = tid & 63;
    const int wm = (wave >> 1) * 32, wn = (wave & 1) * 64;
    const int l15 = lane & 15, quad = lane >> 4;

    f32x4 acc[2][4] = {};

    for (int k0 = 0; k0 < K; k0 += 32) {
        {   // A: 64x32 = 4KB/buffer = 4 wave-loads; wave w stages chunk w
            const int r = wave*16 + (lane >> 2);
            const int c8 = (lane & 3) * 8;
            const long aoff = (long)(m0 + r)*K + k0 + c8;
            GLOAD_LDS16(Ah + aoff, &Ash[wave*16][0]);
            GLOAD_LDS16(Al + aoff, &Asl[wave*16][0]);
        }
        #pragma unroll
        for (int i = 0; i < 2; i++) {   // B: 128x32 = 8KB/buffer = 8 wave-loads
            const int chunk = wave*2 + i;
            const int r = chunk*16 + (lane >> 2);
            const int c8 = (lane & 3) * 8;
            const long boff = (long)(n0 + r)*K + k0 + c8;
            GLOAD_LDS16(Bth + boff, &Bsh[chunk*16][0]);
            GLOAD_LDS16(Btl + boff, &Bsl[chunk*16][0]);
        }
        __syncthreads();
        short8 ah[2], al[2], bh[4], bl[4];
        #pragma unroll
        for (int mi = 0; mi < 2; mi++) {
            ah[mi] = *(const short8*)&Ash[wm + mi*16 + l15][quad*8];
            al[mi] = *(const short8*)&Asl[wm + mi*16 + l15][quad*8];
        }
        #pragma unroll
        for (int ni = 0; ni < 4; ni++) {
            bh[ni] = *(const short8*)&Bsh[wn + ni*16 + l15][quad*8];
            bl[ni] = *(const short8*)&Bsl[wn + ni*16 + l15][quad*8];
        }
        #pragma unroll
        for (int mi = 0; mi < 2; mi++)
            #pragma unroll
            for (int ni = 0; ni < 4; ni++) {
                acc[mi][ni] = __builtin_amdgcn_mfma_f32_16x16x32_bf16(ah[mi], bh[ni], acc[mi][ni], 0,0,0);
                acc[mi][ni] = __builtin_amdgcn_mfma_f32_16x16x32_bf16(ah[mi], bl[ni], acc[mi][ni], 0,0,0);
                acc[mi][ni] = __builtin_amdgcn_mfma_f32_16x16x32_bf16(al[mi], bh[ni], acc[mi][ni], 0,0,0);
            }
        __syncthreads();
    }

    #pragma unroll
    for (int mi = 0; mi < 2; mi++)
        #pragma unroll
        for (int r = 0; r < 4; r++) {
            const int row = m0 + wm + mi*16 + quad*4 + r;
            #pragma unroll
            for (int ni = 0; ni < 4; ni++) {
                const int col = n0 + wn + ni*16 + l15;
                Cp[(long)row*N + col] = acc[mi][ni][r] + resid[(long)row*N + col];
            }
        }
}

// ---------------------------------------------------------------------------
// Sparse expert GEMM1: mid[e][slot] = gelu(h2b[tok(slot)] @ w1t[e]^T), bf16.
// global_load_lds staging; A rows gathered via per-lane source addresses
// (rowmap cached in VGPRs). Blocks beyond cnt[e] exit.
// ---------------------------------------------------------------------------
__global__ __launch_bounds__(256) void gemm_moe1_sparse(
        const __hip_bfloat16* __restrict__ A,      // h2b [NN][CC]
        const __hip_bfloat16* __restrict__ w1t,    // [16][II][CC]
        __hip_bfloat16* __restrict__ mid,          // [16][NN][II] compacted
        const int* __restrict__ cnt,
        const int* __restrict__ elist) {
    __shared__ __hip_bfloat16 As[128][32];
    __shared__ __hip_bfloat16 Bs[128][32];
    __shared__ int rowmap[128];
    const int e = blockIdx.z;
    const int count = cnt[e];
    const int m0 = blockIdx.y * 128;
    if (m0 >= count) return;
    const int n0 = blockIdx.x * 128;
    const __hip_bfloat16* Bt = w1t + (long)e*II*CC;
    const int* lst = elist + (long)e*NN;
    const int tid = threadIdx.x;
    if (tid < 128) rowmap[tid] = lst[min(m0 + tid, count - 1)];
    __syncthreads();
    const int wave = tid >> 6, lane = tid & 63;
    const int wm = (wave >> 1) * 64, wn = (wave & 1) * 64;
    const int l15 = lane & 15, quad = lane >> 4;
    // cache this lane's 2 gather rows (for staging chunks wave*2, wave*2+1)
    int rm[2];
    #pragma unroll
    for (int i = 0; i < 2; i++) rm[i] = rowmap[(wave*2 + i)*16 + (lane >> 2)];

    f32x4 acc[4][4] = {};

    for (int k0 = 0; k0 < CC; k0 += 32) {
        #pragma unroll
        for (int i = 0; i < 2; i++) {
            const int chunk = wave*2 + i;
            const int r = chunk*16 + (lane >> 2);
            const int c8 = (lane & 3) * 8;
            GLOAD_LDS16(A  + (long)rm[i]*CC + k0 + c8, &As[chunk*16][0]);
            GLOAD_LDS16(Bt + (long)(n0 + r)*CC + k0 + c8, &Bs[chunk*16][0]);
        }
        __syncthreads();
        short8 af[4], bff[4];
        #pragma unroll
        for (int i = 0; i < 4; i++) {
            af[i]  = *(const short8*)&As[wm + i*16 + l15][quad*8];
            bff[i] = *(const short8*)&Bs[wn + i*16 + l15][quad*8];
        }
        #pragma unroll
        for (int mi = 0; mi < 4; mi++)
            #pragma unroll
            for (int ni = 0; ni < 4; ni++)
                acc[mi][ni] = __builtin_amdgcn_mfma_f32_16x16x32_bf16(
                                  af[mi], bff[ni], acc[mi][ni], 0, 0, 0);
        __syncthreads();
    }

    #pragma unroll
    for (int mi = 0; mi < 4; mi++) {
        #pragma unroll
        for (int r = 0; r < 4; r++) {
            const int slot = m0 + wm + mi*16 + quad*4 + r;
            if (slot < count) {
                #pragma unroll
                for (int ni = 0; ni < 4; ni++) {
                    const int col = n0 + wn + ni*16 + l15;
                    float val = acc[mi][ni][r];
                    val = 0.5f*val*(1.f + erff(val*0.70710678118f));
                    mid[((long)e*NN + slot)*II + col] = __float2bfloat16(val);
                }
            }
        }
    }
}

// ---------------------------------------------------------------------------
// Sparse expert GEMM2: eo[tok(slot), e, :] = mid[e][slot] @ w2t[e]^T
// global_load_lds staging (both operands contiguous). No atomics.
// ---------------------------------------------------------------------------
__global__ __launch_bounds__(256) void gemm_moe2_sparse(
        const __hip_bfloat16* __restrict__ mid,    // [16][NN][II] compacted
        const __hip_bfloat16* __restrict__ w2t,    // [16][CC][II]
        float* __restrict__ eo,                    // [NN][EE][CC]
        const int* __restrict__ cnt,
        const int* __restrict__ elist) {
    __shared__ __hip_bfloat16 As[128][32];
    __shared__ __hip_bfloat16 Bs[128][32];
    __shared__ int rowmap[128];
    const int e = blockIdx.z;
    const int count = cnt[e];
    const int m0 = blockIdx.y * 128;
    if (m0 >= count) return;
    const int n0 = blockIdx.x * 128;
    const __hip_bfloat16* A  = mid + (long)e*NN*II;
    const __hip_bfloat16* Bt = w2t + (long)e*CC*II;
    const int* lst = elist + (long)e*NN;
    const int tid = threadIdx.x;
    if (tid < 128) rowmap[tid] = lst[min(m0 + tid, count - 1)];
    __syncthreads();
    const int wave = tid >> 6, lane = tid & 63;
    const int wm = (wave >> 1) * 64, wn = (wave & 1) * 64;
    const int l15 = lane & 15, quad = lane >> 4;

    f32x4 acc[4][4] = {};

    for (int k0 = 0; k0 < II; k0 += 32) {
        #pragma unroll
        for (int i = 0; i < 2; i++) {
            const int chunk = wave*2 + i;
            const int r = chunk*16 + (lane >> 2);
            const int c8 = (lane & 3) * 8;
            GLOAD_LDS16(A  + (long)(m0 + r)*II + k0 + c8, &As[chunk*16][0]);
            GLOAD_LDS16(Bt + (long)(n0 + r)*II + k0 + c8, &Bs[chunk*16][0]);
        }
        __syncthreads();
        short8 af[4], bff[4];
        #pragma unroll
        for (int i = 0; i < 4; i++) {
            af[i]  = *(const short8*)&As[wm + i*16 + l15][quad*8];
            bff[i] = *(const short8*)&Bs[wn + i*16 + l15][quad*8];
        }
        #pragma unroll
        for (int mi = 0; mi < 4; mi++)
            #pragma unroll
            for (int ni = 0; ni < 4; ni++)
                acc[mi][ni] = __builtin_amdgcn_mfma_f32_16x16x32_bf16(
                                  af[mi], bff[ni], acc[mi][ni], 0, 0, 0);
        __syncthreads();
    }

    #pragma unroll
    for (int mi = 0; mi < 4; mi++) {
        #pragma unroll
        for (int r = 0; r < 4; r++) {
            const int slot = m0 + wm + mi*16 + quad*4 + r;
            if (slot < count) {
                const int tok = rowmap[wm + mi*16 + quad*4 + r];
                #pragma unroll
                for (int ni = 0; ni < 4; ni++) {
                    const int col = n0 + wn + ni*16 + l15;
                    eo[((long)tok*EE + e)*CC + col] = acc[mi][ni][r];
                }
            }
        }
    }
}

// ---------------------------------------------------------------------------
// Fused: zero inactive eo rows + final[n,:] = sum over active e of eo[n,e,:];
// xio += final. Deterministic e-ascending order (skipping exact zeros is
// bitwise-identical to summing them).
// ---------------------------------------------------------------------------
__global__ __launch_bounds__(256) void moe_sum_zero(const float* __restrict__ maskb,
                                                    float* __restrict__ eo,
                                                    float* __restrict__ xio) {
    const int row = blockIdx.x, tid = threadIdx.x;
    float4 s = {0.f, 0.f, 0.f, 0.f};
    const float4 z4 = {0.f, 0.f, 0.f, 0.f};
    #pragma unroll
    for (int e = 0; e < EE; e++) {
        float4* p = ((float4*)(eo + ((long)row*EE + e)*CC)) + tid;
        if (maskb[(long)row*EE + e] != 0.f) {
            float4 v = *p;
            s.x += v.x; s.y += v.y; s.z += v.z; s.w += v.w;
        } else {
            *p = z4;
        }
    }
    float4 xv = ((float4*)(xio + (long)row*CC))[tid];
    xv.x += s.x; xv.y += s.y; xv.z += s.z; xv.w += s.w;
    ((float4*)(xio + (long)row*CC))[tid] = xv;
}

// ---------------------------------------------------------------------------
// Flash attention with bf16x3 MFMA for QK^T and PV. kt-split for balance.
// All inputs PRE-SPLIT bf16 hi/lo; V pre-transposed [(b*H+h)*64+d][T].
// ---------------------------------------------------------------------------
__global__ __launch_bounds__(256, 4) void attn_split(
        const __hip_bfloat16* __restrict__ Qh, const __hip_bfloat16* __restrict__ Ql,
        const __hip_bfloat16* __restrict__ Kh, const __hip_bfloat16* __restrict__ Kl,
        const __hip_bfloat16* __restrict__ Vtg_h, const __hip_bfloat16* __restrict__ Vtg_l,
        float* __restrict__ Opart,
        float* __restrict__ mpart,
        float* __restrict__ lpart) {
    __shared__ __hip_bfloat16 KPh[64][LDA], KPl[64][LDA];   // K, then P
    __shared__ __hip_bfloat16 Vth[64][LDA], Vtl[64][LDA];   // V^T [d][kk]

    const int bx = blockIdx.x;                 // 0..31, heavy qt first
    const int qt = 15 - (bx >> 1), half = bx & 1;
    const int h = blockIdx.y, b = blockIdx.z;
    const int tid = threadIdx.x;
    const int wave = tid >> 6, lane = tid & 63;
    const int l15 = lane & 15, quad = lane >> 4;
    const int wm = wave * 16;                  // wave's 16 q-rows in the 64-tile
    const long tbase = (long)b * TT * CC + (long)h * DD;          // [token][C] slab
    const long vbase = (long)(b*HH + h) * 64 * TT;                // V^T slab
    const int pidx = ((b*HH + h)*16 + qt)*2 + half;
    float* Op = Opart + (long)pidx * 4096;

    const int n_kt = qt + 1, mid_kt = (n_kt + 1) >> 1;
    const int kt_lo = half ? mid_kt : 0;
    const int kt_hi = half ? n_kt   : mid_kt;

    if (kt_lo >= kt_hi) {      // empty half (qt=0): neutral partials
        for (int i = tid; i < 64*64; i += 256) Op[i] = 0.f;
        if (tid < 64) { mpart[(long)pidx*64 + tid] = -1e30f; lpart[(long)pidx*64 + tid] = 0.f; }
        return;
    }

    // Q A-fragments direct from pre-split global
    short8 qh[2], ql[2];
    {
        const long qoff = tbase + (long)(qt*64 + wm + l15)*CC;
        #pragma unroll
        for (int kc = 0; kc < 2; kc++) {
            qh[kc] = *(const short8*)(Qh + qoff + kc*32 + quad*8);
            ql[kc] = *(const short8*)(Ql + qoff + kc*32 + quad*8);
        }
    }

    f32x4 oacc[4] = {};            // 4 d-tiles, rows = quad*4+reg
    float m_run[4], l_run[4];
    #pragma unroll
    for (int r = 0; r < 4; r++) { m_run[r] = -1e30f; l_run[r] = 0.f; }

    for (int kt = kt_lo; kt < kt_hi; kt++) {
        __syncthreads();           // prev-iter PV reads of KP/Vt done
        #pragma unroll
        for (int it = 0; it < 2; it++) {
            const int idx = tid + it*256;
            const int r = idx >> 3, g = (idx & 7)*8;
            const long koff = tbase + (long)(kt*64 + r)*CC + g;
            const long voff = vbase + (long)r*TT + kt*64 + g;
            *(short8*)&KPh[r][g] = *(const short8*)(Kh + koff);
            *(short8*)&KPl[r][g] = *(const short8*)(Kl + koff);
            *(short8*)&Vth[r][g] = *(const short8*)(Vtg_h + voff);
            *(short8*)&Vtl[r][g] = *(const short8*)(Vtg_l + voff);
        }
        __syncthreads();

        // QK^T via MFMA: 4 key-tiles x 2 k-chunks x 3 split terms
        f32x4 s[4] = {};
        #pragma unroll
        for (int nt = 0; nt < 4; nt++)
            #pragma unroll
            for (int kc = 0; kc < 2; kc++) {
                short8 bh = *(const short8*)&KPh[nt*16 + l15][kc*32 + quad*8];
                short8 bl = *(const short8*)&KPl[nt*16 + l15][kc*32 + quad*8];
                s[nt] = __builtin_amdgcn_mfma_f32_16x16x32_bf16(qh[kc], bh, s[nt], 0,0,0);
                s[nt] = __builtin_amdgcn_mfma_f32_16x16x32_bf16(qh[kc], bl, s[nt], 0,0,0);
                s[nt] = __builtin_amdgcn_mfma_f32_16x16x32_bf16(ql[kc], bh, s[nt], 0,0,0);
            }

        // online softmax in regs; row = wm + quad*4 + r, col = nt*16 + l15
        const bool diag = (kt == qt);
        float alpha[4];
        float pr[4][4];
        #pragma unroll
        for (int r = 0; r < 4; r++) {
            const int rowg = wm + quad*4 + r;
            float sv[4], mx = -1e30f;
            #pragma unroll
            for (int nt = 0; nt < 4; nt++) {
                float val = s[nt][r] * 0.125f;
                if (diag && (nt*16 + l15) > rowg) val = -1e30f;
                sv[nt] = val;
                mx = fmaxf(mx, val);
            }
            #pragma unroll
            for (int off = 1; off < 16; off <<= 1) mx = fmaxf(mx, __shfl_xor(mx, off, 16));
            const float mnew = fmaxf(m_run[r], mx);
            alpha[r] = __expf(m_run[r] - mnew);
            float rs = 0.f;
            #pragma unroll
            for (int nt = 0; nt < 4; nt++) {
                float p = __expf(sv[nt] - mnew);
                pr[r][nt] = p;
                rs += p;
            }
            #pragma unroll
            for (int off = 1; off < 16; off <<= 1) rs += __shfl_xor(rs, off, 16);
            l_run[r] = l_run[r]*alpha[r] + rs;
            m_run[r] = mnew;
        }
        __syncthreads();           // all QK reads of KP done -> overwrite as P

        // write P split into KP region: row = wm+quad*4+r, col = nt*16+l15
        #pragma unroll
        for (int r = 0; r < 4; r++)
            #pragma unroll
            for (int nt = 0; nt < 4; nt++) {
                short hh, ll; splitbf(pr[r][nt], hh, ll);
                *(short*)&KPh[wm + quad*4 + r][nt*16 + l15] = hh;
                *(short*)&KPl[wm + quad*4 + r][nt*16 + l15] = ll;
            }
        // no barrier: PV reads only this wave's own 16 P-rows

        // rescale O and accumulate PV via MFMA
        #pragma unroll
        for (int dt = 0; dt < 4; dt++)
            #pragma unroll
            for (int r = 0; r < 4; r++)
                oacc[dt][r] *= alpha[r];
        #pragma unroll
        for (int kc = 0; kc < 2; kc++) {
            short8 ph = *(const short8*)&KPh[wm + l15][kc*32 + quad*8];
            short8 pl = *(const short8*)&KPl[wm + l15][kc*32 + quad*8];
            #pragma unroll
            for (int dt = 0; dt < 4; dt++) {
                short8 vh = *(const short8*)&Vth[dt*16 + l15][kc*32 + quad*8];
                short8 vl = *(const short8*)&Vtl[dt*16 + l15][kc*32 + quad*8];
                oacc[dt] = __builtin_amdgcn_mfma_f32_16x16x32_bf16(ph, vh, oacc[dt], 0,0,0);
                oacc[dt] = __builtin_amdgcn_mfma_f32_16x16x32_bf16(ph, vl, oacc[dt], 0,0,0);
                oacc[dt] = __builtin_amdgcn_mfma_f32_16x16x32_bf16(pl, vh, oacc[dt], 0,0,0);
            }
        }
    }

    // store unnormalized O partial + (m,l)
    #pragma unroll
    for (int dt = 0; dt < 4; dt++)
        #pragma unroll
        for (int r = 0; r < 4; r++)
            Op[(wm + quad*4 + r)*64 + dt*16 + l15] = oacc[dt][r];
    if (l15 == 0) {
        #pragma unroll
        for (int r = 0; r < 4; r++) {
            mpart[(long)pidx*64 + wm + quad*4 + r] = m_run[r];
            lpart[(long)pidx*64 + wm + quad*4 + r] = l_run[r];
        }
    }
}

// ---------------------------------------------------------------------------
// Merge the two kt-half partials -> normalized attention output, emitted as
// pre-split bf16 hi/lo (direct feed for the WO bf16x3 GEMM).
// ---------------------------------------------------------------------------
__global__ __launch_bounds__(256) void attn_merge(const float* __restrict__ Opart,
                                                  const float* __restrict__ mpart,
                                                  const float* __restrict__ lpart,
                                                  __hip_bfloat16* __restrict__ aoh,
                                                  __hip_bfloat16* __restrict__ aol) {
    const int qt = blockIdx.x, h = blockIdx.y, b = blockIdx.z;
    const int pA = ((b*HH + h)*16 + qt)*2, pB = pA + 1;
    const int tid = threadIdx.x;
    const int r = tid >> 2, c0 = (tid & 3) * 16;
    const float mA = mpart[(long)pA*64 + r], mB = mpart[(long)pB*64 + r];
    const float lA = lpart[(long)pA*64 + r], lB = lpart[(long)pB*64 + r];
    const float M  = fmaxf(mA, mB);
    const float wA = __expf(mA - M), wB = __expf(mB - M);
    const float inv = 1.f / (lA*wA + lB*wB);
    const float* OA = Opart + (long)pA*4096 + r*64 + c0;
    const float* OB = Opart + (long)pB*4096 + r*64 + c0;
    const long dst = (long)b*TT*CC + (long)(qt*64 + r)*CC + h*DD + c0;
    #pragma unroll
    for (int j = 0; j < 16; j += 4) {
        float4 oa = *(const float4*)(OA + j);
        float4 ob = *(const float4*)(OB + j);
        float xs[4];
        xs[0] = (oa.x*wA + ob.x*wB)*inv;
        xs[1] = (oa.y*wA + ob.y*wB)*inv;
        xs[2] = (oa.z*wA + ob.z*wB)*inv;
        xs[3] = (oa.w*wA + ob.w*wB)*inv;
        s16x4 hv, lv;
        #pragma unroll
        for (int t = 0; t < 4; t++) { short hh,ll; splitbf(xs[t],hh,ll); hv[t]=hh; lv[t]=ll; }
        *(s16x4*)(aoh + dst + j) = hv;
        *(s16x4*)(aol + dst + j) = lv;
    }
}

// ---------------------------------------------------------------------------
// Column norms of sim_matrix [C, E]; also zeros the compaction counters.
// ---------------------------------------------------------------------------
__global__ __launch_bounds__(256) void colnorm_kernel(const float* __restrict__ sim,
                                                      float* __restrict__ cn,
                                                      int* __restrict__ cnt) {
    const int e = blockIdx.x, tid = threadIdx.x;
    __shared__ float red[256];
    float s = 0.f;
    for (int c = tid; c < CC; c += 256) {
        float vv = sim[(long)c*EE + e];
        s += vv*vv;
    }
    red[tid] = s; __syncthreads();
    for (int st = 128; st > 0; st >>= 1) {
        if (tid < st) red[tid] += red[tid+st];
        __syncthreads();
    }
    if (tid == 0) { cn[e] = sqrtf(red[0]); cnt[e] = 0; }
}

// ---------------------------------------------------------------------------
extern "C" void kernel_launch(void* const* d_in, const int* in_sizes, int n_in,
                              void* d_out, int out_size, void* d_ws, size_t ws_size,
                              hipStream_t stream) {
    const float* x     = (const float*)d_in[0];
    const float* ln1_g = (const float*)d_in[1];
    const float* ln1_b = (const float*)d_in[2];
    const float* ln2_g = (const float*)d_in[3];
    const float* ln2_b = (const float*)d_in[4];
    const float* wq    = (const float*)d_in[5];
    const float* wk    = (const float*)d_in[6];
    const float* wv    = (const float*)d_in[7];
    const float* wo    = (const float*)d_in[8];
    const float* sim   = (const float*)d_in[9];
    const float* thr   = (const float*)d_in[10];
    const float* w1    = (const float*)d_in[11];
    const float* w2    = (const float*)d_in[12];

    float* out_x      = (float*)d_out;
    float* out_scores = out_x + (long)NN*CC;
    float* out_eo     = out_scores + (long)NN*EE;
    float* out_kpt    = out_eo + (long)NN*EE*CC;

    const long MF = (long)NN*CC;     // 2M floats
    const long CK = (long)CC*CC;     // 1M elems per weight slab
    float* ws   = (float*)d_ws;
    // [0, MF): attn-out split bf16 (hi/lo)
    __hip_bfloat16* aoh = (__hip_bfloat16*)ws;
    __hip_bfloat16* aol = (__hip_bfloat16*)(ws + MF/2);
    // [MF, 4MF): QKV pre-split bf16 (3 slabs hi, 3 slabs lo)
    __hip_bfloat16* qkvh = (__hip_bfloat16*)(ws + MF);
    __hip_bfloat16* qkvl = (__hip_bfloat16*)(ws + MF + 3*MF/2);
    // [4MF, 5MF): V^T pre-split bf16
    __hip_bfloat16* vth = (__hip_bfloat16*)(ws + 4*MF);
    __hip_bfloat16* vtl = (__hip_bfloat16*)(ws + 4*MF + MF/2);
    // [5MF, 5.5MF): LN2 bf16 for expert GEMM
    __hip_bfloat16* h2b = (__hip_bfloat16*)(ws + 5*MF);
    // [5.5MF, 7.5MF): attn partials; hh/hl (LN1 split) + mid alias
    float* Opart = ws + 5*MF + MF/2;
    __hip_bfloat16* hh  = (__hip_bfloat16*)(ws + 5*MF + MF/2);       // dead after QKV GEMM
    __hip_bfloat16* hl  = (__hip_bfloat16*)(ws + 6*MF);
    __hip_bfloat16* mid = (__hip_bfloat16*)(ws + 5*MF + MF/2);       // after merge
    // [7.5MF, 9.5MF): QKVO weight splits; w1t/w2t alias (after WO GEMM)
    __hip_bfloat16* wsph = (__hip_bfloat16*)(ws + 7*MF + MF/2);      // [4][C][C] hi
    __hip_bfloat16* wspl = (__hip_bfloat16*)(ws + 8*MF + MF/2);      // [4][C][C] lo
    __hip_bfloat16* w1t  = (__hip_bfloat16*)(ws + 7*MF + MF/2);
    __hip_bfloat16* w2t  = (__hip_bfloat16*)(ws + 8*MF + MF/2);
    float* maskb = ws + 9*MF + MF/2;                                  // 32K floats
    float* cn    = maskb + (long)NN*EE;                               // 16
    float* mpart = cn + 16;                                           // 64K
    float* lpart = mpart + 1024L*64;                                  // 64K
    int*   cnt   = (int*)(lpart + 1024L*64);                          // 16 ints
    int*   elist = cnt + 16;                                          // EE*NN ints

    // 0. sim column norms + zero compaction counters
    colnorm_kernel<<<EE, 256, 0, stream>>>(sim, cn, cnt);

    // 1. one-shot QKVO weight transpose + bf16x3 split (single launch)
    {
        dim3 gt(CC/32, CC/32, 4);
        transpose_split4<<<gt, 256, 0, stream>>>(wq, wk, wv, wo, wsph, wspl);
    }

    // 2. LN1 -> pre-split bf16 hi/lo
    ln_kernel<<<NN, 256, 0, stream>>>(x, ln1_g, ln1_b, hh, hl);

    // 3. fused QKV projection, 128x128 tile, global_load_lds staging
    {
        dim3 gq(CC/128, NN/128, 3);
        gemm_split_big<<<gq, 256, 0, stream>>>(hh, hl, wsph, wspl,
                                               qkvh, qkvl, NN, CC, CC);
    }

    // 3.5 V transpose (bf16 hi/lo): [token][C] -> per-(b,h) [d][T]
    {
        dim3 gv(TT/32, CC/32, BB);
        transpose_v_bf16<<<gv, 256, 0, stream>>>(qkvh + 2*(long)NN*CC, qkvl + 2*(long)NN*CC,
                                                 vth, vtl);
    }

    // 4. causal attention (MFMA flash, kt-split, pre-split inputs) + merge
    {
        dim3 gattn(32, HH, BB);
        attn_split<<<gattn, 256, 0, stream>>>(qkvh, qkvl,
                                              qkvh + (long)NN*CC, qkvl + (long)NN*CC,
                                              vth, vtl, Opart, mpart, lpart);
        dim3 gmerge(16, HH, BB);
        attn_merge<<<gmerge, 256, 0, stream>>>(Opart, mpart, lpart, aoh, aol);
    }

    // 5. output projection + residual -> d_out x slot (gload_lds staging)
    {
        dim3 go(CC/128, NN/64, 1);
        gemm_split<<<go, 256, 0, stream>>>(aoh, aol, wsph + 3*CK, wspl + 3*CK,
                                           out_x, NN, CC, CC, x);
    }

    // 6. expert weight transposes (single launch; safe to overwrite QKVO splits)
    {
        dim3 ge(256, 1, 2*EE);
        transpose_f2b_both<<<ge, 256, 0, stream>>>(w1, w2, w1t, w2t);
    }

    // 7. fused LN2 + router + active-token compaction
    ln2_router<<<NN, 256, 0, stream>>>(out_x, ln2_g, ln2_b, sim, cn, thr,
                                       h2b, out_scores, out_kpt, maskb,
                                       cnt, elist);

    // 8. sparse expert GEMM 1: mid[e][slot] = gelu(h2[tok] @ w1[e])
    {
        dim3 g(II/128, NN/128, EE);
        gemm_moe1_sparse<<<g, 256, 0, stream>>>(h2b, w1t, mid, cnt, elist);
    }

    // 9. sparse expert GEMM 2: eo[tok,e,:] = mid[e][slot] @ w2[e]
    {
        dim3 g(CC/128, NN/128, EE);
        gemm_moe2_sparse<<<g, 256, 0, stream>>>(mid, w2t, out_eo, cnt, elist);
    }

    // 10. fused: zero inactive eo rows + sum active -> x (deterministic order)
    moe_sum_zero<<<NN, 256, 0, stream>>>(maskb, out_eo, out_x);
}

// Round 9
// 453.961 us; speedup vs baseline: 1.0705x; 1.0042x over previous
//
#include <hip/hip_runtime.h>
#include <hip/hip_bf16.h>
#include <math.h>

// Problem constants
#define BB 2
#define TT 1024
#define CC 1024
#define HH 16
#define DD 64
#define EE 16
#define II 256
#define NN (BB*TT)          // 2048 tokens
#define EPSLN 1e-5f
#define LDA 72              // bf16 LDS row stride: 144B rows, 16B-aligned

typedef __attribute__((ext_vector_type(8))) short short8;
typedef __attribute__((ext_vector_type(4))) short s16x4;
typedef __attribute__((ext_vector_type(4))) float f32x4;

// Direct global->LDS 16B copy: LDS dest = uniform base + lane*16.
#define GLOAD_LDS16(g, l) \
    __builtin_amdgcn_global_load_lds((const __attribute__((address_space(1))) void*)(g), \
                                     (__attribute__((address_space(3))) void*)(l), 16, 0, 0)

__device__ inline void splitbf(float x, short& hi, short& lo) {
    __hip_bfloat16 h = __float2bfloat16(x);
    float hf = __bfloat162float(h);
    __hip_bfloat16 l = __float2bfloat16(x - hf);
    hi = *(short*)&h;
    lo = *(short*)&l;
}

// ---------------------------------------------------------------------------
// LayerNorm (LN1): one block per row. Emits pre-split bf16 hi/lo.
// ---------------------------------------------------------------------------
__global__ __launch_bounds__(256) void ln_kernel(const float* __restrict__ x,
                                                 const float* __restrict__ g,
                                                 const float* __restrict__ bta,
                                                 __hip_bfloat16* __restrict__ outh,
                                                 __hip_bfloat16* __restrict__ outl) {
    const int row = blockIdx.x, tid = threadIdx.x;
    __shared__ float r1[256], r2[256];
    const float* xr = x + (long)row * CC;
    float4 xv = ((const float4*)xr)[tid];
    float s  = xv.x + xv.y + xv.z + xv.w;
    float q2 = xv.x*xv.x + xv.y*xv.y + xv.z*xv.z + xv.w*xv.w;
    r1[tid] = s; r2[tid] = q2; __syncthreads();
    for (int st = 128; st > 0; st >>= 1) {
        if (tid < st) { r1[tid] += r1[tid+st]; r2[tid] += r2[tid+st]; }
        __syncthreads();
    }
    const float mu  = r1[0] * (1.f/CC);
    const float var = r2[0] * (1.f/CC) - mu*mu;
    const float rs  = rsqrtf(var + EPSLN);
    float4 gv = ((const float4*)g)[tid];
    float4 bv = ((const float4*)bta)[tid];
    float xs[4];
    xs[0] = (xv.x-mu)*rs*gv.x + bv.x;
    xs[1] = (xv.y-mu)*rs*gv.y + bv.y;
    xs[2] = (xv.z-mu)*rs*gv.z + bv.z;
    xs[3] = (xv.w-mu)*rs*gv.w + bv.w;
    s16x4 hv, lv;
    #pragma unroll
    for (int j = 0; j < 4; j++) { short h,l; splitbf(xs[j], h, l); hv[j]=h; lv[j]=l; }
    *(s16x4*)(outh + (long)row * CC + tid*4) = hv;
    *(s16x4*)(outl + (long)row * CC + tid*4) = lv;
}

// ---------------------------------------------------------------------------
// Fused LN2 + router: LN -> h2b bf16; scores/mask/k_per_token; and per-expert
// active-token compaction lists (order-free: values don't depend on order).
// ---------------------------------------------------------------------------
__global__ __launch_bounds__(256) void ln2_router(const float* __restrict__ xio,
                                                  const float* __restrict__ g,
                                                  const float* __restrict__ bta,
                                                  const float* __restrict__ sim,
                                                  const float* __restrict__ cn,
                                                  const float* __restrict__ thr,
                                                  __hip_bfloat16* __restrict__ h2b,
                                                  float* __restrict__ scores,
                                                  float* __restrict__ kpt,
                                                  float* __restrict__ maskb,
                                                  int* __restrict__ cnt,
                                                  int* __restrict__ elist) {
    const int row = blockIdx.x, tid = threadIdx.x;
    __shared__ float r1[256], r2[256];
    __shared__ float red[256*17];
    float4 xv = ((const float4*)(xio + (long)row*CC))[tid];
    float s  = xv.x + xv.y + xv.z + xv.w;
    float q2 = xv.x*xv.x + xv.y*xv.y + xv.z*xv.z + xv.w*xv.w;
    r1[tid] = s; r2[tid] = q2; __syncthreads();
    for (int st = 128; st > 0; st >>= 1) {
        if (tid < st) { r1[tid] += r1[tid+st]; r2[tid] += r2[tid+st]; }
        __syncthreads();
    }
    const float mu  = r1[0] * (1.f/CC);
    const float var = r2[0] * (1.f/CC) - mu*mu;
    const float rs  = rsqrtf(var + EPSLN);
    float4 gv = ((const float4*)g)[tid];
    float4 bv = ((const float4*)bta)[tid];
    float ovs[4];
    ovs[0] = (xv.x-mu)*rs*gv.x + bv.x;
    ovs[1] = (xv.y-mu)*rs*gv.y + bv.y;
    ovs[2] = (xv.z-mu)*rs*gv.z + bv.z;
    ovs[3] = (xv.w-mu)*rs*gv.w + bv.w;
    {
        __hip_bfloat16* p = h2b + (long)row*CC + tid*4;
        p[0] = __float2bfloat16(ovs[0]); p[1] = __float2bfloat16(ovs[1]);
        p[2] = __float2bfloat16(ovs[2]); p[3] = __float2bfloat16(ovs[3]);
    }
    // router: this thread's 4 contiguous channels
    float acc[17] = {};
    #pragma unroll
    for (int j = 0; j < 4; j++) {
        const float v = ovs[j];
        acc[16] += v*v;
        const float* sr = sim + (long)(tid*4 + j)*EE;
        #pragma unroll
        for (int e2 = 0; e2 < EE; e2++) acc[e2] += v*sr[e2];
    }
    #pragma unroll
    for (int e2 = 0; e2 < 17; e2++) red[tid*17 + e2] = acc[e2];
    __syncthreads();
    for (int st = 128; st > 0; st >>= 1) {
        if (tid < st)
            for (int e2 = 0; e2 < 17; e2++) red[tid*17+e2] += red[(tid+st)*17+e2];
        __syncthreads();
    }
    if (tid < EE) {
        const float nrm = sqrtf(red[16]);
        const float sc  = red[tid] / (nrm * cn[tid]);
        scores[(long)row*EE + tid] = sc;
        const float mkv = sc > thr[0] ? 1.f : 0.f;
        maskb[(long)row*EE + tid] = mkv;
        red[tid] = mkv;
        if (mkv > 0.f) {
            int slot = atomicAdd(&cnt[tid], 1);
            elist[(long)tid*NN + slot] = row;
        }
    }
    __syncthreads();
    if (tid == 0) {
        float c2 = 0.f;
        for (int e2 = 0; e2 < EE; e2++) c2 += red[e2];
        kpt[row] = c2;
    }
}

// ---------------------------------------------------------------------------
// One-shot QKVO weight prep (single launch, z selects weight):
// W[K][N] fp32 -> Wt[N][K] bf16 hi + lo (bf16x3 split).
// ---------------------------------------------------------------------------
__global__ __launch_bounds__(256) void transpose_split4(const float* __restrict__ W0,
                                                        const float* __restrict__ W1,
                                                        const float* __restrict__ W2,
                                                        const float* __restrict__ W3,
                                                        __hip_bfloat16* __restrict__ Wth_base,
                                                        __hip_bfloat16* __restrict__ Wtl_base) {
    const int z = blockIdx.z;
    const float* W = (z==0) ? W0 : (z==1) ? W1 : (z==2) ? W2 : W3;
    __hip_bfloat16* Wth = Wth_base + (long)z*CC*CC;
    __hip_bfloat16* Wtl = Wtl_base + (long)z*CC*CC;
    const int n0 = blockIdx.x * 32, k0 = blockIdx.y * 32;
    __shared__ float t[32][33];
    const int tx = threadIdx.x & 31, ty = threadIdx.x >> 5;
    #pragma unroll
    for (int i = 0; i < 4; i++)
        t[ty + i*8][tx] = W[(long)(k0 + ty + i*8)*CC + n0 + tx];
    __syncthreads();
    #pragma unroll
    for (int i = 0; i < 4; i++) {
        float v = t[tx][ty + i*8];
        short h, l; splitbf(v, h, l);
        *(short*)&Wth[(long)(n0 + ty + i*8)*CC + k0 + tx] = h;
        *(short*)&Wtl[(long)(n0 + ty + i*8)*CC + k0 + tx] = l;
    }
}

// ---------------------------------------------------------------------------
// Expert weight prep (single launch): z = half*16 + e. half0: w1 [C][I] ->
// w1t [I][C]; half1: w2 [I][C] -> w2t [C][I]. Flattened grid.x = 256 blocks/e.
// ---------------------------------------------------------------------------
__global__ __launch_bounds__(256) void transpose_f2b_both(const float* __restrict__ w1,
                                                          const float* __restrict__ w2,
                                                          __hip_bfloat16* __restrict__ w1t,
                                                          __hip_bfloat16* __restrict__ w2t) {
    const int zz = blockIdx.z;
    const int half = zz >> 4, e = zz & 15;
    const float* W; __hip_bfloat16* Wt; int K, N, nbx;
    if (half == 0) { W = w1 + (long)e*CC*II; Wt = w1t + (long)e*CC*II; K = CC; N = II; nbx = II/32; }
    else           { W = w2 + (long)e*II*CC; Wt = w2t + (long)e*II*CC; K = II; N = CC; nbx = CC/32; }
    const int bx = blockIdx.x;
    const int n0 = (bx % nbx) * 32, k0 = (bx / nbx) * 32;
    __shared__ float t[32][33];
    const int tx = threadIdx.x & 31, ty = threadIdx.x >> 5;
    #pragma unroll
    for (int i = 0; i < 4; i++)
        t[ty + i*8][tx] = W[(long)(k0 + ty + i*8)*N + n0 + tx];
    __syncthreads();
    #pragma unroll
    for (int i = 0; i < 4; i++)
        Wt[(long)(n0 + ty + i*8)*K + k0 + tx] = __float2bfloat16(t[tx][ty + i*8]);
}

// ---------------------------------------------------------------------------
// bf16 transpose for V: [b*T + t][C] (hi/lo) -> [(b*H + h)*64 + d][T] (hi/lo)
// ---------------------------------------------------------------------------
__global__ __launch_bounds__(256) void transpose_v_bf16(
        const __hip_bfloat16* __restrict__ Vh, const __hip_bfloat16* __restrict__ Vl,
        __hip_bfloat16* __restrict__ Vth, __hip_bfloat16* __restrict__ Vtl) {
    const int b = blockIdx.z;
    const int c0 = blockIdx.y * 32, t0 = blockIdx.x * 32;
    __shared__ unsigned short th[32][33], tl[32][33];
    const int tx = threadIdx.x & 31, ty = threadIdx.x >> 5;
    const unsigned short* vh = (const unsigned short*)Vh;
    const unsigned short* vl = (const unsigned short*)Vl;
    #pragma unroll
    for (int i = 0; i < 4; i++) {
        const long src = ((long)b*TT + t0 + ty + i*8)*CC + c0 + tx;
        th[ty + i*8][tx] = vh[src];
        tl[ty + i*8][tx] = vl[src];
    }
    __syncthreads();
    #pragma unroll
    for (int i = 0; i < 4; i++) {
        const int gc = c0 + ty + i*8;          // global channel
        const int hh = gc >> 6, d = gc & 63;
        const long dst = ((long)(b*HH + hh)*64 + d)*TT + t0 + tx;
        ((unsigned short*)Vth)[dst] = th[tx][ty + i*8];
        ((unsigned short*)Vtl)[dst] = tl[tx][ty + i*8];
    }
}

// ---------------------------------------------------------------------------
// Big-tile bf16x3 split GEMM (QKV): 128Mx128N, BK=32, 4 waves each 64x64.
// Staging via global_load_lds width=16 (direct HBM->LDS, no VGPR round trip).
// LDS is LINEAR [128][32] (required: dest = wave-uniform base + lane*16).
// Emits pre-split bf16 hi/lo. Same bytes, same MFMA order -> bit-identical.
// ---------------------------------------------------------------------------
__global__ __launch_bounds__(256, 2) void gemm_split_big(
        const __hip_bfloat16* __restrict__ Ah,
        const __hip_bfloat16* __restrict__ Al,
        const __hip_bfloat16* __restrict__ Bh_base,
        const __hip_bfloat16* __restrict__ Bl_base,
        __hip_bfloat16* __restrict__ Ch_base,
        __hip_bfloat16* __restrict__ Cl_base,
        int M, int N, int K) {
    __shared__ __hip_bfloat16 Ash[128][32], Asl[128][32];
    __shared__ __hip_bfloat16 Bsh[128][32], Bsl[128][32];
    const int z = blockIdx.z;
    const __hip_bfloat16* Bth = Bh_base + (long)z * N * K;
    const __hip_bfloat16* Btl = Bl_base + (long)z * N * K;
    const int n0 = blockIdx.x * 128, m0 = blockIdx.y * 128;
    const int tid = threadIdx.x;
    const int wave = tid >> 6, lane = tid & 63;
    const int wm = (wave >> 1) * 64, wn = (wave & 1) * 64;
    const int l15 = lane & 15, quad = lane >> 4;

    f32x4 acc[4][4] = {};

    for (int k0 = 0; k0 < K; k0 += 32) {
        // stage 4 buffers: each = 128 rows x 32 k x 2B = 8 KB = 8 wave-loads.
        // wave w issues chunks {2w, 2w+1}; lane maps row=(lane>>2), col=(lane&3)*8.
        #pragma unroll
        for (int i = 0; i < 2; i++) {
            const int chunk = wave*2 + i;              // 0..7
            const int r = chunk*16 + (lane >> 2);
            const int c8 = (lane & 3) * 8;
            const long aoff = (long)(m0 + r)*K + k0 + c8;
            const long boff = (long)(n0 + r)*K + k0 + c8;
            GLOAD_LDS16(Ah  + aoff, &Ash[chunk*16][0]);
            GLOAD_LDS16(Al  + aoff, &Asl[chunk*16][0]);
            GLOAD_LDS16(Bth + boff, &Bsh[chunk*16][0]);
            GLOAD_LDS16(Btl + boff, &Bsl[chunk*16][0]);
        }
        __syncthreads();
        short8 ah[4], al[4], bh[4], bl[4];
        #pragma unroll
        for (int i = 0; i < 4; i++) {
            ah[i] = *(const short8*)&Ash[wm + i*16 + l15][quad*8];
            al[i] = *(const short8*)&Asl[wm + i*16 + l15][quad*8];
            bh[i] = *(const short8*)&Bsh[wn + i*16 + l15][quad*8];
            bl[i] = *(const short8*)&Bsl[wn + i*16 + l15][quad*8];
        }
        #pragma unroll
        for (int mi = 0; mi < 4; mi++)
            #pragma unroll
            for (int ni = 0; ni < 4; ni++) {
                acc[mi][ni] = __builtin_amdgcn_mfma_f32_16x16x32_bf16(ah[mi], bh[ni], acc[mi][ni], 0,0,0);
                acc[mi][ni] = __builtin_amdgcn_mfma_f32_16x16x32_bf16(ah[mi], bl[ni], acc[mi][ni], 0,0,0);
                acc[mi][ni] = __builtin_amdgcn_mfma_f32_16x16x32_bf16(al[mi], bh[ni], acc[mi][ni], 0,0,0);
            }
        __syncthreads();
    }

    #pragma unroll
    for (int mi = 0; mi < 4; mi++)
        #pragma unroll
        for (int r = 0; r < 4; r++) {
            const int row = m0 + wm + mi*16 + quad*4 + r;
            #pragma unroll
            for (int ni = 0; ni < 4; ni++) {
                const int col = n0 + wn + ni*16 + l15;
                short hh, ll; splitbf(acc[mi][ni][r], hh, ll);
                *(short*)&Ch_base[(long)z*M*N + (long)row*N + col] = hh;
                *(short*)&Cl_base[(long)z*M*N + (long)row*N + col] = ll;
            }
        }
}

// ---------------------------------------------------------------------------
// fp32-accurate MFMA GEMM via bf16x3 split, 64Mx128N tile (WO path), with
// global_load_lds staging (linear LDS).
// ---------------------------------------------------------------------------
__global__ __launch_bounds__(256, 2) void gemm_split(
        const __hip_bfloat16* __restrict__ Ah,
        const __hip_bfloat16* __restrict__ Al,
        const __hip_bfloat16* __restrict__ Bth,
        const __hip_bfloat16* __restrict__ Btl,
        float* __restrict__ Cp,
        int M, int N, int K,
        const float* __restrict__ resid) {
    __shared__ __hip_bfloat16 Ash[64][32], Asl[64][32];
    __shared__ __hip_bfloat16 Bsh[128][32], Bsl[128][32];
    const int n0 = blockIdx.x * 128, m0 = blockIdx.y * 64;
    const int tid = threadIdx.x;
    const int wave = tid >> 6, lane = tid & 63;
    const int wm = (wave >> 1) * 32, wn = (wave & 1) * 64;
    const int l15 = lane & 15, quad = lane >> 4;

    f32x4 acc[2][4] = {};

    for (int k0 = 0; k0 < K; k0 += 32) {
        {   // A: 64x32 = 4KB/buffer = 4 wave-loads; wave w stages chunk w
            const int r = wave*16 + (lane >> 2);
            const int c8 = (lane & 3) * 8;
            const long aoff = (long)(m0 + r)*K + k0 + c8;
            GLOAD_LDS16(Ah + aoff, &Ash[wave*16][0]);
            GLOAD_LDS16(Al + aoff, &Asl[wave*16][0]);
        }
        #pragma unroll
        for (int i = 0; i < 2; i++) {   // B: 128x32 = 8KB/buffer = 8 wave-loads
            const int chunk = wave*2 + i;
            const int r = chunk*16 + (lane >> 2);
            const int c8 = (lane & 3) * 8;
            const long boff = (long)(n0 + r)*K + k0 + c8;
            GLOAD_LDS16(Bth + boff, &Bsh[chunk*16][0]);
            GLOAD_LDS16(Btl + boff, &Bsl[chunk*16][0]);
        }
        __syncthreads();
        short8 ah[2], al[2], bh[4], bl[4];
        #pragma unroll
        for (int mi = 0; mi < 2; mi++) {
            ah[mi] = *(const short8*)&Ash[wm + mi*16 + l15][quad*8];
            al[mi] = *(const short8*)&Asl[wm + mi*16 + l15][quad*8];
        }
        #pragma unroll
        for (int ni = 0; ni < 4; ni++) {
            bh[ni] = *(const short8*)&Bsh[wn + ni*16 + l15][quad*8];
            bl[ni] = *(const short8*)&Bsl[wn + ni*16 + l15][quad*8];
        }
        #pragma unroll
        for (int mi = 0; mi < 2; mi++)
            #pragma unroll
            for (int ni = 0; ni < 4; ni++) {
                acc[mi][ni] = __builtin_amdgcn_mfma_f32_16x16x32_bf16(ah[mi], bh[ni], acc[mi][ni], 0,0,0);
                acc[mi][ni] = __builtin_amdgcn_mfma_f32_16x16x32_bf16(ah[mi], bl[ni], acc[mi][ni], 0,0,0);
                acc[mi][ni] = __builtin_amdgcn_mfma_f32_16x16x32_bf16(al[mi], bh[ni], acc[mi][ni], 0,0,0);
            }
        __syncthreads();
    }

    #pragma unroll
    for (int mi = 0; mi < 2; mi++)
        #pragma unroll
        for (int r = 0; r < 4; r++) {
            const int row = m0 + wm + mi*16 + quad*4 + r;
            #pragma unroll
            for (int ni = 0; ni < 4; ni++) {
                const int col = n0 + wn + ni*16 + l15;
                Cp[(long)row*N + col] = acc[mi][ni][r] + resid[(long)row*N + col];
            }
        }
}

// ---------------------------------------------------------------------------
// Sparse expert GEMM1: mid[e][slot] = gelu(h2b[tok(slot)] @ w1t[e]^T), bf16.
// global_load_lds staging; A rows gathered via per-lane source addresses
// (rowmap cached in VGPRs). Blocks beyond cnt[e] exit.
// ---------------------------------------------------------------------------
__global__ __launch_bounds__(256) void gemm_moe1_sparse(
        const __hip_bfloat16* __restrict__ A,      // h2b [NN][CC]
        const __hip_bfloat16* __restrict__ w1t,    // [16][II][CC]
        __hip_bfloat16* __restrict__ mid,          // [16][NN][II] compacted
        const int* __restrict__ cnt,
        const int* __restrict__ elist) {
    __shared__ __hip_bfloat16 As[128][32];
    __shared__ __hip_bfloat16 Bs[128][32];
    __shared__ int rowmap[128];
    const int e = blockIdx.z;
    const int count = cnt[e];
    const int m0 = blockIdx.y * 128;
    if (m0 >= count) return;
    const int n0 = blockIdx.x * 128;
    const __hip_bfloat16* Bt = w1t + (long)e*II*CC;
    const int* lst = elist + (long)e*NN;
    const int tid = threadIdx.x;
    if (tid < 128) rowmap[tid] = lst[min(m0 + tid, count - 1)];
    __syncthreads();
    const int wave = tid >> 6, lane = tid & 63;
    const int wm = (wave >> 1) * 64, wn = (wave & 1) * 64;
    const int l15 = lane & 15, quad = lane >> 4;
    // cache this lane's 2 gather rows (for staging chunks wave*2, wave*2+1)
    int rm[2];
    #pragma unroll
    for (int i = 0; i < 2; i++) rm[i] = rowmap[(wave*2 + i)*16 + (lane >> 2)];

    f32x4 acc[4][4] = {};

    for (int k0 = 0; k0 < CC; k0 += 32) {
        #pragma unroll
        for (int i = 0; i < 2; i++) {
            const int chunk = wave*2 + i;
            const int r = chunk*16 + (lane >> 2);
            const int c8 = (lane & 3) * 8;
            GLOAD_LDS16(A  + (long)rm[i]*CC + k0 + c8, &As[chunk*16][0]);
            GLOAD_LDS16(Bt + (long)(n0 + r)*CC + k0 + c8, &Bs[chunk*16][0]);
        }
        __syncthreads();
        short8 af[4], bff[4];
        #pragma unroll
        for (int i = 0; i < 4; i++) {
            af[i]  = *(const short8*)&As[wm + i*16 + l15][quad*8];
            bff[i] = *(const short8*)&Bs[wn + i*16 + l15][quad*8];
        }
        #pragma unroll
        for (int mi = 0; mi < 4; mi++)
            #pragma unroll
            for (int ni = 0; ni < 4; ni++)
                acc[mi][ni] = __builtin_amdgcn_mfma_f32_16x16x32_bf16(
                                  af[mi], bff[ni], acc[mi][ni], 0, 0, 0);
        __syncthreads();
    }

    #pragma unroll
    for (int mi = 0; mi < 4; mi++) {
        #pragma unroll
        for (int r = 0; r < 4; r++) {
            const int slot = m0 + wm + mi*16 + quad*4 + r;
            if (slot < count) {
                #pragma unroll
                for (int ni = 0; ni < 4; ni++) {
                    const int col = n0 + wn + ni*16 + l15;
                    float val = acc[mi][ni][r];
                    val = 0.5f*val*(1.f + erff(val*0.70710678118f));
                    mid[((long)e*NN + slot)*II + col] = __float2bfloat16(val);
                }
            }
        }
    }
}

// ---------------------------------------------------------------------------
// Sparse expert GEMM2: eo[tok(slot), e, :] = mid[e][slot] @ w2t[e]^T
// global_load_lds staging (both operands contiguous). No atomics.
// ---------------------------------------------------------------------------
__global__ __launch_bounds__(256) void gemm_moe2_sparse(
        const __hip_bfloat16* __restrict__ mid,    // [16][NN][II] compacted
        const __hip_bfloat16* __restrict__ w2t,    // [16][CC][II]
        float* __restrict__ eo,                    // [NN][EE][CC]
        const int* __restrict__ cnt,
        const int* __restrict__ elist) {
    __shared__ __hip_bfloat16 As[128][32];
    __shared__ __hip_bfloat16 Bs[128][32];
    __shared__ int rowmap[128];
    const int e = blockIdx.z;
    const int count = cnt[e];
    const int m0 = blockIdx.y * 128;
    if (m0 >= count) return;
    const int n0 = blockIdx.x * 128;
    const __hip_bfloat16* A  = mid + (long)e*NN*II;
    const __hip_bfloat16* Bt = w2t + (long)e*CC*II;
    const int* lst = elist + (long)e*NN;
    const int tid = threadIdx.x;
    if (tid < 128) rowmap[tid] = lst[min(m0 + tid, count - 1)];
    __syncthreads();
    const int wave = tid >> 6, lane = tid & 63;
    const int wm = (wave >> 1) * 64, wn = (wave & 1) * 64;
    const int l15 = lane & 15, quad = lane >> 4;

    f32x4 acc[4][4] = {};

    for (int k0 = 0; k0 < II; k0 += 32) {
        #pragma unroll
        for (int i = 0; i < 2; i++) {
            const int chunk = wave*2 + i;
            const int r = chunk*16 + (lane >> 2);
            const int c8 = (lane & 3) * 8;
            GLOAD_LDS16(A  + (long)(m0 + r)*II + k0 + c8, &As[chunk*16][0]);
            GLOAD_LDS16(Bt + (long)(n0 + r)*II + k0 + c8, &Bs[chunk*16][0]);
        }
        __syncthreads();
        short8 af[4], bff[4];
        #pragma unroll
        for (int i = 0; i < 4; i++) {
            af[i]  = *(const short8*)&As[wm + i*16 + l15][quad*8];
            bff[i] = *(const short8*)&Bs[wn + i*16 + l15][quad*8];
        }
        #pragma unroll
        for (int mi = 0; mi < 4; mi++)
            #pragma unroll
            for (int ni = 0; ni < 4; ni++)
                acc[mi][ni] = __builtin_amdgcn_mfma_f32_16x16x32_bf16(
                                  af[mi], bff[ni], acc[mi][ni], 0, 0, 0);
        __syncthreads();
    }

    #pragma unroll
    for (int mi = 0; mi < 4; mi++) {
        #pragma unroll
        for (int r = 0; r < 4; r++) {
            const int slot = m0 + wm + mi*16 + quad*4 + r;
            if (slot < count) {
                const int tok = rowmap[wm + mi*16 + quad*4 + r];
                #pragma unroll
                for (int ni = 0; ni < 4; ni++) {
                    const int col = n0 + wn + ni*16 + l15;
                    eo[((long)tok*EE + e)*CC + col] = acc[mi][ni][r];
                }
            }
        }
    }
}

// ---------------------------------------------------------------------------
// Fused: zero inactive eo rows + final[n,:] = sum over active e of eo[n,e,:];
// xio += final. Deterministic e-ascending order (skipping exact zeros is
// bitwise-identical to summing them).
// ---------------------------------------------------------------------------
__global__ __launch_bounds__(256) void moe_sum_zero(const float* __restrict__ maskb,
                                                    float* __restrict__ eo,
                                                    float* __restrict__ xio) {
    const int row = blockIdx.x, tid = threadIdx.x;
    float4 s = {0.f, 0.f, 0.f, 0.f};
    const float4 z4 = {0.f, 0.f, 0.f, 0.f};
    #pragma unroll
    for (int e = 0; e < EE; e++) {
        float4* p = ((float4*)(eo + ((long)row*EE + e)*CC)) + tid;
        if (maskb[(long)row*EE + e] != 0.f) {
            float4 v = *p;
            s.x += v.x; s.y += v.y; s.z += v.z; s.w += v.w;
        } else {
            *p = z4;
        }
    }
    float4 xv = ((float4*)(xio + (long)row*CC))[tid];
    xv.x += s.x; xv.y += s.y; xv.z += s.z; xv.w += s.w;
    ((float4*)(xio + (long)row*CC))[tid] = xv;
}

// ---------------------------------------------------------------------------
// Flash attention with bf16x3 MFMA for QK^T and PV. kt-split for balance.
// All inputs PRE-SPLIT bf16 hi/lo; V pre-transposed [(b*H+h)*64+d][T].
// T14 async-STAGE split: next tile's global loads issued right after the
// current LDS write, hiding HBM latency under QK/softmax/PV compute.
// ---------------------------------------------------------------------------
__global__ __launch_bounds__(256, 4) void attn_split(
        const __hip_bfloat16* __restrict__ Qh, const __hip_bfloat16* __restrict__ Ql,
        const __hip_bfloat16* __restrict__ Kh, const __hip_bfloat16* __restrict__ Kl,
        const __hip_bfloat16* __restrict__ Vtg_h, const __hip_bfloat16* __restrict__ Vtg_l,
        float* __restrict__ Opart,
        float* __restrict__ mpart,
        float* __restrict__ lpart) {
    __shared__ __hip_bfloat16 KPh[64][LDA], KPl[64][LDA];   // K, then P
    __shared__ __hip_bfloat16 Vth[64][LDA], Vtl[64][LDA];   // V^T [d][kk]

    const int bx = blockIdx.x;                 // 0..31, heavy qt first
    const int qt = 15 - (bx >> 1), half = bx & 1;
    const int h = blockIdx.y, b = blockIdx.z;
    const int tid = threadIdx.x;
    const int wave = tid >> 6, lane = tid & 63;
    const int l15 = lane & 15, quad = lane >> 4;
    const int wm = wave * 16;                  // wave's 16 q-rows in the 64-tile
    const long tbase = (long)b * TT * CC + (long)h * DD;          // [token][C] slab
    const long vbase = (long)(b*HH + h) * 64 * TT;                // V^T slab
    const int pidx = ((b*HH + h)*16 + qt)*2 + half;
    float* Op = Opart + (long)pidx * 4096;

    const int n_kt = qt + 1, mid_kt = (n_kt + 1) >> 1;
    const int kt_lo = half ? mid_kt : 0;
    const int kt_hi = half ? n_kt   : mid_kt;

    if (kt_lo >= kt_hi) {      // empty half (qt=0): neutral partials
        for (int i = tid; i < 64*64; i += 256) Op[i] = 0.f;
        if (tid < 64) { mpart[(long)pidx*64 + tid] = -1e30f; lpart[(long)pidx*64 + tid] = 0.f; }
        return;
    }

    // Q A-fragments direct from pre-split global
    short8 qh[2], ql[2];
    {
        const long qoff = tbase + (long)(qt*64 + wm + l15)*CC;
        #pragma unroll
        for (int kc = 0; kc < 2; kc++) {
            qh[kc] = *(const short8*)(Qh + qoff + kc*32 + quad*8);
            ql[kc] = *(const short8*)(Ql + qoff + kc*32 + quad*8);
        }
    }

    // staging geometry: this thread covers rows r0 and r0+32, col group g0
    const int r0 = tid >> 3, g0 = (tid & 7) * 8;

    // prefetch registers for the next K/V tile (T14 async-STAGE split)
    short8 sKh0, sKl0, sVh0, sVl0, sKh1, sKl1, sVh1, sVl1;
    {
        const int kt = kt_lo;
        const long k0off = tbase + (long)(kt*64 + r0)*CC + g0;
        const long k1off = tbase + (long)(kt*64 + r0 + 32)*CC + g0;
        const long v0off = vbase + (long)r0*TT + kt*64 + g0;
        const long v1off = vbase + (long)(r0 + 32)*TT + kt*64 + g0;
        sKh0 = *(const short8*)(Kh + k0off);    sKl0 = *(const short8*)(Kl + k0off);
        sKh1 = *(const short8*)(Kh + k1off);    sKl1 = *(const short8*)(Kl + k1off);
        sVh0 = *(const short8*)(Vtg_h + v0off); sVl0 = *(const short8*)(Vtg_l + v0off);
        sVh1 = *(const short8*)(Vtg_h + v1off); sVl1 = *(const short8*)(Vtg_l + v1off);
    }

    f32x4 oacc[4] = {};            // 4 d-tiles, rows = quad*4+reg
    float m_run[4], l_run[4];
    #pragma unroll
    for (int r = 0; r < 4; r++) { m_run[r] = -1e30f; l_run[r] = 0.f; }

    for (int kt = kt_lo; kt < kt_hi; kt++) {
        __syncthreads();           // prev-iter PV reads of KP/Vt done
        // write prefetched tile to LDS
        *(short8*)&KPh[r0][g0]      = sKh0;  *(short8*)&KPl[r0][g0]      = sKl0;
        *(short8*)&KPh[r0 + 32][g0] = sKh1;  *(short8*)&KPl[r0 + 32][g0] = sKl1;
        *(short8*)&Vth[r0][g0]      = sVh0;  *(short8*)&Vtl[r0][g0]      = sVl0;
        *(short8*)&Vth[r0 + 32][g0] = sVh1;  *(short8*)&Vtl[r0 + 32][g0] = sVl1;
        // issue next tile's global loads (latency hides under QK/softmax/PV)
        if (kt + 1 < kt_hi) {
            const int kn = kt + 1;
            const long k0off = tbase + (long)(kn*64 + r0)*CC + g0;
            const long k1off = tbase + (long)(kn*64 + r0 + 32)*CC + g0;
            const long v0off = vbase + (long)r0*TT + kn*64 + g0;
            const long v1off = vbase + (long)(r0 + 32)*TT + kn*64 + g0;
            sKh0 = *(const short8*)(Kh + k0off);    sKl0 = *(const short8*)(Kl + k0off);
            sKh1 = *(const short8*)(Kh + k1off);    sKl1 = *(const short8*)(Kl + k1off);
            sVh0 = *(const short8*)(Vtg_h + v0off); sVl0 = *(const short8*)(Vtg_l + v0off);
            sVh1 = *(const short8*)(Vtg_h + v1off); sVl1 = *(const short8*)(Vtg_l + v1off);
        }
        __syncthreads();

        // QK^T via MFMA: 4 key-tiles x 2 k-chunks x 3 split terms
        f32x4 s[4] = {};
        #pragma unroll
        for (int nt = 0; nt < 4; nt++)
            #pragma unroll
            for (int kc = 0; kc < 2; kc++) {
                short8 bh = *(const short8*)&KPh[nt*16 + l15][kc*32 + quad*8];
                short8 bl = *(const short8*)&KPl[nt*16 + l15][kc*32 + quad*8];
                s[nt] = __builtin_amdgcn_mfma_f32_16x16x32_bf16(qh[kc], bh, s[nt], 0,0,0);
                s[nt] = __builtin_amdgcn_mfma_f32_16x16x32_bf16(qh[kc], bl, s[nt], 0,0,0);
                s[nt] = __builtin_amdgcn_mfma_f32_16x16x32_bf16(ql[kc], bh, s[nt], 0,0,0);
            }

        // online softmax in regs; row = wm + quad*4 + r, col = nt*16 + l15
        const bool diag = (kt == qt);
        float alpha[4];
        float pr[4][4];
        #pragma unroll
        for (int r = 0; r < 4; r++) {
            const int rowg = wm + quad*4 + r;
            float sv[4], mx = -1e30f;
            #pragma unroll
            for (int nt = 0; nt < 4; nt++) {
                float val = s[nt][r] * 0.125f;
                if (diag && (nt*16 + l15) > rowg) val = -1e30f;
                sv[nt] = val;
                mx = fmaxf(mx, val);
            }
            #pragma unroll
            for (int off = 1; off < 16; off <<= 1) mx = fmaxf(mx, __shfl_xor(mx, off, 16));
            const float mnew = fmaxf(m_run[r], mx);
            alpha[r] = __expf(m_run[r] - mnew);
            float rs = 0.f;
            #pragma unroll
            for (int nt = 0; nt < 4; nt++) {
                float p = __expf(sv[nt] - mnew);
                pr[r][nt] = p;
                rs += p;
            }
            #pragma unroll
            for (int off = 1; off < 16; off <<= 1) rs += __shfl_xor(rs, off, 16);
            l_run[r] = l_run[r]*alpha[r] + rs;
            m_run[r] = mnew;
        }
        __syncthreads();           // all QK reads of KP done -> overwrite as P

        // write P split into KP region: row = wm+quad*4+r, col = nt*16+l15
        #pragma unroll
        for (int r = 0; r < 4; r++)
            #pragma unroll
            for (int nt = 0; nt < 4; nt++) {
                short hh, ll; splitbf(pr[r][nt], hh, ll);
                *(short*)&KPh[wm + quad*4 + r][nt*16 + l15] = hh;
                *(short*)&KPl[wm + quad*4 + r][nt*16 + l15] = ll;
            }
        // no barrier: PV reads only this wave's own 16 P-rows

        // rescale O and accumulate PV via MFMA
        #pragma unroll
        for (int dt = 0; dt < 4; dt++)
            #pragma unroll
            for (int r = 0; r < 4; r++)
                oacc[dt][r] *= alpha[r];
        #pragma unroll
        for (int kc = 0; kc < 2; kc++) {
            short8 ph = *(const short8*)&KPh[wm + l15][kc*32 + quad*8];
            short8 pl = *(const short8*)&KPl[wm + l15][kc*32 + quad*8];
            #pragma unroll
            for (int dt = 0; dt < 4; dt++) {
                short8 vh = *(const short8*)&Vth[dt*16 + l15][kc*32 + quad*8];
                short8 vl = *(const short8*)&Vtl[dt*16 + l15][kc*32 + quad*8];
                oacc[dt] = __builtin_amdgcn_mfma_f32_16x16x32_bf16(ph, vh, oacc[dt], 0,0,0);
                oacc[dt] = __builtin_amdgcn_mfma_f32_16x16x32_bf16(ph, vl, oacc[dt], 0,0,0);
                oacc[dt] = __builtin_amdgcn_mfma_f32_16x16x32_bf16(pl, vh, oacc[dt], 0,0,0);
            }
        }
    }

    // store unnormalized O partial + (m,l)
    #pragma unroll
    for (int dt = 0; dt < 4; dt++)
        #pragma unroll
        for (int r = 0; r < 4; r++)
            Op[(wm + quad*4 + r)*64 + dt*16 + l15] = oacc[dt][r];
    if (l15 == 0) {
        #pragma unroll
        for (int r = 0; r < 4; r++) {
            mpart[(long)pidx*64 + wm + quad*4 + r] = m_run[r];
            lpart[(long)pidx*64 + wm + quad*4 + r] = l_run[r];
        }
    }
}

// ---------------------------------------------------------------------------
// Merge the two kt-half partials -> normalized attention output, emitted as
// pre-split bf16 hi/lo (direct feed for the WO bf16x3 GEMM).
// ---------------------------------------------------------------------------
__global__ __launch_bounds__(256) void attn_merge(const float* __restrict__ Opart,
                                                  const float* __restrict__ mpart,
                                                  const float* __restrict__ lpart,
                                                  __hip_bfloat16* __restrict__ aoh,
                                                  __hip_bfloat16* __restrict__ aol) {
    const int qt = blockIdx.x, h = blockIdx.y, b = blockIdx.z;
    const int pA = ((b*HH + h)*16 + qt)*2, pB = pA + 1;
    const int tid = threadIdx.x;
    const int r = tid >> 2, c0 = (tid & 3) * 16;
    const float mA = mpart[(long)pA*64 + r], mB = mpart[(long)pB*64 + r];
    const float lA = lpart[(long)pA*64 + r], lB = lpart[(long)pB*64 + r];
    const float M  = fmaxf(mA, mB);
    const float wA = __expf(mA - M), wB = __expf(mB - M);
    const float inv = 1.f / (lA*wA + lB*wB);
    const float* OA = Opart + (long)pA*4096 + r*64 + c0;
    const float* OB = Opart + (long)pB*4096 + r*64 + c0;
    const long dst = (long)b*TT*CC + (long)(qt*64 + r)*CC + h*DD + c0;
    #pragma unroll
    for (int j = 0; j < 16; j += 4) {
        float4 oa = *(const float4*)(OA + j);
        float4 ob = *(const float4*)(OB + j);
        float xs[4];
        xs[0] = (oa.x*wA + ob.x*wB)*inv;
        xs[1] = (oa.y*wA + ob.y*wB)*inv;
        xs[2] = (oa.z*wA + ob.z*wB)*inv;
        xs[3] = (oa.w*wA + ob.w*wB)*inv;
        s16x4 hv, lv;
        #pragma unroll
        for (int t = 0; t < 4; t++) { short hh,ll; splitbf(xs[t],hh,ll); hv[t]=hh; lv[t]=ll; }
        *(s16x4*)(aoh + dst + j) = hv;
        *(s16x4*)(aol + dst + j) = lv;
    }
}

// ---------------------------------------------------------------------------
// Column norms of sim_matrix [C, E]; also zeros the compaction counters.
// ---------------------------------------------------------------------------
__global__ __launch_bounds__(256) void colnorm_kernel(const float* __restrict__ sim,
                                                      float* __restrict__ cn,
                                                      int* __restrict__ cnt) {
    const int e = blockIdx.x, tid = threadIdx.x;
    __shared__ float red[256];
    float s = 0.f;
    for (int c = tid; c < CC; c += 256) {
        float vv = sim[(long)c*EE + e];
        s += vv*vv;
    }
    red[tid] = s; __syncthreads();
    for (int st = 128; st > 0; st >>= 1) {
        if (tid < st) red[tid] += red[tid+st];
        __syncthreads();
    }
    if (tid == 0) { cn[e] = sqrtf(red[0]); cnt[e] = 0; }
}

// ---------------------------------------------------------------------------
extern "C" void kernel_launch(void* const* d_in, const int* in_sizes, int n_in,
                              void* d_out, int out_size, void* d_ws, size_t ws_size,
                              hipStream_t stream) {
    const float* x     = (const float*)d_in[0];
    const float* ln1_g = (const float*)d_in[1];
    const float* ln1_b = (const float*)d_in[2];
    const float* ln2_g = (const float*)d_in[3];
    const float* ln2_b = (const float*)d_in[4];
    const float* wq    = (const float*)d_in[5];
    const float* wk    = (const float*)d_in[6];
    const float* wv    = (const float*)d_in[7];
    const float* wo    = (const float*)d_in[8];
    const float* sim   = (const float*)d_in[9];
    const float* thr   = (const float*)d_in[10];
    const float* w1    = (const float*)d_in[11];
    const float* w2    = (const float*)d_in[12];

    float* out_x      = (float*)d_out;
    float* out_scores = out_x + (long)NN*CC;
    float* out_eo     = out_scores + (long)NN*EE;
    float* out_kpt    = out_eo + (long)NN*EE*CC;

    const long MF = (long)NN*CC;     // 2M floats
    const long CK = (long)CC*CC;     // 1M elems per weight slab
    float* ws   = (float*)d_ws;
    // [0, MF): attn-out split bf16 (hi/lo)
    __hip_bfloat16* aoh = (__hip_bfloat16*)ws;
    __hip_bfloat16* aol = (__hip_bfloat16*)(ws + MF/2);
    // [MF, 4MF): QKV pre-split bf16 (3 slabs hi, 3 slabs lo)
    __hip_bfloat16* qkvh = (__hip_bfloat16*)(ws + MF);
    __hip_bfloat16* qkvl = (__hip_bfloat16*)(ws + MF + 3*MF/2);
    // [4MF, 5MF): V^T pre-split bf16
    __hip_bfloat16* vth = (__hip_bfloat16*)(ws + 4*MF);
    __hip_bfloat16* vtl = (__hip_bfloat16*)(ws + 4*MF + MF/2);
    // [5MF, 5.5MF): LN2 bf16 for expert GEMM
    __hip_bfloat16* h2b = (__hip_bfloat16*)(ws + 5*MF);
    // [5.5MF, 7.5MF): attn partials; hh/hl (LN1 split) + mid alias
    float* Opart = ws + 5*MF + MF/2;
    __hip_bfloat16* hh  = (__hip_bfloat16*)(ws + 5*MF + MF/2);       // dead after QKV GEMM
    __hip_bfloat16* hl  = (__hip_bfloat16*)(ws + 6*MF);
    __hip_bfloat16* mid = (__hip_bfloat16*)(ws + 5*MF + MF/2);       // after merge
    // [7.5MF, 9.5MF): QKVO weight splits; w1t/w2t alias (after WO GEMM)
    __hip_bfloat16* wsph = (__hip_bfloat16*)(ws + 7*MF + MF/2);      // [4][C][C] hi
    __hip_bfloat16* wspl = (__hip_bfloat16*)(ws + 8*MF + MF/2);      // [4][C][C] lo
    __hip_bfloat16* w1t  = (__hip_bfloat16*)(ws + 7*MF + MF/2);
    __hip_bfloat16* w2t  = (__hip_bfloat16*)(ws + 8*MF + MF/2);
    float* maskb = ws + 9*MF + MF/2;                                  // 32K floats
    float* cn    = maskb + (long)NN*EE;                               // 16
    float* mpart = cn + 16;                                           // 64K
    float* lpart = mpart + 1024L*64;                                  // 64K
    int*   cnt   = (int*)(lpart + 1024L*64);                          // 16 ints
    int*   elist = cnt + 16;                                          // EE*NN ints

    // 0. sim column norms + zero compaction counters
    colnorm_kernel<<<EE, 256, 0, stream>>>(sim, cn, cnt);

    // 1. one-shot QKVO weight transpose + bf16x3 split (single launch)
    {
        dim3 gt(CC/32, CC/32, 4);
        transpose_split4<<<gt, 256, 0, stream>>>(wq, wk, wv, wo, wsph, wspl);
    }

    // 2. LN1 -> pre-split bf16 hi/lo
    ln_kernel<<<NN, 256, 0, stream>>>(x, ln1_g, ln1_b, hh, hl);

    // 3. fused QKV projection, 128x128 tile, global_load_lds staging
    {
        dim3 gq(CC/128, NN/128, 3);
        gemm_split_big<<<gq, 256, 0, stream>>>(hh, hl, wsph, wspl,
                                               qkvh, qkvl, NN, CC, CC);
    }

    // 3.5 V transpose (bf16 hi/lo): [token][C] -> per-(b,h) [d][T]
    {
        dim3 gv(TT/32, CC/32, BB);
        transpose_v_bf16<<<gv, 256, 0, stream>>>(qkvh + 2*(long)NN*CC, qkvl + 2*(long)NN*CC,
                                                 vth, vtl);
    }

    // 4. causal attention (MFMA flash, kt-split, async-STAGE prefetch) + merge
    {
        dim3 gattn(32, HH, BB);
        attn_split<<<gattn, 256, 0, stream>>>(qkvh, qkvl,
                                              qkvh + (long)NN*CC, qkvl + (long)NN*CC,
                                              vth, vtl, Opart, mpart, lpart);
        dim3 gmerge(16, HH, BB);
        attn_merge<<<gmerge, 256, 0, stream>>>(Opart, mpart, lpart, aoh, aol);
    }

    // 5. output projection + residual -> d_out x slot (gload_lds staging)
    {
        dim3 go(CC/128, NN/64, 1);
        gemm_split<<<go, 256, 0, stream>>>(aoh, aol, wsph + 3*CK, wspl + 3*CK,
                                           out_x, NN, CC, CC, x);
    }

    // 6. expert weight transposes (single launch; safe to overwrite QKVO splits)
    {
        dim3 ge(256, 1, 2*EE);
        transpose_f2b_both<<<ge, 256, 0, stream>>>(w1, w2, w1t, w2t);
    }

    // 7. fused LN2 + router + active-token compaction
    ln2_router<<<NN, 256, 0, stream>>>(out_x, ln2_g, ln2_b, sim, cn, thr,
                                       h2b, out_scores, out_kpt, maskb,
                                       cnt, elist);

    // 8. sparse expert GEMM 1: mid[e][slot] = gelu(h2[tok] @ w1[e])
    {
        dim3 g(II/128, NN/128, EE);
        gemm_moe1_sparse<<<g, 256, 0, stream>>>(h2b, w1t, mid, cnt, elist);
    }

    // 9. sparse expert GEMM 2: eo[tok,e,:] = mid[e][slot] @ w2[e]
    {
        dim3 g(CC/128, NN/128, EE);
        gemm_moe2_sparse<<<g, 256, 0, stream>>>(mid, w2t, out_eo, cnt, elist);
    }

    // 10. fused: zero inactive eo rows + sum active -> x (deterministic order)
    moe_sum_zero<<<NN, 256, 0, stream>>>(maskb, out_eo, out_x);
}

// Round 10
// 447.080 us; speedup vs baseline: 1.0870x; 1.0154x over previous
//
#include <hip/hip_runtime.h>
#include <hip/hip_bf16.h>
#include <math.h>

// Problem constants
#define BB 2
#define TT 1024
#define CC 1024
#define HH 16
#define DD 64
#define EE 16
#define II 256
#define NN (BB*TT)          // 2048 tokens
#define EPSLN 1e-5f
#define LDA 72              // bf16 LDS row stride: 144B rows, 16B-aligned

typedef __attribute__((ext_vector_type(8))) short short8;
typedef __attribute__((ext_vector_type(4))) short s16x4;
typedef __attribute__((ext_vector_type(4))) float f32x4;

// Direct global->LDS 16B copy: LDS dest = uniform base + lane*16.
#define GLOAD_LDS16(g, l) \
    __builtin_amdgcn_global_load_lds((const __attribute__((address_space(1))) void*)(g), \
                                     (__attribute__((address_space(3))) void*)(l), 16, 0, 0)

__device__ inline void splitbf(float x, short& hi, short& lo) {
    __hip_bfloat16 h = __float2bfloat16(x);
    float hf = __bfloat162float(h);
    __hip_bfloat16 l = __float2bfloat16(x - hf);
    hi = *(short*)&h;
    lo = *(short*)&l;
}

// ---------------------------------------------------------------------------
// Fused prep (single launch, flattened grid):
//   blocks [0, 4096):        QKVO weight transpose + bf16x3 split
//   blocks [4096, 4096+NN):  LN1 -> pre-split bf16 hi/lo
//   blocks [4096+NN, +EE):   sim column norms + zero compaction counters
// All three are independent input->workspace producers; per-block code is
// identical to the previous separate kernels -> bit-identical outputs.
// ---------------------------------------------------------------------------
__global__ __launch_bounds__(256) void prep_kernel(
        const float* __restrict__ x,
        const float* __restrict__ ln1_g, const float* __restrict__ ln1_b,
        __hip_bfloat16* __restrict__ outh, __hip_bfloat16* __restrict__ outl,
        const float* __restrict__ W0, const float* __restrict__ W1,
        const float* __restrict__ W2, const float* __restrict__ W3,
        __hip_bfloat16* __restrict__ Wth_base, __hip_bfloat16* __restrict__ Wtl_base,
        const float* __restrict__ sim, float* __restrict__ cn,
        int* __restrict__ cnt) {
    __shared__ float sh[32*33];
    const int bid = blockIdx.x, tid = threadIdx.x;
    if (bid < 4096) {
        // ---- QKVO weight transpose + split ----
        const int z = bid >> 10;
        const float* W = (z==0) ? W0 : (z==1) ? W1 : (z==2) ? W2 : W3;
        __hip_bfloat16* Wth = Wth_base + (long)z*CC*CC;
        __hip_bfloat16* Wtl = Wtl_base + (long)z*CC*CC;
        const int n0 = (bid & 31) * 32, k0 = ((bid >> 5) & 31) * 32;
        float (*t)[33] = (float(*)[33])sh;
        const int tx = tid & 31, ty = tid >> 5;
        #pragma unroll
        for (int i = 0; i < 4; i++)
            t[ty + i*8][tx] = W[(long)(k0 + ty + i*8)*CC + n0 + tx];
        __syncthreads();
        #pragma unroll
        for (int i = 0; i < 4; i++) {
            float v = t[tx][ty + i*8];
            short h, l; splitbf(v, h, l);
            *(short*)&Wth[(long)(n0 + ty + i*8)*CC + k0 + tx] = h;
            *(short*)&Wtl[(long)(n0 + ty + i*8)*CC + k0 + tx] = l;
        }
    } else if (bid < 4096 + NN) {
        // ---- LN1 -> pre-split bf16 hi/lo ----
        const int row = bid - 4096;
        float* r1 = sh;
        float* r2 = sh + 256;
        const float* xr = x + (long)row * CC;
        float4 xv = ((const float4*)xr)[tid];
        float s  = xv.x + xv.y + xv.z + xv.w;
        float q2 = xv.x*xv.x + xv.y*xv.y + xv.z*xv.z + xv.w*xv.w;
        r1[tid] = s; r2[tid] = q2; __syncthreads();
        for (int st = 128; st > 0; st >>= 1) {
            if (tid < st) { r1[tid] += r1[tid+st]; r2[tid] += r2[tid+st]; }
            __syncthreads();
        }
        const float mu  = r1[0] * (1.f/CC);
        const float var = r2[0] * (1.f/CC) - mu*mu;
        const float rs  = rsqrtf(var + EPSLN);
        float4 gv = ((const float4*)ln1_g)[tid];
        float4 bv = ((const float4*)ln1_b)[tid];
        float xs[4];
        xs[0] = (xv.x-mu)*rs*gv.x + bv.x;
        xs[1] = (xv.y-mu)*rs*gv.y + bv.y;
        xs[2] = (xv.z-mu)*rs*gv.z + bv.z;
        xs[3] = (xv.w-mu)*rs*gv.w + bv.w;
        s16x4 hv, lv;
        #pragma unroll
        for (int j = 0; j < 4; j++) { short h,l; splitbf(xs[j], h, l); hv[j]=h; lv[j]=l; }
        *(s16x4*)(outh + (long)row * CC + tid*4) = hv;
        *(s16x4*)(outl + (long)row * CC + tid*4) = lv;
    } else {
        // ---- sim column norms + zero counters ----
        const int e = bid - 4096 - NN;
        float* red = sh;
        float s = 0.f;
        for (int c = tid; c < CC; c += 256) {
            float vv = sim[(long)c*EE + e];
            s += vv*vv;
        }
        red[tid] = s; __syncthreads();
        for (int st = 128; st > 0; st >>= 1) {
            if (tid < st) red[tid] += red[tid+st];
            __syncthreads();
        }
        if (tid == 0) { cn[e] = sqrtf(red[0]); cnt[e] = 0; }
    }
}

// ---------------------------------------------------------------------------
// Fused LN2 + router: LN -> h2b bf16; scores/mask/k_per_token; and per-expert
// active-token compaction lists (order-free: values don't depend on order).
// ---------------------------------------------------------------------------
__global__ __launch_bounds__(256) void ln2_router(const float* __restrict__ xio,
                                                  const float* __restrict__ g,
                                                  const float* __restrict__ bta,
                                                  const float* __restrict__ sim,
                                                  const float* __restrict__ cn,
                                                  const float* __restrict__ thr,
                                                  __hip_bfloat16* __restrict__ h2b,
                                                  float* __restrict__ scores,
                                                  float* __restrict__ kpt,
                                                  float* __restrict__ maskb,
                                                  int* __restrict__ cnt,
                                                  int* __restrict__ elist) {
    const int row = blockIdx.x, tid = threadIdx.x;
    __shared__ float r1[256], r2[256];
    __shared__ float red[256*17];
    float4 xv = ((const float4*)(xio + (long)row*CC))[tid];
    float s  = xv.x + xv.y + xv.z + xv.w;
    float q2 = xv.x*xv.x + xv.y*xv.y + xv.z*xv.z + xv.w*xv.w;
    r1[tid] = s; r2[tid] = q2; __syncthreads();
    for (int st = 128; st > 0; st >>= 1) {
        if (tid < st) { r1[tid] += r1[tid+st]; r2[tid] += r2[tid+st]; }
        __syncthreads();
    }
    const float mu  = r1[0] * (1.f/CC);
    const float var = r2[0] * (1.f/CC) - mu*mu;
    const float rs  = rsqrtf(var + EPSLN);
    float4 gv = ((const float4*)g)[tid];
    float4 bv = ((const float4*)bta)[tid];
    float ovs[4];
    ovs[0] = (xv.x-mu)*rs*gv.x + bv.x;
    ovs[1] = (xv.y-mu)*rs*gv.y + bv.y;
    ovs[2] = (xv.z-mu)*rs*gv.z + bv.z;
    ovs[3] = (xv.w-mu)*rs*gv.w + bv.w;
    {
        __hip_bfloat16* p = h2b + (long)row*CC + tid*4;
        p[0] = __float2bfloat16(ovs[0]); p[1] = __float2bfloat16(ovs[1]);
        p[2] = __float2bfloat16(ovs[2]); p[3] = __float2bfloat16(ovs[3]);
    }
    // router: this thread's 4 contiguous channels
    float acc[17] = {};
    #pragma unroll
    for (int j = 0; j < 4; j++) {
        const float v = ovs[j];
        acc[16] += v*v;
        const float* sr = sim + (long)(tid*4 + j)*EE;
        #pragma unroll
        for (int e2 = 0; e2 < EE; e2++) acc[e2] += v*sr[e2];
    }
    #pragma unroll
    for (int e2 = 0; e2 < 17; e2++) red[tid*17 + e2] = acc[e2];
    __syncthreads();
    for (int st = 128; st > 0; st >>= 1) {
        if (tid < st)
            for (int e2 = 0; e2 < 17; e2++) red[tid*17+e2] += red[(tid+st)*17+e2];
        __syncthreads();
    }
    if (tid < EE) {
        const float nrm = sqrtf(red[16]);
        const float sc  = red[tid] / (nrm * cn[tid]);
        scores[(long)row*EE + tid] = sc;
        const float mkv = sc > thr[0] ? 1.f : 0.f;
        maskb[(long)row*EE + tid] = mkv;
        red[tid] = mkv;
        if (mkv > 0.f) {
            int slot = atomicAdd(&cnt[tid], 1);
            elist[(long)tid*NN + slot] = row;
        }
    }
    __syncthreads();
    if (tid == 0) {
        float c2 = 0.f;
        for (int e2 = 0; e2 < EE; e2++) c2 += red[e2];
        kpt[row] = c2;
    }
}

// ---------------------------------------------------------------------------
// Expert weight prep (single launch): z = half*16 + e. half0: w1 [C][I] ->
// w1t [I][C]; half1: w2 [I][C] -> w2t [C][I]. Flattened grid.x = 256 blocks/e.
// ---------------------------------------------------------------------------
__global__ __launch_bounds__(256) void transpose_f2b_both(const float* __restrict__ w1,
                                                          const float* __restrict__ w2,
                                                          __hip_bfloat16* __restrict__ w1t,
                                                          __hip_bfloat16* __restrict__ w2t) {
    const int zz = blockIdx.z;
    const int half = zz >> 4, e = zz & 15;
    const float* W; __hip_bfloat16* Wt; int K, N, nbx;
    if (half == 0) { W = w1 + (long)e*CC*II; Wt = w1t + (long)e*CC*II; K = CC; N = II; nbx = II/32; }
    else           { W = w2 + (long)e*II*CC; Wt = w2t + (long)e*II*CC; K = II; N = CC; nbx = CC/32; }
    const int bx = blockIdx.x;
    const int n0 = (bx % nbx) * 32, k0 = (bx / nbx) * 32;
    __shared__ float t[32][33];
    const int tx = threadIdx.x & 31, ty = threadIdx.x >> 5;
    #pragma unroll
    for (int i = 0; i < 4; i++)
        t[ty + i*8][tx] = W[(long)(k0 + ty + i*8)*N + n0 + tx];
    __syncthreads();
    #pragma unroll
    for (int i = 0; i < 4; i++)
        Wt[(long)(n0 + ty + i*8)*K + k0 + tx] = __float2bfloat16(t[tx][ty + i*8]);
}

// ---------------------------------------------------------------------------
// bf16 transpose for V: [b*T + t][C] (hi/lo) -> [(b*H + h)*64 + d][T] (hi/lo)
// ---------------------------------------------------------------------------
__global__ __launch_bounds__(256) void transpose_v_bf16(
        const __hip_bfloat16* __restrict__ Vh, const __hip_bfloat16* __restrict__ Vl,
        __hip_bfloat16* __restrict__ Vth, __hip_bfloat16* __restrict__ Vtl) {
    const int b = blockIdx.z;
    const int c0 = blockIdx.y * 32, t0 = blockIdx.x * 32;
    __shared__ unsigned short th[32][33], tl[32][33];
    const int tx = threadIdx.x & 31, ty = threadIdx.x >> 5;
    const unsigned short* vh = (const unsigned short*)Vh;
    const unsigned short* vl = (const unsigned short*)Vl;
    #pragma unroll
    for (int i = 0; i < 4; i++) {
        const long src = ((long)b*TT + t0 + ty + i*8)*CC + c0 + tx;
        th[ty + i*8][tx] = vh[src];
        tl[ty + i*8][tx] = vl[src];
    }
    __syncthreads();
    #pragma unroll
    for (int i = 0; i < 4; i++) {
        const int gc = c0 + ty + i*8;          // global channel
        const int hh = gc >> 6, d = gc & 63;
        const long dst = ((long)(b*HH + hh)*64 + d)*TT + t0 + tx;
        ((unsigned short*)Vth)[dst] = th[tx][ty + i*8];
        ((unsigned short*)Vtl)[dst] = tl[tx][ty + i*8];
    }
}

// ---------------------------------------------------------------------------
// Big-tile bf16x3 split GEMM (QKV): 128Mx128N, BK=32, 4 waves each 64x64.
// Staging via global_load_lds width=16 (direct HBM->LDS, no VGPR round trip).
// LDS is LINEAR [128][32] (required: dest = wave-uniform base + lane*16).
// Emits pre-split bf16 hi/lo. Same bytes, same MFMA order -> bit-identical.
// ---------------------------------------------------------------------------
__global__ __launch_bounds__(256, 2) void gemm_split_big(
        const __hip_bfloat16* __restrict__ Ah,
        const __hip_bfloat16* __restrict__ Al,
        const __hip_bfloat16* __restrict__ Bh_base,
        const __hip_bfloat16* __restrict__ Bl_base,
        __hip_bfloat16* __restrict__ Ch_base,
        __hip_bfloat16* __restrict__ Cl_base,
        int M, int N, int K) {
    __shared__ __hip_bfloat16 Ash[128][32], Asl[128][32];
    __shared__ __hip_bfloat16 Bsh[128][32], Bsl[128][32];
    const int z = blockIdx.z;
    const __hip_bfloat16* Bth = Bh_base + (long)z * N * K;
    const __hip_bfloat16* Btl = Bl_base + (long)z * N * K;
    const int n0 = blockIdx.x * 128, m0 = blockIdx.y * 128;
    const int tid = threadIdx.x;
    const int wave = tid >> 6, lane = tid & 63;
    const int wm = (wave >> 1) * 64, wn = (wave & 1) * 64;
    const int l15 = lane & 15, quad = lane >> 4;

    f32x4 acc[4][4] = {};

    for (int k0 = 0; k0 < K; k0 += 32) {
        // stage 4 buffers: each = 128 rows x 32 k x 2B = 8 KB = 8 wave-loads.
        // wave w issues chunks {2w, 2w+1}; lane maps row=(lane>>2), col=(lane&3)*8.
        #pragma unroll
        for (int i = 0; i < 2; i++) {
            const int chunk = wave*2 + i;              // 0..7
            const int r = chunk*16 + (lane >> 2);
            const int c8 = (lane & 3) * 8;
            const long aoff = (long)(m0 + r)*K + k0 + c8;
            const long boff = (long)(n0 + r)*K + k0 + c8;
            GLOAD_LDS16(Ah  + aoff, &Ash[chunk*16][0]);
            GLOAD_LDS16(Al  + aoff, &Asl[chunk*16][0]);
            GLOAD_LDS16(Bth + boff, &Bsh[chunk*16][0]);
            GLOAD_LDS16(Btl + boff, &Bsl[chunk*16][0]);
        }
        __syncthreads();
        short8 ah[4], al[4], bh[4], bl[4];
        #pragma unroll
        for (int i = 0; i < 4; i++) {
            ah[i] = *(const short8*)&Ash[wm + i*16 + l15][quad*8];
            al[i] = *(const short8*)&Asl[wm + i*16 + l15][quad*8];
            bh[i] = *(const short8*)&Bsh[wn + i*16 + l15][quad*8];
            bl[i] = *(const short8*)&Bsl[wn + i*16 + l15][quad*8];
        }
        #pragma unroll
        for (int mi = 0; mi < 4; mi++)
            #pragma unroll
            for (int ni = 0; ni < 4; ni++) {
                acc[mi][ni] = __builtin_amdgcn_mfma_f32_16x16x32_bf16(ah[mi], bh[ni], acc[mi][ni], 0,0,0);
                acc[mi][ni] = __builtin_amdgcn_mfma_f32_16x16x32_bf16(ah[mi], bl[ni], acc[mi][ni], 0,0,0);
                acc[mi][ni] = __builtin_amdgcn_mfma_f32_16x16x32_bf16(al[mi], bh[ni], acc[mi][ni], 0,0,0);
            }
        __syncthreads();
    }

    #pragma unroll
    for (int mi = 0; mi < 4; mi++)
        #pragma unroll
        for (int r = 0; r < 4; r++) {
            const int row = m0 + wm + mi*16 + quad*4 + r;
            #pragma unroll
            for (int ni = 0; ni < 4; ni++) {
                const int col = n0 + wn + ni*16 + l15;
                short hh, ll; splitbf(acc[mi][ni][r], hh, ll);
                *(short*)&Ch_base[(long)z*M*N + (long)row*N + col] = hh;
                *(short*)&Cl_base[(long)z*M*N + (long)row*N + col] = ll;
            }
        }
}

// ---------------------------------------------------------------------------
// fp32-accurate MFMA GEMM via bf16x3 split, 64Mx128N tile (WO path), with
// global_load_lds staging (linear LDS).
// ---------------------------------------------------------------------------
__global__ __launch_bounds__(256, 2) void gemm_split(
        const __hip_bfloat16* __restrict__ Ah,
        const __hip_bfloat16* __restrict__ Al,
        const __hip_bfloat16* __restrict__ Bth,
        const __hip_bfloat16* __restrict__ Btl,
        float* __restrict__ Cp,
        int M, int N, int K,
        const float* __restrict__ resid) {
    __shared__ __hip_bfloat16 Ash[64][32], Asl[64][32];
    __shared__ __hip_bfloat16 Bsh[128][32], Bsl[128][32];
    const int n0 = blockIdx.x * 128, m0 = blockIdx.y * 64;
    const int tid = threadIdx.x;
    const int wave = tid >> 6, lane = tid & 63;
    const int wm = (wave >> 1) * 32, wn = (wave & 1) * 64;
    const int l15 = lane & 15, quad = lane >> 4;

    f32x4 acc[2][4] = {};

    for (int k0 = 0; k0 < K; k0 += 32) {
        {   // A: 64x32 = 4KB/buffer = 4 wave-loads; wave w stages chunk w
            const int r = wave*16 + (lane >> 2);
            const int c8 = (lane & 3) * 8;
            const long aoff = (long)(m0 + r)*K + k0 + c8;
            GLOAD_LDS16(Ah + aoff, &Ash[wave*16][0]);
            GLOAD_LDS16(Al + aoff, &Asl[wave*16][0]);
        }
        #pragma unroll
        for (int i = 0; i < 2; i++) {   // B: 128x32 = 8KB/buffer = 8 wave-loads
            const int chunk = wave*2 + i;
            const int r = chunk*16 + (lane >> 2);
            const int c8 = (lane & 3) * 8;
            const long boff = (long)(n0 + r)*K + k0 + c8;
            GLOAD_LDS16(Bth + boff, &Bsh[chunk*16][0]);
            GLOAD_LDS16(Btl + boff, &Bsl[chunk*16][0]);
        }
        __syncthreads();
        short8 ah[2], al[2], bh[4], bl[4];
        #pragma unroll
        for (int mi = 0; mi < 2; mi++) {
            ah[mi] = *(const short8*)&Ash[wm + mi*16 + l15][quad*8];
            al[mi] = *(const short8*)&Asl[wm + mi*16 + l15][quad*8];
        }
        #pragma unroll
        for (int ni = 0; ni < 4; ni++) {
            bh[ni] = *(const short8*)&Bsh[wn + ni*16 + l15][quad*8];
            bl[ni] = *(const short8*)&Bsl[wn + ni*16 + l15][quad*8];
        }
        #pragma unroll
        for (int mi = 0; mi < 2; mi++)
            #pragma unroll
            for (int ni = 0; ni < 4; ni++) {
                acc[mi][ni] = __builtin_amdgcn_mfma_f32_16x16x32_bf16(ah[mi], bh[ni], acc[mi][ni], 0,0,0);
                acc[mi][ni] = __builtin_amdgcn_mfma_f32_16x16x32_bf16(ah[mi], bl[ni], acc[mi][ni], 0,0,0);
                acc[mi][ni] = __builtin_amdgcn_mfma_f32_16x16x32_bf16(al[mi], bh[ni], acc[mi][ni], 0,0,0);
            }
        __syncthreads();
    }

    #pragma unroll
    for (int mi = 0; mi < 2; mi++)
        #pragma unroll
        for (int r = 0; r < 4; r++) {
            const int row = m0 + wm + mi*16 + quad*4 + r;
            #pragma unroll
            for (int ni = 0; ni < 4; ni++) {
                const int col = n0 + wn + ni*16 + l15;
                Cp[(long)row*N + col] = acc[mi][ni][r] + resid[(long)row*N + col];
            }
        }
}

// ---------------------------------------------------------------------------
// Sparse expert GEMM1: mid[e][slot] = gelu(h2b[tok(slot)] @ w1t[e]^T), bf16.
// global_load_lds staging; A rows gathered via per-lane source addresses
// (rowmap cached in VGPRs). Blocks beyond cnt[e] exit.
// ---------------------------------------------------------------------------
__global__ __launch_bounds__(256) void gemm_moe1_sparse(
        const __hip_bfloat16* __restrict__ A,      // h2b [NN][CC]
        const __hip_bfloat16* __restrict__ w1t,    // [16][II][CC]
        __hip_bfloat16* __restrict__ mid,          // [16][NN][II] compacted
        const int* __restrict__ cnt,
        const int* __restrict__ elist) {
    __shared__ __hip_bfloat16 As[128][32];
    __shared__ __hip_bfloat16 Bs[128][32];
    __shared__ int rowmap[128];
    const int e = blockIdx.z;
    const int count = cnt[e];
    const int m0 = blockIdx.y * 128;
    if (m0 >= count) return;
    const int n0 = blockIdx.x * 128;
    const __hip_bfloat16* Bt = w1t + (long)e*II*CC;
    const int* lst = elist + (long)e*NN;
    const int tid = threadIdx.x;
    if (tid < 128) rowmap[tid] = lst[min(m0 + tid, count - 1)];
    __syncthreads();
    const int wave = tid >> 6, lane = tid & 63;
    const int wm = (wave >> 1) * 64, wn = (wave & 1) * 64;
    const int l15 = lane & 15, quad = lane >> 4;
    // cache this lane's 2 gather rows (for staging chunks wave*2, wave*2+1)
    int rm[2];
    #pragma unroll
    for (int i = 0; i < 2; i++) rm[i] = rowmap[(wave*2 + i)*16 + (lane >> 2)];

    f32x4 acc[4][4] = {};

    for (int k0 = 0; k0 < CC; k0 += 32) {
        #pragma unroll
        for (int i = 0; i < 2; i++) {
            const int chunk = wave*2 + i;
            const int r = chunk*16 + (lane >> 2);
            const int c8 = (lane & 3) * 8;
            GLOAD_LDS16(A  + (long)rm[i]*CC + k0 + c8, &As[chunk*16][0]);
            GLOAD_LDS16(Bt + (long)(n0 + r)*CC + k0 + c8, &Bs[chunk*16][0]);
        }
        __syncthreads();
        short8 af[4], bff[4];
        #pragma unroll
        for (int i = 0; i < 4; i++) {
            af[i]  = *(const short8*)&As[wm + i*16 + l15][quad*8];
            bff[i] = *(const short8*)&Bs[wn + i*16 + l15][quad*8];
        }
        #pragma unroll
        for (int mi = 0; mi < 4; mi++)
            #pragma unroll
            for (int ni = 0; ni < 4; ni++)
                acc[mi][ni] = __builtin_amdgcn_mfma_f32_16x16x32_bf16(
                                  af[mi], bff[ni], acc[mi][ni], 0, 0, 0);
        __syncthreads();
    }

    #pragma unroll
    for (int mi = 0; mi < 4; mi++) {
        #pragma unroll
        for (int r = 0; r < 4; r++) {
            const int slot = m0 + wm + mi*16 + quad*4 + r;
            if (slot < count) {
                #pragma unroll
                for (int ni = 0; ni < 4; ni++) {
                    const int col = n0 + wn + ni*16 + l15;
                    float val = acc[mi][ni][r];
                    val = 0.5f*val*(1.f + erff(val*0.70710678118f));
                    mid[((long)e*NN + slot)*II + col] = __float2bfloat16(val);
                }
            }
        }
    }
}

// ---------------------------------------------------------------------------
// Sparse expert GEMM2: eo[tok(slot), e, :] = mid[e][slot] @ w2t[e]^T
// global_load_lds staging (both operands contiguous). No atomics.
// ---------------------------------------------------------------------------
__global__ __launch_bounds__(256) void gemm_moe2_sparse(
        const __hip_bfloat16* __restrict__ mid,    // [16][NN][II] compacted
        const __hip_bfloat16* __restrict__ w2t,    // [16][CC][II]
        float* __restrict__ eo,                    // [NN][EE][CC]
        const int* __restrict__ cnt,
        const int* __restrict__ elist) {
    __shared__ __hip_bfloat16 As[128][32];
    __shared__ __hip_bfloat16 Bs[128][32];
    __shared__ int rowmap[128];
    const int e = blockIdx.z;
    const int count = cnt[e];
    const int m0 = blockIdx.y * 128;
    if (m0 >= count) return;
    const int n0 = blockIdx.x * 128;
    const __hip_bfloat16* A  = mid + (long)e*NN*II;
    const __hip_bfloat16* Bt = w2t + (long)e*CC*II;
    const int* lst = elist + (long)e*NN;
    const int tid = threadIdx.x;
    if (tid < 128) rowmap[tid] = lst[min(m0 + tid, count - 1)];
    __syncthreads();
    const int wave = tid >> 6, lane = tid & 63;
    const int wm = (wave >> 1) * 64, wn = (wave & 1) * 64;
    const int l15 = lane & 15, quad = lane >> 4;

    f32x4 acc[4][4] = {};

    for (int k0 = 0; k0 < II; k0 += 32) {
        #pragma unroll
        for (int i = 0; i < 2; i++) {
            const int chunk = wave*2 + i;
            const int r = chunk*16 + (lane >> 2);
            const int c8 = (lane & 3) * 8;
            GLOAD_LDS16(A  + (long)(m0 + r)*II + k0 + c8, &As[chunk*16][0]);
            GLOAD_LDS16(Bt + (long)(n0 + r)*II + k0 + c8, &Bs[chunk*16][0]);
        }
        __syncthreads();
        short8 af[4], bff[4];
        #pragma unroll
        for (int i = 0; i < 4; i++) {
            af[i]  = *(const short8*)&As[wm + i*16 + l15][quad*8];
            bff[i] = *(const short8*)&Bs[wn + i*16 + l15][quad*8];
        }
        #pragma unroll
        for (int mi = 0; mi < 4; mi++)
            #pragma unroll
            for (int ni = 0; ni < 4; ni++)
                acc[mi][ni] = __builtin_amdgcn_mfma_f32_16x16x32_bf16(
                                  af[mi], bff[ni], acc[mi][ni], 0, 0, 0);
        __syncthreads();
    }

    #pragma unroll
    for (int mi = 0; mi < 4; mi++) {
        #pragma unroll
        for (int r = 0; r < 4; r++) {
            const int slot = m0 + wm + mi*16 + quad*4 + r;
            if (slot < count) {
                const int tok = rowmap[wm + mi*16 + quad*4 + r];
                #pragma unroll
                for (int ni = 0; ni < 4; ni++) {
                    const int col = n0 + wn + ni*16 + l15;
                    eo[((long)tok*EE + e)*CC + col] = acc[mi][ni][r];
                }
            }
        }
    }
}

// ---------------------------------------------------------------------------
// Fused: zero inactive eo rows + final[n,:] = sum over active e of eo[n,e,:];
// xio += final. Deterministic e-ascending order (skipping exact zeros is
// bitwise-identical to summing them).
// ---------------------------------------------------------------------------
__global__ __launch_bounds__(256) void moe_sum_zero(const float* __restrict__ maskb,
                                                    float* __restrict__ eo,
                                                    float* __restrict__ xio) {
    const int row = blockIdx.x, tid = threadIdx.x;
    float4 s = {0.f, 0.f, 0.f, 0.f};
    const float4 z4 = {0.f, 0.f, 0.f, 0.f};
    #pragma unroll
    for (int e = 0; e < EE; e++) {
        float4* p = ((float4*)(eo + ((long)row*EE + e)*CC)) + tid;
        if (maskb[(long)row*EE + e] != 0.f) {
            float4 v = *p;
            s.x += v.x; s.y += v.y; s.z += v.z; s.w += v.w;
        } else {
            *p = z4;
        }
    }
    float4 xv = ((float4*)(xio + (long)row*CC))[tid];
    xv.x += s.x; xv.y += s.y; xv.z += s.z; xv.w += s.w;
    ((float4*)(xio + (long)row*CC))[tid] = xv;
}

// ---------------------------------------------------------------------------
// Flash attention with bf16x3 MFMA for QK^T and PV. kt-split for balance.
// All inputs PRE-SPLIT bf16 hi/lo; V pre-transposed [(b*H+h)*64+d][T].
// T14 async-STAGE prefetch + T5 setprio around MFMA clusters.
// ---------------------------------------------------------------------------
__global__ __launch_bounds__(256, 4) void attn_split(
        const __hip_bfloat16* __restrict__ Qh, const __hip_bfloat16* __restrict__ Ql,
        const __hip_bfloat16* __restrict__ Kh, const __hip_bfloat16* __restrict__ Kl,
        const __hip_bfloat16* __restrict__ Vtg_h, const __hip_bfloat16* __restrict__ Vtg_l,
        float* __restrict__ Opart,
        float* __restrict__ mpart,
        float* __restrict__ lpart) {
    __shared__ __hip_bfloat16 KPh[64][LDA], KPl[64][LDA];   // K, then P
    __shared__ __hip_bfloat16 Vth[64][LDA], Vtl[64][LDA];   // V^T [d][kk]

    const int bx = blockIdx.x;                 // 0..31, heavy qt first
    const int qt = 15 - (bx >> 1), half = bx & 1;
    const int h = blockIdx.y, b = blockIdx.z;
    const int tid = threadIdx.x;
    const int wave = tid >> 6, lane = tid & 63;
    const int l15 = lane & 15, quad = lane >> 4;
    const int wm = wave * 16;                  // wave's 16 q-rows in the 64-tile
    const long tbase = (long)b * TT * CC + (long)h * DD;          // [token][C] slab
    const long vbase = (long)(b*HH + h) * 64 * TT;                // V^T slab
    const int pidx = ((b*HH + h)*16 + qt)*2 + half;
    float* Op = Opart + (long)pidx * 4096;

    const int n_kt = qt + 1, mid_kt = (n_kt + 1) >> 1;
    const int kt_lo = half ? mid_kt : 0;
    const int kt_hi = half ? n_kt   : mid_kt;

    if (kt_lo >= kt_hi) {      // empty half (qt=0): neutral partials
        for (int i = tid; i < 64*64; i += 256) Op[i] = 0.f;
        if (tid < 64) { mpart[(long)pidx*64 + tid] = -1e30f; lpart[(long)pidx*64 + tid] = 0.f; }
        return;
    }

    // Q A-fragments direct from pre-split global
    short8 qh[2], ql[2];
    {
        const long qoff = tbase + (long)(qt*64 + wm + l15)*CC;
        #pragma unroll
        for (int kc = 0; kc < 2; kc++) {
            qh[kc] = *(const short8*)(Qh + qoff + kc*32 + quad*8);
            ql[kc] = *(const short8*)(Ql + qoff + kc*32 + quad*8);
        }
    }

    // staging geometry: this thread covers rows r0 and r0+32, col group g0
    const int r0 = tid >> 3, g0 = (tid & 7) * 8;

    // prefetch registers for the next K/V tile (T14 async-STAGE split)
    short8 sKh0, sKl0, sVh0, sVl0, sKh1, sKl1, sVh1, sVl1;
    {
        const int kt = kt_lo;
        const long k0off = tbase + (long)(kt*64 + r0)*CC + g0;
        const long k1off = tbase + (long)(kt*64 + r0 + 32)*CC + g0;
        const long v0off = vbase + (long)r0*TT + kt*64 + g0;
        const long v1off = vbase + (long)(r0 + 32)*TT + kt*64 + g0;
        sKh0 = *(const short8*)(Kh + k0off);    sKl0 = *(const short8*)(Kl + k0off);
        sKh1 = *(const short8*)(Kh + k1off);    sKl1 = *(const short8*)(Kl + k1off);
        sVh0 = *(const short8*)(Vtg_h + v0off); sVl0 = *(const short8*)(Vtg_l + v0off);
        sVh1 = *(const short8*)(Vtg_h + v1off); sVl1 = *(const short8*)(Vtg_l + v1off);
    }

    f32x4 oacc[4] = {};            // 4 d-tiles, rows = quad*4+reg
    float m_run[4], l_run[4];
    #pragma unroll
    for (int r = 0; r < 4; r++) { m_run[r] = -1e30f; l_run[r] = 0.f; }

    for (int kt = kt_lo; kt < kt_hi; kt++) {
        __syncthreads();           // prev-iter PV reads of KP/Vt done
        // write prefetched tile to LDS
        *(short8*)&KPh[r0][g0]      = sKh0;  *(short8*)&KPl[r0][g0]      = sKl0;
        *(short8*)&KPh[r0 + 32][g0] = sKh1;  *(short8*)&KPl[r0 + 32][g0] = sKl1;
        *(short8*)&Vth[r0][g0]      = sVh0;  *(short8*)&Vtl[r0][g0]      = sVl0;
        *(short8*)&Vth[r0 + 32][g0] = sVh1;  *(short8*)&Vtl[r0 + 32][g0] = sVl1;
        // issue next tile's global loads (latency hides under QK/softmax/PV)
        if (kt + 1 < kt_hi) {
            const int kn = kt + 1;
            const long k0off = tbase + (long)(kn*64 + r0)*CC + g0;
            const long k1off = tbase + (long)(kn*64 + r0 + 32)*CC + g0;
            const long v0off = vbase + (long)r0*TT + kn*64 + g0;
            const long v1off = vbase + (long)(r0 + 32)*TT + kn*64 + g0;
            sKh0 = *(const short8*)(Kh + k0off);    sKl0 = *(const short8*)(Kl + k0off);
            sKh1 = *(const short8*)(Kh + k1off);    sKl1 = *(const short8*)(Kl + k1off);
            sVh0 = *(const short8*)(Vtg_h + v0off); sVl0 = *(const short8*)(Vtg_l + v0off);
            sVh1 = *(const short8*)(Vtg_h + v1off); sVl1 = *(const short8*)(Vtg_l + v1off);
        }
        __syncthreads();

        // QK^T via MFMA: 4 key-tiles x 2 k-chunks x 3 split terms (T5 setprio)
        f32x4 s[4] = {};
        __builtin_amdgcn_s_setprio(1);
        #pragma unroll
        for (int nt = 0; nt < 4; nt++)
            #pragma unroll
            for (int kc = 0; kc < 2; kc++) {
                short8 bh = *(const short8*)&KPh[nt*16 + l15][kc*32 + quad*8];
                short8 bl = *(const short8*)&KPl[nt*16 + l15][kc*32 + quad*8];
                s[nt] = __builtin_amdgcn_mfma_f32_16x16x32_bf16(qh[kc], bh, s[nt], 0,0,0);
                s[nt] = __builtin_amdgcn_mfma_f32_16x16x32_bf16(qh[kc], bl, s[nt], 0,0,0);
                s[nt] = __builtin_amdgcn_mfma_f32_16x16x32_bf16(ql[kc], bh, s[nt], 0,0,0);
            }
        __builtin_amdgcn_s_setprio(0);

        // online softmax in regs; row = wm + quad*4 + r, col = nt*16 + l15
        const bool diag = (kt == qt);
        float alpha[4];
        float pr[4][4];
        #pragma unroll
        for (int r = 0; r < 4; r++) {
            const int rowg = wm + quad*4 + r;
            float sv[4], mx = -1e30f;
            #pragma unroll
            for (int nt = 0; nt < 4; nt++) {
                float val = s[nt][r] * 0.125f;
                if (diag && (nt*16 + l15) > rowg) val = -1e30f;
                sv[nt] = val;
                mx = fmaxf(mx, val);
            }
            #pragma unroll
            for (int off = 1; off < 16; off <<= 1) mx = fmaxf(mx, __shfl_xor(mx, off, 16));
            const float mnew = fmaxf(m_run[r], mx);
            alpha[r] = __expf(m_run[r] - mnew);
            float rs = 0.f;
            #pragma unroll
            for (int nt = 0; nt < 4; nt++) {
                float p = __expf(sv[nt] - mnew);
                pr[r][nt] = p;
                rs += p;
            }
            #pragma unroll
            for (int off = 1; off < 16; off <<= 1) rs += __shfl_xor(rs, off, 16);
            l_run[r] = l_run[r]*alpha[r] + rs;
            m_run[r] = mnew;
        }
        __syncthreads();           // all QK reads of KP done -> overwrite as P

        // write P split into KP region: row = wm+quad*4+r, col = nt*16+l15
        #pragma unroll
        for (int r = 0; r < 4; r++)
            #pragma unroll
            for (int nt = 0; nt < 4; nt++) {
                short hh, ll; splitbf(pr[r][nt], hh, ll);
                *(short*)&KPh[wm + quad*4 + r][nt*16 + l15] = hh;
                *(short*)&KPl[wm + quad*4 + r][nt*16 + l15] = ll;
            }
        // no barrier: PV reads only this wave's own 16 P-rows

        // rescale O and accumulate PV via MFMA (T5 setprio)
        #pragma unroll
        for (int dt = 0; dt < 4; dt++)
            #pragma unroll
            for (int r = 0; r < 4; r++)
                oacc[dt][r] *= alpha[r];
        __builtin_amdgcn_s_setprio(1);
        #pragma unroll
        for (int kc = 0; kc < 2; kc++) {
            short8 ph = *(const short8*)&KPh[wm + l15][kc*32 + quad*8];
            short8 pl = *(const short8*)&KPl[wm + l15][kc*32 + quad*8];
            #pragma unroll
            for (int dt = 0; dt < 4; dt++) {
                short8 vh = *(const short8*)&Vth[dt*16 + l15][kc*32 + quad*8];
                short8 vl = *(const short8*)&Vtl[dt*16 + l15][kc*32 + quad*8];
                oacc[dt] = __builtin_amdgcn_mfma_f32_16x16x32_bf16(ph, vh, oacc[dt], 0,0,0);
                oacc[dt] = __builtin_amdgcn_mfma_f32_16x16x32_bf16(ph, vl, oacc[dt], 0,0,0);
                oacc[dt] = __builtin_amdgcn_mfma_f32_16x16x32_bf16(pl, vh, oacc[dt], 0,0,0);
            }
        }
        __builtin_amdgcn_s_setprio(0);
    }

    // store unnormalized O partial + (m,l)
    #pragma unroll
    for (int dt = 0; dt < 4; dt++)
        #pragma unroll
        for (int r = 0; r < 4; r++)
            Op[(wm + quad*4 + r)*64 + dt*16 + l15] = oacc[dt][r];
    if (l15 == 0) {
        #pragma unroll
        for (int r = 0; r < 4; r++) {
            mpart[(long)pidx*64 + wm + quad*4 + r] = m_run[r];
            lpart[(long)pidx*64 + wm + quad*4 + r] = l_run[r];
        }
    }
}

// ---------------------------------------------------------------------------
// Merge the two kt-half partials -> normalized attention output, emitted as
// pre-split bf16 hi/lo (direct feed for the WO bf16x3 GEMM).
// ---------------------------------------------------------------------------
__global__ __launch_bounds__(256) void attn_merge(const float* __restrict__ Opart,
                                                  const float* __restrict__ mpart,
                                                  const float* __restrict__ lpart,
                                                  __hip_bfloat16* __restrict__ aoh,
                                                  __hip_bfloat16* __restrict__ aol) {
    const int qt = blockIdx.x, h = blockIdx.y, b = blockIdx.z;
    const int pA = ((b*HH + h)*16 + qt)*2, pB = pA + 1;
    const int tid = threadIdx.x;
    const int r = tid >> 2, c0 = (tid & 3) * 16;
    const float mA = mpart[(long)pA*64 + r], mB = mpart[(long)pB*64 + r];
    const float lA = lpart[(long)pA*64 + r], lB = lpart[(long)pB*64 + r];
    const float M  = fmaxf(mA, mB);
    const float wA = __expf(mA - M), wB = __expf(mB - M);
    const float inv = 1.f / (lA*wA + lB*wB);
    const float* OA = Opart + (long)pA*4096 + r*64 + c0;
    const float* OB = Opart + (long)pB*4096 + r*64 + c0;
    const long dst = (long)b*TT*CC + (long)(qt*64 + r)*CC + h*DD + c0;
    #pragma unroll
    for (int j = 0; j < 16; j += 4) {
        float4 oa = *(const float4*)(OA + j);
        float4 ob = *(const float4*)(OB + j);
        float xs[4];
        xs[0] = (oa.x*wA + ob.x*wB)*inv;
        xs[1] = (oa.y*wA + ob.y*wB)*inv;
        xs[2] = (oa.z*wA + ob.z*wB)*inv;
        xs[3] = (oa.w*wA + ob.w*wB)*inv;
        s16x4 hv, lv;
        #pragma unroll
        for (int t = 0; t < 4; t++) { short hh,ll; splitbf(xs[t],hh,ll); hv[t]=hh; lv[t]=ll; }
        *(s16x4*)(aoh + dst + j) = hv;
        *(s16x4*)(aol + dst + j) = lv;
    }
}

// ---------------------------------------------------------------------------
extern "C" void kernel_launch(void* const* d_in, const int* in_sizes, int n_in,
                              void* d_out, int out_size, void* d_ws, size_t ws_size,
                              hipStream_t stream) {
    const float* x     = (const float*)d_in[0];
    const float* ln1_g = (const float*)d_in[1];
    const float* ln1_b = (const float*)d_in[2];
    const float* ln2_g = (const float*)d_in[3];
    const float* ln2_b = (const float*)d_in[4];
    const float* wq    = (const float*)d_in[5];
    const float* wk    = (const float*)d_in[6];
    const float* wv    = (const float*)d_in[7];
    const float* wo    = (const float*)d_in[8];
    const float* sim   = (const float*)d_in[9];
    const float* thr   = (const float*)d_in[10];
    const float* w1    = (const float*)d_in[11];
    const float* w2    = (const float*)d_in[12];

    float* out_x      = (float*)d_out;
    float* out_scores = out_x + (long)NN*CC;
    float* out_eo     = out_scores + (long)NN*EE;
    float* out_kpt    = out_eo + (long)NN*EE*CC;

    const long MF = (long)NN*CC;     // 2M floats
    const long CK = (long)CC*CC;     // 1M elems per weight slab
    float* ws   = (float*)d_ws;
    // [0, MF): attn-out split bf16 (hi/lo)
    __hip_bfloat16* aoh = (__hip_bfloat16*)ws;
    __hip_bfloat16* aol = (__hip_bfloat16*)(ws + MF/2);
    // [MF, 4MF): QKV pre-split bf16 (3 slabs hi, 3 slabs lo)
    __hip_bfloat16* qkvh = (__hip_bfloat16*)(ws + MF);
    __hip_bfloat16* qkvl = (__hip_bfloat16*)(ws + MF + 3*MF/2);
    // [4MF, 5MF): V^T pre-split bf16
    __hip_bfloat16* vth = (__hip_bfloat16*)(ws + 4*MF);
    __hip_bfloat16* vtl = (__hip_bfloat16*)(ws + 4*MF + MF/2);
    // [5MF, 5.5MF): LN2 bf16 for expert GEMM
    __hip_bfloat16* h2b = (__hip_bfloat16*)(ws + 5*MF);
    // [5.5MF, 7.5MF): attn partials; hh/hl (LN1 split) + mid alias
    float* Opart = ws + 5*MF + MF/2;
    __hip_bfloat16* hh  = (__hip_bfloat16*)(ws + 5*MF + MF/2);       // dead after QKV GEMM
    __hip_bfloat16* hl  = (__hip_bfloat16*)(ws + 6*MF);
    __hip_bfloat16* mid = (__hip_bfloat16*)(ws + 5*MF + MF/2);       // after merge
    // [7.5MF, 9.5MF): QKVO weight splits; w1t/w2t alias (after WO GEMM)
    __hip_bfloat16* wsph = (__hip_bfloat16*)(ws + 7*MF + MF/2);      // [4][C][C] hi
    __hip_bfloat16* wspl = (__hip_bfloat16*)(ws + 8*MF + MF/2);      // [4][C][C] lo
    __hip_bfloat16* w1t  = (__hip_bfloat16*)(ws + 7*MF + MF/2);
    __hip_bfloat16* w2t  = (__hip_bfloat16*)(ws + 8*MF + MF/2);
    float* maskb = ws + 9*MF + MF/2;                                  // 32K floats
    float* cn    = maskb + (long)NN*EE;                               // 16
    float* mpart = cn + 16;                                           // 64K
    float* lpart = mpart + 1024L*64;                                  // 64K
    int*   cnt   = (int*)(lpart + 1024L*64);                          // 16 ints
    int*   elist = cnt + 16;                                          // EE*NN ints

    // 0. fused prep: QKVO weight split + LN1 + sim col-norms + cnt zero
    prep_kernel<<<4096 + NN + EE, 256, 0, stream>>>(
        x, ln1_g, ln1_b, hh, hl, wq, wk, wv, wo, wsph, wspl, sim, cn, cnt);

    // 1. fused QKV projection, 128x128 tile, global_load_lds staging
    {
        dim3 gq(CC/128, NN/128, 3);
        gemm_split_big<<<gq, 256, 0, stream>>>(hh, hl, wsph, wspl,
                                               qkvh, qkvl, NN, CC, CC);
    }

    // 1.5 V transpose (bf16 hi/lo): [token][C] -> per-(b,h) [d][T]
    {
        dim3 gv(TT/32, CC/32, BB);
        transpose_v_bf16<<<gv, 256, 0, stream>>>(qkvh + 2*(long)NN*CC, qkvl + 2*(long)NN*CC,
                                                 vth, vtl);
    }

    // 2. causal attention (MFMA flash, prefetch + setprio) + merge
    {
        dim3 gattn(32, HH, BB);
        attn_split<<<gattn, 256, 0, stream>>>(qkvh, qkvl,
                                              qkvh + (long)NN*CC, qkvl + (long)NN*CC,
                                              vth, vtl, Opart, mpart, lpart);
        dim3 gmerge(16, HH, BB);
        attn_merge<<<gmerge, 256, 0, stream>>>(Opart, mpart, lpart, aoh, aol);
    }

    // 3. output projection + residual -> d_out x slot (gload_lds staging)
    {
        dim3 go(CC/128, NN/64, 1);
        gemm_split<<<go, 256, 0, stream>>>(aoh, aol, wsph + 3*CK, wspl + 3*CK,
                                           out_x, NN, CC, CC, x);
    }

    // 4. expert weight transposes (single launch; safe to overwrite QKVO splits)
    {
        dim3 ge(256, 1, 2*EE);
        transpose_f2b_both<<<ge, 256, 0, stream>>>(w1, w2, w1t, w2t);
    }

    // 5. fused LN2 + router + active-token compaction
    ln2_router<<<NN, 256, 0, stream>>>(out_x, ln2_g, ln2_b, sim, cn, thr,
                                       h2b, out_scores, out_kpt, maskb,
                                       cnt, elist);

    // 6. sparse expert GEMM 1: mid[e][slot] = gelu(h2[tok] @ w1[e])
    {
        dim3 g(II/128, NN/128, EE);
        gemm_moe1_sparse<<<g, 256, 0, stream>>>(h2b, w1t, mid, cnt, elist);
    }

    // 7. sparse expert GEMM 2: eo[tok,e,:] = mid[e][slot] @ w2[e]
    {
        dim3 g(CC/128, NN/128, EE);
        gemm_moe2_sparse<<<g, 256, 0, stream>>>(mid, w2t, out_eo, cnt, elist);
    }

    // 8. fused: zero inactive eo rows + sum active -> x (deterministic order)
    moe_sum_zero<<<NN, 256, 0, stream>>>(maskb, out_eo, out_x);
}

// Round 11
// 441.436 us; speedup vs baseline: 1.1009x; 1.0128x over previous
//
#include <hip/hip_runtime.h>
#include <hip/hip_bf16.h>
#include <math.h>

// Problem constants
#define BB 2
#define TT 1024
#define CC 1024
#define HH 16
#define DD 64
#define EE 16
#define II 256
#define NN (BB*TT)          // 2048 tokens
#define EPSLN 1e-5f
#define LDA 72              // bf16 LDS row stride: 144B rows, 16B-aligned

typedef __attribute__((ext_vector_type(8))) short short8;
typedef __attribute__((ext_vector_type(4))) short s16x4;
typedef __attribute__((ext_vector_type(4))) float f32x4;

// Direct global->LDS 16B copy: LDS dest = uniform base + lane*16.
#define GLOAD_LDS16(g, l) \
    __builtin_amdgcn_global_load_lds((const __attribute__((address_space(1))) void*)(g), \
                                     (__attribute__((address_space(3))) void*)(l), 16, 0, 0)

// T1 XCD-aware chunked swizzle (bijective when total wg count % 8 == 0):
// consecutive ORIGINAL tile ids land on the SAME XCD -> panel reuse in L2.
__device__ inline void xcd_swizzle3(int& xx, int& yy, int& zz) {
    const int nx = gridDim.x, ny = gridDim.y;
    const int nwg = nx * ny * gridDim.z;
    const int wgid = blockIdx.x + nx * (blockIdx.y + ny * blockIdx.z);
    const int orig = (wgid & 7) * (nwg >> 3) + (wgid >> 3);
    xx = orig % nx;
    const int t = orig / nx;
    yy = t % ny;
    zz = t / ny;
}

__device__ inline void splitbf(float x, short& hi, short& lo) {
    __hip_bfloat16 h = __float2bfloat16(x);
    float hf = __bfloat162float(h);
    __hip_bfloat16 l = __float2bfloat16(x - hf);
    hi = *(short*)&h;
    lo = *(short*)&l;
}

// ---------------------------------------------------------------------------
// Fused prep (single launch, flattened grid):
//   blocks [0, 4096):        QKVO weight transpose + bf16x3 split
//   blocks [4096, 4096+NN):  LN1 -> pre-split bf16 hi/lo
//   blocks [4096+NN, +EE):   sim column norms + zero compaction counters
// ---------------------------------------------------------------------------
__global__ __launch_bounds__(256) void prep_kernel(
        const float* __restrict__ x,
        const float* __restrict__ ln1_g, const float* __restrict__ ln1_b,
        __hip_bfloat16* __restrict__ outh, __hip_bfloat16* __restrict__ outl,
        const float* __restrict__ W0, const float* __restrict__ W1,
        const float* __restrict__ W2, const float* __restrict__ W3,
        __hip_bfloat16* __restrict__ Wth_base, __hip_bfloat16* __restrict__ Wtl_base,
        const float* __restrict__ sim, float* __restrict__ cn,
        int* __restrict__ cnt) {
    __shared__ float sh[32*33];
    const int bid = blockIdx.x, tid = threadIdx.x;
    if (bid < 4096) {
        // ---- QKVO weight transpose + split ----
        const int z = bid >> 10;
        const float* W = (z==0) ? W0 : (z==1) ? W1 : (z==2) ? W2 : W3;
        __hip_bfloat16* Wth = Wth_base + (long)z*CC*CC;
        __hip_bfloat16* Wtl = Wtl_base + (long)z*CC*CC;
        const int n0 = (bid & 31) * 32, k0 = ((bid >> 5) & 31) * 32;
        float (*t)[33] = (float(*)[33])sh;
        const int tx = tid & 31, ty = tid >> 5;
        #pragma unroll
        for (int i = 0; i < 4; i++)
            t[ty + i*8][tx] = W[(long)(k0 + ty + i*8)*CC + n0 + tx];
        __syncthreads();
        #pragma unroll
        for (int i = 0; i < 4; i++) {
            float v = t[tx][ty + i*8];
            short h, l; splitbf(v, h, l);
            *(short*)&Wth[(long)(n0 + ty + i*8)*CC + k0 + tx] = h;
            *(short*)&Wtl[(long)(n0 + ty + i*8)*CC + k0 + tx] = l;
        }
    } else if (bid < 4096 + NN) {
        // ---- LN1 -> pre-split bf16 hi/lo ----
        const int row = bid - 4096;
        float* r1 = sh;
        float* r2 = sh + 256;
        const float* xr = x + (long)row * CC;
        float4 xv = ((const float4*)xr)[tid];
        float s  = xv.x + xv.y + xv.z + xv.w;
        float q2 = xv.x*xv.x + xv.y*xv.y + xv.z*xv.z + xv.w*xv.w;
        r1[tid] = s; r2[tid] = q2; __syncthreads();
        for (int st = 128; st > 0; st >>= 1) {
            if (tid < st) { r1[tid] += r1[tid+st]; r2[tid] += r2[tid+st]; }
            __syncthreads();
        }
        const float mu  = r1[0] * (1.f/CC);
        const float var = r2[0] * (1.f/CC) - mu*mu;
        const float rs  = rsqrtf(var + EPSLN);
        float4 gv = ((const float4*)ln1_g)[tid];
        float4 bv = ((const float4*)ln1_b)[tid];
        float xs[4];
        xs[0] = (xv.x-mu)*rs*gv.x + bv.x;
        xs[1] = (xv.y-mu)*rs*gv.y + bv.y;
        xs[2] = (xv.z-mu)*rs*gv.z + bv.z;
        xs[3] = (xv.w-mu)*rs*gv.w + bv.w;
        s16x4 hv, lv;
        #pragma unroll
        for (int j = 0; j < 4; j++) { short h,l; splitbf(xs[j], h, l); hv[j]=h; lv[j]=l; }
        *(s16x4*)(outh + (long)row * CC + tid*4) = hv;
        *(s16x4*)(outl + (long)row * CC + tid*4) = lv;
    } else {
        // ---- sim column norms + zero counters ----
        const int e = bid - 4096 - NN;
        float* red = sh;
        float s = 0.f;
        for (int c = tid; c < CC; c += 256) {
            float vv = sim[(long)c*EE + e];
            s += vv*vv;
        }
        red[tid] = s; __syncthreads();
        for (int st = 128; st > 0; st >>= 1) {
            if (tid < st) red[tid] += red[tid+st];
            __syncthreads();
        }
        if (tid == 0) { cn[e] = sqrtf(red[0]); cnt[e] = 0; }
    }
}

// ---------------------------------------------------------------------------
// Fused LN2 + router: LN -> h2b bf16; scores/mask/k_per_token; and per-expert
// active-token compaction lists (order-free: values don't depend on order).
// ---------------------------------------------------------------------------
__global__ __launch_bounds__(256) void ln2_router(const float* __restrict__ xio,
                                                  const float* __restrict__ g,
                                                  const float* __restrict__ bta,
                                                  const float* __restrict__ sim,
                                                  const float* __restrict__ cn,
                                                  const float* __restrict__ thr,
                                                  __hip_bfloat16* __restrict__ h2b,
                                                  float* __restrict__ scores,
                                                  float* __restrict__ kpt,
                                                  float* __restrict__ maskb,
                                                  int* __restrict__ cnt,
                                                  int* __restrict__ elist) {
    const int row = blockIdx.x, tid = threadIdx.x;
    __shared__ float r1[256], r2[256];
    __shared__ float red[256*17];
    float4 xv = ((const float4*)(xio + (long)row*CC))[tid];
    float s  = xv.x + xv.y + xv.z + xv.w;
    float q2 = xv.x*xv.x + xv.y*xv.y + xv.z*xv.z + xv.w*xv.w;
    r1[tid] = s; r2[tid] = q2; __syncthreads();
    for (int st = 128; st > 0; st >>= 1) {
        if (tid < st) { r1[tid] += r1[tid+st]; r2[tid] += r2[tid+st]; }
        __syncthreads();
    }
    const float mu  = r1[0] * (1.f/CC);
    const float var = r2[0] * (1.f/CC) - mu*mu;
    const float rs  = rsqrtf(var + EPSLN);
    float4 gv = ((const float4*)g)[tid];
    float4 bv = ((const float4*)bta)[tid];
    float ovs[4];
    ovs[0] = (xv.x-mu)*rs*gv.x + bv.x;
    ovs[1] = (xv.y-mu)*rs*gv.y + bv.y;
    ovs[2] = (xv.z-mu)*rs*gv.z + bv.z;
    ovs[3] = (xv.w-mu)*rs*gv.w + bv.w;
    {
        __hip_bfloat16* p = h2b + (long)row*CC + tid*4;
        p[0] = __float2bfloat16(ovs[0]); p[1] = __float2bfloat16(ovs[1]);
        p[2] = __float2bfloat16(ovs[2]); p[3] = __float2bfloat16(ovs[3]);
    }
    // router: this thread's 4 contiguous channels
    float acc[17] = {};
    #pragma unroll
    for (int j = 0; j < 4; j++) {
        const float v = ovs[j];
        acc[16] += v*v;
        const float* sr = sim + (long)(tid*4 + j)*EE;
        #pragma unroll
        for (int e2 = 0; e2 < EE; e2++) acc[e2] += v*sr[e2];
    }
    #pragma unroll
    for (int e2 = 0; e2 < 17; e2++) red[tid*17 + e2] = acc[e2];
    __syncthreads();
    for (int st = 128; st > 0; st >>= 1) {
        if (tid < st)
            for (int e2 = 0; e2 < 17; e2++) red[tid*17+e2] += red[(tid+st)*17+e2];
        __syncthreads();
    }
    if (tid < EE) {
        const float nrm = sqrtf(red[16]);
        const float sc  = red[tid] / (nrm * cn[tid]);
        scores[(long)row*EE + tid] = sc;
        const float mkv = sc > thr[0] ? 1.f : 0.f;
        maskb[(long)row*EE + tid] = mkv;
        red[tid] = mkv;
        if (mkv > 0.f) {
            int slot = atomicAdd(&cnt[tid], 1);
            elist[(long)tid*NN + slot] = row;
        }
    }
    __syncthreads();
    if (tid == 0) {
        float c2 = 0.f;
        for (int e2 = 0; e2 < EE; e2++) c2 += red[e2];
        kpt[row] = c2;
    }
}

// ---------------------------------------------------------------------------
// Expert weight prep (single launch): z = half*16 + e. half0: w1 [C][I] ->
// w1t [I][C]; half1: w2 [I][C] -> w2t [C][I]. Flattened grid.x = 256 blocks/e.
// ---------------------------------------------------------------------------
__global__ __launch_bounds__(256) void transpose_f2b_both(const float* __restrict__ w1,
                                                          const float* __restrict__ w2,
                                                          __hip_bfloat16* __restrict__ w1t,
                                                          __hip_bfloat16* __restrict__ w2t) {
    const int zz = blockIdx.z;
    const int half = zz >> 4, e = zz & 15;
    const float* W; __hip_bfloat16* Wt; int K, N, nbx;
    if (half == 0) { W = w1 + (long)e*CC*II; Wt = w1t + (long)e*CC*II; K = CC; N = II; nbx = II/32; }
    else           { W = w2 + (long)e*II*CC; Wt = w2t + (long)e*II*CC; K = II; N = CC; nbx = CC/32; }
    const int bx = blockIdx.x;
    const int n0 = (bx % nbx) * 32, k0 = (bx / nbx) * 32;
    __shared__ float t[32][33];
    const int tx = threadIdx.x & 31, ty = threadIdx.x >> 5;
    #pragma unroll
    for (int i = 0; i < 4; i++)
        t[ty + i*8][tx] = W[(long)(k0 + ty + i*8)*N + n0 + tx];
    __syncthreads();
    #pragma unroll
    for (int i = 0; i < 4; i++)
        Wt[(long)(n0 + ty + i*8)*K + k0 + tx] = __float2bfloat16(t[tx][ty + i*8]);
}

// ---------------------------------------------------------------------------
// bf16 transpose for V: [b*T + t][C] (hi/lo) -> [(b*H + h)*64 + d][T] (hi/lo)
// ---------------------------------------------------------------------------
__global__ __launch_bounds__(256) void transpose_v_bf16(
        const __hip_bfloat16* __restrict__ Vh, const __hip_bfloat16* __restrict__ Vl,
        __hip_bfloat16* __restrict__ Vth, __hip_bfloat16* __restrict__ Vtl) {
    const int b = blockIdx.z;
    const int c0 = blockIdx.y * 32, t0 = blockIdx.x * 32;
    __shared__ unsigned short th[32][33], tl[32][33];
    const int tx = threadIdx.x & 31, ty = threadIdx.x >> 5;
    const unsigned short* vh = (const unsigned short*)Vh;
    const unsigned short* vl = (const unsigned short*)Vl;
    #pragma unroll
    for (int i = 0; i < 4; i++) {
        const long src = ((long)b*TT + t0 + ty + i*8)*CC + c0 + tx;
        th[ty + i*8][tx] = vh[src];
        tl[ty + i*8][tx] = vl[src];
    }
    __syncthreads();
    #pragma unroll
    for (int i = 0; i < 4; i++) {
        const int gc = c0 + ty + i*8;          // global channel
        const int hh = gc >> 6, d = gc & 63;
        const long dst = ((long)(b*HH + hh)*64 + d)*TT + t0 + tx;
        ((unsigned short*)Vth)[dst] = th[tx][ty + i*8];
        ((unsigned short*)Vtl)[dst] = tl[tx][ty + i*8];
    }
}

// ---------------------------------------------------------------------------
// Big-tile bf16x3 split GEMM (QKV): 128Mx128N, BK=32, 4 waves each 64x64.
// global_load_lds staging, linear LDS, T1 XCD swizzle for L2 panel reuse.
// ---------------------------------------------------------------------------
__global__ __launch_bounds__(256, 2) void gemm_split_big(
        const __hip_bfloat16* __restrict__ Ah,
        const __hip_bfloat16* __restrict__ Al,
        const __hip_bfloat16* __restrict__ Bh_base,
        const __hip_bfloat16* __restrict__ Bl_base,
        __hip_bfloat16* __restrict__ Ch_base,
        __hip_bfloat16* __restrict__ Cl_base,
        int M, int N, int K) {
    __shared__ __hip_bfloat16 Ash[128][32], Asl[128][32];
    __shared__ __hip_bfloat16 Bsh[128][32], Bsl[128][32];
    int bx, by, bz;
    xcd_swizzle3(bx, by, bz);
    const int z = bz;
    const __hip_bfloat16* Bth = Bh_base + (long)z * N * K;
    const __hip_bfloat16* Btl = Bl_base + (long)z * N * K;
    const int n0 = bx * 128, m0 = by * 128;
    const int tid = threadIdx.x;
    const int wave = tid >> 6, lane = tid & 63;
    const int wm = (wave >> 1) * 64, wn = (wave & 1) * 64;
    const int l15 = lane & 15, quad = lane >> 4;

    f32x4 acc[4][4] = {};

    for (int k0 = 0; k0 < K; k0 += 32) {
        #pragma unroll
        for (int i = 0; i < 2; i++) {
            const int chunk = wave*2 + i;              // 0..7
            const int r = chunk*16 + (lane >> 2);
            const int c8 = (lane & 3) * 8;
            const long aoff = (long)(m0 + r)*K + k0 + c8;
            const long boff = (long)(n0 + r)*K + k0 + c8;
            GLOAD_LDS16(Ah  + aoff, &Ash[chunk*16][0]);
            GLOAD_LDS16(Al  + aoff, &Asl[chunk*16][0]);
            GLOAD_LDS16(Bth + boff, &Bsh[chunk*16][0]);
            GLOAD_LDS16(Btl + boff, &Bsl[chunk*16][0]);
        }
        __syncthreads();
        short8 ah[4], al[4], bh[4], bl[4];
        #pragma unroll
        for (int i = 0; i < 4; i++) {
            ah[i] = *(const short8*)&Ash[wm + i*16 + l15][quad*8];
            al[i] = *(const short8*)&Asl[wm + i*16 + l15][quad*8];
            bh[i] = *(const short8*)&Bsh[wn + i*16 + l15][quad*8];
            bl[i] = *(const short8*)&Bsl[wn + i*16 + l15][quad*8];
        }
        #pragma unroll
        for (int mi = 0; mi < 4; mi++)
            #pragma unroll
            for (int ni = 0; ni < 4; ni++) {
                acc[mi][ni] = __builtin_amdgcn_mfma_f32_16x16x32_bf16(ah[mi], bh[ni], acc[mi][ni], 0,0,0);
                acc[mi][ni] = __builtin_amdgcn_mfma_f32_16x16x32_bf16(ah[mi], bl[ni], acc[mi][ni], 0,0,0);
                acc[mi][ni] = __builtin_amdgcn_mfma_f32_16x16x32_bf16(al[mi], bh[ni], acc[mi][ni], 0,0,0);
            }
        __syncthreads();
    }

    #pragma unroll
    for (int mi = 0; mi < 4; mi++)
        #pragma unroll
        for (int r = 0; r < 4; r++) {
            const int row = m0 + wm + mi*16 + quad*4 + r;
            #pragma unroll
            for (int ni = 0; ni < 4; ni++) {
                const int col = n0 + wn + ni*16 + l15;
                short hh, ll; splitbf(acc[mi][ni][r], hh, ll);
                *(short*)&Ch_base[(long)z*M*N + (long)row*N + col] = hh;
                *(short*)&Cl_base[(long)z*M*N + (long)row*N + col] = ll;
            }
        }
}

// ---------------------------------------------------------------------------
// fp32-accurate MFMA GEMM via bf16x3 split, 64Mx128N tile (WO path), with
// global_load_lds staging (linear LDS) + T1 XCD swizzle.
// ---------------------------------------------------------------------------
__global__ __launch_bounds__(256, 2) void gemm_split(
        const __hip_bfloat16* __restrict__ Ah,
        const __hip_bfloat16* __restrict__ Al,
        const __hip_bfloat16* __restrict__ Bth,
        const __hip_bfloat16* __restrict__ Btl,
        float* __restrict__ Cp,
        int M, int N, int K,
        const float* __restrict__ resid) {
    __shared__ __hip_bfloat16 Ash[64][32], Asl[64][32];
    __shared__ __hip_bfloat16 Bsh[128][32], Bsl[128][32];
    int bx, by, bz;
    xcd_swizzle3(bx, by, bz);
    const int n0 = bx * 128, m0 = by * 64;
    const int tid = threadIdx.x;
    const int wave = tid >> 6, lane = tid & 63;
    const int wm = (wave >> 1) * 32, wn = (wave & 1) * 64;
    const int l15 = lane & 15, quad = lane >> 4;

    f32x4 acc[2][4] = {};

    for (int k0 = 0; k0 < K; k0 += 32) {
        {   // A: 64x32 = 4KB/buffer = 4 wave-loads; wave w stages chunk w
            const int r = wave*16 + (lane >> 2);
            const int c8 = (lane & 3) * 8;
            const long aoff = (long)(m0 + r)*K + k0 + c8;
            GLOAD_LDS16(Ah + aoff, &Ash[wave*16][0]);
            GLOAD_LDS16(Al + aoff, &Asl[wave*16][0]);
        }
        #pragma unroll
        for (int i = 0; i < 2; i++) {   // B: 128x32 = 8KB/buffer = 8 wave-loads
            const int chunk = wave*2 + i;
            const int r = chunk*16 + (lane >> 2);
            const int c8 = (lane & 3) * 8;
            const long boff = (long)(n0 + r)*K + k0 + c8;
            GLOAD_LDS16(Bth + boff, &Bsh[chunk*16][0]);
            GLOAD_LDS16(Btl + boff, &Bsl[chunk*16][0]);
        }
        __syncthreads();
        short8 ah[2], al[2], bh[4], bl[4];
        #pragma unroll
        for (int mi = 0; mi < 2; mi++) {
            ah[mi] = *(const short8*)&Ash[wm + mi*16 + l15][quad*8];
            al[mi] = *(const short8*)&Asl[wm + mi*16 + l15][quad*8];
        }
        #pragma unroll
        for (int ni = 0; ni < 4; ni++) {
            bh[ni] = *(const short8*)&Bsh[wn + ni*16 + l15][quad*8];
            bl[ni] = *(const short8*)&Bsl[wn + ni*16 + l15][quad*8];
        }
        #pragma unroll
        for (int mi = 0; mi < 2; mi++)
            #pragma unroll
            for (int ni = 0; ni < 4; ni++) {
                acc[mi][ni] = __builtin_amdgcn_mfma_f32_16x16x32_bf16(ah[mi], bh[ni], acc[mi][ni], 0,0,0);
                acc[mi][ni] = __builtin_amdgcn_mfma_f32_16x16x32_bf16(ah[mi], bl[ni], acc[mi][ni], 0,0,0);
                acc[mi][ni] = __builtin_amdgcn_mfma_f32_16x16x32_bf16(al[mi], bh[ni], acc[mi][ni], 0,0,0);
            }
        __syncthreads();
    }

    #pragma unroll
    for (int mi = 0; mi < 2; mi++)
        #pragma unroll
        for (int r = 0; r < 4; r++) {
            const int row = m0 + wm + mi*16 + quad*4 + r;
            #pragma unroll
            for (int ni = 0; ni < 4; ni++) {
                const int col = n0 + wn + ni*16 + l15;
                Cp[(long)row*N + col] = acc[mi][ni][r] + resid[(long)row*N + col];
            }
        }
}

// ---------------------------------------------------------------------------
// Sparse expert GEMM1: mid[e][slot] = gelu(h2b[tok(slot)] @ w1t[e]^T), bf16.
// global_load_lds staging; rowmap gather; T1 XCD swizzle.
// ---------------------------------------------------------------------------
__global__ __launch_bounds__(256) void gemm_moe1_sparse(
        const __hip_bfloat16* __restrict__ A,      // h2b [NN][CC]
        const __hip_bfloat16* __restrict__ w1t,    // [16][II][CC]
        __hip_bfloat16* __restrict__ mid,          // [16][NN][II] compacted
        const int* __restrict__ cnt,
        const int* __restrict__ elist) {
    __shared__ __hip_bfloat16 As[128][32];
    __shared__ __hip_bfloat16 Bs[128][32];
    __shared__ int rowmap[128];
    int bx, by, bz;
    xcd_swizzle3(bx, by, bz);
    const int e = bz;
    const int count = cnt[e];
    const int m0 = by * 128;
    if (m0 >= count) return;
    const int n0 = bx * 128;
    const __hip_bfloat16* Bt = w1t + (long)e*II*CC;
    const int* lst = elist + (long)e*NN;
    const int tid = threadIdx.x;
    if (tid < 128) rowmap[tid] = lst[min(m0 + tid, count - 1)];
    __syncthreads();
    const int wave = tid >> 6, lane = tid & 63;
    const int wm = (wave >> 1) * 64, wn = (wave & 1) * 64;
    const int l15 = lane & 15, quad = lane >> 4;
    // cache this lane's 2 gather rows (for staging chunks wave*2, wave*2+1)
    int rm[2];
    #pragma unroll
    for (int i = 0; i < 2; i++) rm[i] = rowmap[(wave*2 + i)*16 + (lane >> 2)];

    f32x4 acc[4][4] = {};

    for (int k0 = 0; k0 < CC; k0 += 32) {
        #pragma unroll
        for (int i = 0; i < 2; i++) {
            const int chunk = wave*2 + i;
            const int r = chunk*16 + (lane >> 2);
            const int c8 = (lane & 3) * 8;
            GLOAD_LDS16(A  + (long)rm[i]*CC + k0 + c8, &As[chunk*16][0]);
            GLOAD_LDS16(Bt + (long)(n0 + r)*CC + k0 + c8, &Bs[chunk*16][0]);
        }
        __syncthreads();
        short8 af[4], bff[4];
        #pragma unroll
        for (int i = 0; i < 4; i++) {
            af[i]  = *(const short8*)&As[wm + i*16 + l15][quad*8];
            bff[i] = *(const short8*)&Bs[wn + i*16 + l15][quad*8];
        }
        #pragma unroll
        for (int mi = 0; mi < 4; mi++)
            #pragma unroll
            for (int ni = 0; ni < 4; ni++)
                acc[mi][ni] = __builtin_amdgcn_mfma_f32_16x16x32_bf16(
                                  af[mi], bff[ni], acc[mi][ni], 0, 0, 0);
        __syncthreads();
    }

    #pragma unroll
    for (int mi = 0; mi < 4; mi++) {
        #pragma unroll
        for (int r = 0; r < 4; r++) {
            const int slot = m0 + wm + mi*16 + quad*4 + r;
            if (slot < count) {
                #pragma unroll
                for (int ni = 0; ni < 4; ni++) {
                    const int col = n0 + wn + ni*16 + l15;
                    float val = acc[mi][ni][r];
                    val = 0.5f*val*(1.f + erff(val*0.70710678118f));
                    mid[((long)e*NN + slot)*II + col] = __float2bfloat16(val);
                }
            }
        }
    }
}

// ---------------------------------------------------------------------------
// Sparse expert GEMM2: eo[tok(slot), e, :] = mid[e][slot] @ w2t[e]^T
// global_load_lds staging + T1 XCD swizzle. No atomics.
// ---------------------------------------------------------------------------
__global__ __launch_bounds__(256) void gemm_moe2_sparse(
        const __hip_bfloat16* __restrict__ mid,    // [16][NN][II] compacted
        const __hip_bfloat16* __restrict__ w2t,    // [16][CC][II]
        float* __restrict__ eo,                    // [NN][EE][CC]
        const int* __restrict__ cnt,
        const int* __restrict__ elist) {
    __shared__ __hip_bfloat16 As[128][32];
    __shared__ __hip_bfloat16 Bs[128][32];
    __shared__ int rowmap[128];
    int bx, by, bz;
    xcd_swizzle3(bx, by, bz);
    const int e = bz;
    const int count = cnt[e];
    const int m0 = by * 128;
    if (m0 >= count) return;
    const int n0 = bx * 128;
    const __hip_bfloat16* A  = mid + (long)e*NN*II;
    const __hip_bfloat16* Bt = w2t + (long)e*CC*II;
    const int* lst = elist + (long)e*NN;
    const int tid = threadIdx.x;
    if (tid < 128) rowmap[tid] = lst[min(m0 + tid, count - 1)];
    __syncthreads();
    const int wave = tid >> 6, lane = tid & 63;
    const int wm = (wave >> 1) * 64, wn = (wave & 1) * 64;
    const int l15 = lane & 15, quad = lane >> 4;

    f32x4 acc[4][4] = {};

    for (int k0 = 0; k0 < II; k0 += 32) {
        #pragma unroll
        for (int i = 0; i < 2; i++) {
            const int chunk = wave*2 + i;
            const int r = chunk*16 + (lane >> 2);
            const int c8 = (lane & 3) * 8;
            GLOAD_LDS16(A  + (long)(m0 + r)*II + k0 + c8, &As[chunk*16][0]);
            GLOAD_LDS16(Bt + (long)(n0 + r)*II + k0 + c8, &Bs[chunk*16][0]);
        }
        __syncthreads();
        short8 af[4], bff[4];
        #pragma unroll
        for (int i = 0; i < 4; i++) {
            af[i]  = *(const short8*)&As[wm + i*16 + l15][quad*8];
            bff[i] = *(const short8*)&Bs[wn + i*16 + l15][quad*8];
        }
        #pragma unroll
        for (int mi = 0; mi < 4; mi++)
            #pragma unroll
            for (int ni = 0; ni < 4; ni++)
                acc[mi][ni] = __builtin_amdgcn_mfma_f32_16x16x32_bf16(
                                  af[mi], bff[ni], acc[mi][ni], 0, 0, 0);
        __syncthreads();
    }

    #pragma unroll
    for (int mi = 0; mi < 4; mi++) {
        #pragma unroll
        for (int r = 0; r < 4; r++) {
            const int slot = m0 + wm + mi*16 + quad*4 + r;
            if (slot < count) {
                const int tok = rowmap[wm + mi*16 + quad*4 + r];
                #pragma unroll
                for (int ni = 0; ni < 4; ni++) {
                    const int col = n0 + wn + ni*16 + l15;
                    eo[((long)tok*EE + e)*CC + col] = acc[mi][ni][r];
                }
            }
        }
    }
}

// ---------------------------------------------------------------------------
// Fused: zero inactive eo rows + final[n,:] = sum over active e of eo[n,e,:];
// xio += final. Deterministic e-ascending order.
// ---------------------------------------------------------------------------
__global__ __launch_bounds__(256) void moe_sum_zero(const float* __restrict__ maskb,
                                                    float* __restrict__ eo,
                                                    float* __restrict__ xio) {
    const int row = blockIdx.x, tid = threadIdx.x;
    float4 s = {0.f, 0.f, 0.f, 0.f};
    const float4 z4 = {0.f, 0.f, 0.f, 0.f};
    #pragma unroll
    for (int e = 0; e < EE; e++) {
        float4* p = ((float4*)(eo + ((long)row*EE + e)*CC)) + tid;
        if (maskb[(long)row*EE + e] != 0.f) {
            float4 v = *p;
            s.x += v.x; s.y += v.y; s.z += v.z; s.w += v.w;
        } else {
            *p = z4;
        }
    }
    float4 xv = ((float4*)(xio + (long)row*CC))[tid];
    xv.x += s.x; xv.y += s.y; xv.z += s.z; xv.w += s.w;
    ((float4*)(xio + (long)row*CC))[tid] = xv;
}

// ---------------------------------------------------------------------------
// Flash attention with bf16x3 MFMA for QK^T and PV. kt-split for balance.
// All inputs PRE-SPLIT bf16 hi/lo; V pre-transposed [(b*H+h)*64+d][T].
// T14 async-STAGE prefetch + T5 setprio around MFMA clusters.
// ---------------------------------------------------------------------------
__global__ __launch_bounds__(256, 4) void attn_split(
        const __hip_bfloat16* __restrict__ Qh, const __hip_bfloat16* __restrict__ Ql,
        const __hip_bfloat16* __restrict__ Kh, const __hip_bfloat16* __restrict__ Kl,
        const __hip_bfloat16* __restrict__ Vtg_h, const __hip_bfloat16* __restrict__ Vtg_l,
        float* __restrict__ Opart,
        float* __restrict__ mpart,
        float* __restrict__ lpart) {
    __shared__ __hip_bfloat16 KPh[64][LDA], KPl[64][LDA];   // K, then P
    __shared__ __hip_bfloat16 Vth[64][LDA], Vtl[64][LDA];   // V^T [d][kk]

    const int bx = blockIdx.x;                 // 0..31, heavy qt first
    const int qt = 15 - (bx >> 1), half = bx & 1;
    const int h = blockIdx.y, b = blockIdx.z;
    const int tid = threadIdx.x;
    const int wave = tid >> 6, lane = tid & 63;
    const int l15 = lane & 15, quad = lane >> 4;
    const int wm = wave * 16;                  // wave's 16 q-rows in the 64-tile
    const long tbase = (long)b * TT * CC + (long)h * DD;          // [token][C] slab
    const long vbase = (long)(b*HH + h) * 64 * TT;                // V^T slab
    const int pidx = ((b*HH + h)*16 + qt)*2 + half;
    float* Op = Opart + (long)pidx * 4096;

    const int n_kt = qt + 1, mid_kt = (n_kt + 1) >> 1;
    const int kt_lo = half ? mid_kt : 0;
    const int kt_hi = half ? n_kt   : mid_kt;

    if (kt_lo >= kt_hi) {      // empty half (qt=0): neutral partials
        for (int i = tid; i < 64*64; i += 256) Op[i] = 0.f;
        if (tid < 64) { mpart[(long)pidx*64 + tid] = -1e30f; lpart[(long)pidx*64 + tid] = 0.f; }
        return;
    }

    // Q A-fragments direct from pre-split global
    short8 qh[2], ql[2];
    {
        const long qoff = tbase + (long)(qt*64 + wm + l15)*CC;
        #pragma unroll
        for (int kc = 0; kc < 2; kc++) {
            qh[kc] = *(const short8*)(Qh + qoff + kc*32 + quad*8);
            ql[kc] = *(const short8*)(Ql + qoff + kc*32 + quad*8);
        }
    }

    // staging geometry: this thread covers rows r0 and r0+32, col group g0
    const int r0 = tid >> 3, g0 = (tid & 7) * 8;

    // prefetch registers for the next K/V tile (T14 async-STAGE split)
    short8 sKh0, sKl0, sVh0, sVl0, sKh1, sKl1, sVh1, sVl1;
    {
        const int kt = kt_lo;
        const long k0off = tbase + (long)(kt*64 + r0)*CC + g0;
        const long k1off = tbase + (long)(kt*64 + r0 + 32)*CC + g0;
        const long v0off = vbase + (long)r0*TT + kt*64 + g0;
        const long v1off = vbase + (long)(r0 + 32)*TT + kt*64 + g0;
        sKh0 = *(const short8*)(Kh + k0off);    sKl0 = *(const short8*)(Kl + k0off);
        sKh1 = *(const short8*)(Kh + k1off);    sKl1 = *(const short8*)(Kl + k1off);
        sVh0 = *(const short8*)(Vtg_h + v0off); sVl0 = *(const short8*)(Vtg_l + v0off);
        sVh1 = *(const short8*)(Vtg_h + v1off); sVl1 = *(const short8*)(Vtg_l + v1off);
    }

    f32x4 oacc[4] = {};            // 4 d-tiles, rows = quad*4+reg
    float m_run[4], l_run[4];
    #pragma unroll
    for (int r = 0; r < 4; r++) { m_run[r] = -1e30f; l_run[r] = 0.f; }

    for (int kt = kt_lo; kt < kt_hi; kt++) {
        __syncthreads();           // prev-iter PV reads of KP/Vt done
        // write prefetched tile to LDS
        *(short8*)&KPh[r0][g0]      = sKh0;  *(short8*)&KPl[r0][g0]      = sKl0;
        *(short8*)&KPh[r0 + 32][g0] = sKh1;  *(short8*)&KPl[r0 + 32][g0] = sKl1;
        *(short8*)&Vth[r0][g0]      = sVh0;  *(short8*)&Vtl[r0][g0]      = sVl0;
        *(short8*)&Vth[r0 + 32][g0] = sVh1;  *(short8*)&Vtl[r0 + 32][g0] = sVl1;
        // issue next tile's global loads (latency hides under QK/softmax/PV)
        if (kt + 1 < kt_hi) {
            const int kn = kt + 1;
            const long k0off = tbase + (long)(kn*64 + r0)*CC + g0;
            const long k1off = tbase + (long)(kn*64 + r0 + 32)*CC + g0;
            const long v0off = vbase + (long)r0*TT + kn*64 + g0;
            const long v1off = vbase + (long)(r0 + 32)*TT + kn*64 + g0;
            sKh0 = *(const short8*)(Kh + k0off);    sKl0 = *(const short8*)(Kl + k0off);
            sKh1 = *(const short8*)(Kh + k1off);    sKl1 = *(const short8*)(Kl + k1off);
            sVh0 = *(const short8*)(Vtg_h + v0off); sVl0 = *(const short8*)(Vtg_l + v0off);
            sVh1 = *(const short8*)(Vtg_h + v1off); sVl1 = *(const short8*)(Vtg_l + v1off);
        }
        __syncthreads();

        // QK^T via MFMA: 4 key-tiles x 2 k-chunks x 3 split terms (T5 setprio)
        f32x4 s[4] = {};
        __builtin_amdgcn_s_setprio(1);
        #pragma unroll
        for (int nt = 0; nt < 4; nt++)
            #pragma unroll
            for (int kc = 0; kc < 2; kc++) {
                short8 bh = *(const short8*)&KPh[nt*16 + l15][kc*32 + quad*8];
                short8 bl = *(const short8*)&KPl[nt*16 + l15][kc*32 + quad*8];
                s[nt] = __builtin_amdgcn_mfma_f32_16x16x32_bf16(qh[kc], bh, s[nt], 0,0,0);
                s[nt] = __builtin_amdgcn_mfma_f32_16x16x32_bf16(qh[kc], bl, s[nt], 0,0,0);
                s[nt] = __builtin_amdgcn_mfma_f32_16x16x32_bf16(ql[kc], bh, s[nt], 0,0,0);
            }
        __builtin_amdgcn_s_setprio(0);

        // online softmax in regs; row = wm + quad*4 + r, col = nt*16 + l15
        const bool diag = (kt == qt);
        float alpha[4];
        float pr[4][4];
        #pragma unroll
        for (int r = 0; r < 4; r++) {
            const int rowg = wm + quad*4 + r;
            float sv[4], mx = -1e30f;
            #pragma unroll
            for (int nt = 0; nt < 4; nt++) {
                float val = s[nt][r] * 0.125f;
                if (diag && (nt*16 + l15) > rowg) val = -1e30f;
                sv[nt] = val;
                mx = fmaxf(mx, val);
            }
            #pragma unroll
            for (int off = 1; off < 16; off <<= 1) mx = fmaxf(mx, __shfl_xor(mx, off, 16));
            const float mnew = fmaxf(m_run[r], mx);
            alpha[r] = __expf(m_run[r] - mnew);
            float rs = 0.f;
            #pragma unroll
            for (int nt = 0; nt < 4; nt++) {
                float p = __expf(sv[nt] - mnew);
                pr[r][nt] = p;
                rs += p;
            }
            #pragma unroll
            for (int off = 1; off < 16; off <<= 1) rs += __shfl_xor(rs, off, 16);
            l_run[r] = l_run[r]*alpha[r] + rs;
            m_run[r] = mnew;
        }
        __syncthreads();           // all QK reads of KP done -> overwrite as P

        // write P split into KP region: row = wm+quad*4+r, col = nt*16+l15
        #pragma unroll
        for (int r = 0; r < 4; r++)
            #pragma unroll
            for (int nt = 0; nt < 4; nt++) {
                short hh, ll; splitbf(pr[r][nt], hh, ll);
                *(short*)&KPh[wm + quad*4 + r][nt*16 + l15] = hh;
                *(short*)&KPl[wm + quad*4 + r][nt*16 + l15] = ll;
            }
        // no barrier: PV reads only this wave's own 16 P-rows

        // rescale O and accumulate PV via MFMA (T5 setprio)
        #pragma unroll
        for (int dt = 0; dt < 4; dt++)
            #pragma unroll
            for (int r = 0; r < 4; r++)
                oacc[dt][r] *= alpha[r];
        __builtin_amdgcn_s_setprio(1);
        #pragma unroll
        for (int kc = 0; kc < 2; kc++) {
            short8 ph = *(const short8*)&KPh[wm + l15][kc*32 + quad*8];
            short8 pl = *(const short8*)&KPl[wm + l15][kc*32 + quad*8];
            #pragma unroll
            for (int dt = 0; dt < 4; dt++) {
                short8 vh = *(const short8*)&Vth[dt*16 + l15][kc*32 + quad*8];
                short8 vl = *(const short8*)&Vtl[dt*16 + l15][kc*32 + quad*8];
                oacc[dt] = __builtin_amdgcn_mfma_f32_16x16x32_bf16(ph, vh, oacc[dt], 0,0,0);
                oacc[dt] = __builtin_amdgcn_mfma_f32_16x16x32_bf16(ph, vl, oacc[dt], 0,0,0);
                oacc[dt] = __builtin_amdgcn_mfma_f32_16x16x32_bf16(pl, vh, oacc[dt], 0,0,0);
            }
        }
        __builtin_amdgcn_s_setprio(0);
    }

    // store unnormalized O partial + (m,l)
    #pragma unroll
    for (int dt = 0; dt < 4; dt++)
        #pragma unroll
        for (int r = 0; r < 4; r++)
            Op[(wm + quad*4 + r)*64 + dt*16 + l15] = oacc[dt][r];
    if (l15 == 0) {
        #pragma unroll
        for (int r = 0; r < 4; r++) {
            mpart[(long)pidx*64 + wm + quad*4 + r] = m_run[r];
            lpart[(long)pidx*64 + wm + quad*4 + r] = l_run[r];
        }
    }
}

// ---------------------------------------------------------------------------
// Merge the two kt-half partials -> normalized attention output, emitted as
// pre-split bf16 hi/lo (direct feed for the WO bf16x3 GEMM).
// ---------------------------------------------------------------------------
__global__ __launch_bounds__(256) void attn_merge(const float* __restrict__ Opart,
                                                  const float* __restrict__ mpart,
                                                  const float* __restrict__ lpart,
                                                  __hip_bfloat16* __restrict__ aoh,
                                                  __hip_bfloat16* __restrict__ aol) {
    const int qt = blockIdx.x, h = blockIdx.y, b = blockIdx.z;
    const int pA = ((b*HH + h)*16 + qt)*2, pB = pA + 1;
    const int tid = threadIdx.x;
    const int r = tid >> 2, c0 = (tid & 3) * 16;
    const float mA = mpart[(long)pA*64 + r], mB = mpart[(long)pB*64 + r];
    const float lA = lpart[(long)pA*64 + r], lB = lpart[(long)pB*64 + r];
    const float M  = fmaxf(mA, mB);
    const float wA = __expf(mA - M), wB = __expf(mB - M);
    const float inv = 1.f / (lA*wA + lB*wB);
    const float* OA = Opart + (long)pA*4096 + r*64 + c0;
    const float* OB = Opart + (long)pB*4096 + r*64 + c0;
    const long dst = (long)b*TT*CC + (long)(qt*64 + r)*CC + h*DD + c0;
    #pragma unroll
    for (int j = 0; j < 16; j += 4) {
        float4 oa = *(const float4*)(OA + j);
        float4 ob = *(const float4*)(OB + j);
        float xs[4];
        xs[0] = (oa.x*wA + ob.x*wB)*inv;
        xs[1] = (oa.y*wA + ob.y*wB)*inv;
        xs[2] = (oa.z*wA + ob.z*wB)*inv;
        xs[3] = (oa.w*wA + ob.w*wB)*inv;
        s16x4 hv, lv;
        #pragma unroll
        for (int t = 0; t < 4; t++) { short hh,ll; splitbf(xs[t],hh,ll); hv[t]=hh; lv[t]=ll; }
        *(s16x4*)(aoh + dst + j) = hv;
        *(s16x4*)(aol + dst + j) = lv;
    }
}

// ---------------------------------------------------------------------------
extern "C" void kernel_launch(void* const* d_in, const int* in_sizes, int n_in,
                              void* d_out, int out_size, void* d_ws, size_t ws_size,
                              hipStream_t stream) {
    const float* x     = (const float*)d_in[0];
    const float* ln1_g = (const float*)d_in[1];
    const float* ln1_b = (const float*)d_in[2];
    const float* ln2_g = (const float*)d_in[3];
    const float* ln2_b = (const float*)d_in[4];
    const float* wq    = (const float*)d_in[5];
    const float* wk    = (const float*)d_in[6];
    const float* wv    = (const float*)d_in[7];
    const float* wo    = (const float*)d_in[8];
    const float* sim   = (const float*)d_in[9];
    const float* thr   = (const float*)d_in[10];
    const float* w1    = (const float*)d_in[11];
    const float* w2    = (const float*)d_in[12];

    float* out_x      = (float*)d_out;
    float* out_scores = out_x + (long)NN*CC;
    float* out_eo     = out_scores + (long)NN*EE;
    float* out_kpt    = out_eo + (long)NN*EE*CC;

    const long MF = (long)NN*CC;     // 2M floats
    const long CK = (long)CC*CC;     // 1M elems per weight slab
    float* ws   = (float*)d_ws;
    // [0, MF): attn-out split bf16 (hi/lo)
    __hip_bfloat16* aoh = (__hip_bfloat16*)ws;
    __hip_bfloat16* aol = (__hip_bfloat16*)(ws + MF/2);
    // [MF, 4MF): QKV pre-split bf16 (3 slabs hi, 3 slabs lo)
    __hip_bfloat16* qkvh = (__hip_bfloat16*)(ws + MF);
    __hip_bfloat16* qkvl = (__hip_bfloat16*)(ws + MF + 3*MF/2);
    // [4MF, 5MF): V^T pre-split bf16
    __hip_bfloat16* vth = (__hip_bfloat16*)(ws + 4*MF);
    __hip_bfloat16* vtl = (__hip_bfloat16*)(ws + 4*MF + MF/2);
    // [5MF, 5.5MF): LN2 bf16 for expert GEMM
    __hip_bfloat16* h2b = (__hip_bfloat16*)(ws + 5*MF);
    // [5.5MF, 7.5MF): attn partials; hh/hl (LN1 split) + mid alias
    float* Opart = ws + 5*MF + MF/2;
    __hip_bfloat16* hh  = (__hip_bfloat16*)(ws + 5*MF + MF/2);       // dead after QKV GEMM
    __hip_bfloat16* hl  = (__hip_bfloat16*)(ws + 6*MF);
    __hip_bfloat16* mid = (__hip_bfloat16*)(ws + 5*MF + MF/2);       // after merge
    // [7.5MF, 9.5MF): QKVO weight splits; w1t/w2t alias (after WO GEMM)
    __hip_bfloat16* wsph = (__hip_bfloat16*)(ws + 7*MF + MF/2);      // [4][C][C] hi
    __hip_bfloat16* wspl = (__hip_bfloat16*)(ws + 8*MF + MF/2);      // [4][C][C] lo
    __hip_bfloat16* w1t  = (__hip_bfloat16*)(ws + 7*MF + MF/2);
    __hip_bfloat16* w2t  = (__hip_bfloat16*)(ws + 8*MF + MF/2);
    float* maskb = ws + 9*MF + MF/2;                                  // 32K floats
    float* cn    = maskb + (long)NN*EE;                               // 16
    float* mpart = cn + 16;                                           // 64K
    float* lpart = mpart + 1024L*64;                                  // 64K
    int*   cnt   = (int*)(lpart + 1024L*64);                          // 16 ints
    int*   elist = cnt + 16;                                          // EE*NN ints

    // 0. fused prep: QKVO weight split + LN1 + sim col-norms + cnt zero
    prep_kernel<<<4096 + NN + EE, 256, 0, stream>>>(
        x, ln1_g, ln1_b, hh, hl, wq, wk, wv, wo, wsph, wspl, sim, cn, cnt);

    // 1. fused QKV projection, 128x128 tile, gload_lds + XCD swizzle
    {
        dim3 gq(CC/128, NN/128, 3);
        gemm_split_big<<<gq, 256, 0, stream>>>(hh, hl, wsph, wspl,
                                               qkvh, qkvl, NN, CC, CC);
    }

    // 1.5 V transpose (bf16 hi/lo): [token][C] -> per-(b,h) [d][T]
    {
        dim3 gv(TT/32, CC/32, BB);
        transpose_v_bf16<<<gv, 256, 0, stream>>>(qkvh + 2*(long)NN*CC, qkvl + 2*(long)NN*CC,
                                                 vth, vtl);
    }

    // 2. causal attention (MFMA flash, prefetch + setprio) + merge
    {
        dim3 gattn(32, HH, BB);
        attn_split<<<gattn, 256, 0, stream>>>(qkvh, qkvl,
                                              qkvh + (long)NN*CC, qkvl + (long)NN*CC,
                                              vth, vtl, Opart, mpart, lpart);
        dim3 gmerge(16, HH, BB);
        attn_merge<<<gmerge, 256, 0, stream>>>(Opart, mpart, lpart, aoh, aol);
    }

    // 3. output projection + residual (gload_lds + XCD swizzle)
    {
        dim3 go(CC/128, NN/64, 1);
        gemm_split<<<go, 256, 0, stream>>>(aoh, aol, wsph + 3*CK, wspl + 3*CK,
                                           out_x, NN, CC, CC, x);
    }

    // 4. expert weight transposes (single launch; safe to overwrite QKVO splits)
    {
        dim3 ge(256, 1, 2*EE);
        transpose_f2b_both<<<ge, 256, 0, stream>>>(w1, w2, w1t, w2t);
    }

    // 5. fused LN2 + router + active-token compaction
    ln2_router<<<NN, 256, 0, stream>>>(out_x, ln2_g, ln2_b, sim, cn, thr,
                                       h2b, out_scores, out_kpt, maskb,
                                       cnt, elist);

    // 6. sparse expert GEMM 1 (XCD swizzle)
    {
        dim3 g(II/128, NN/128, EE);
        gemm_moe1_sparse<<<g, 256, 0, stream>>>(h2b, w1t, mid, cnt, elist);
    }

    // 7. sparse expert GEMM 2 (XCD swizzle)
    {
        dim3 g(CC/128, NN/128, EE);
        gemm_moe2_sparse<<<g, 256, 0, stream>>>(mid, w2t, out_eo, cnt, elist);
    }

    // 8. fused: zero inactive eo rows + sum active -> x (deterministic order)
    moe_sum_zero<<<NN, 256, 0, stream>>>(maskb, out_eo, out_x);
}